// Round 17
// baseline (447.367 us; speedup 1.0000x reference)
//
#include <hip/hip_runtime.h>
#include <hip/hip_bf16.h>

#define B_ 2
#define S_ 2048
#define DM 2048
#define H_ 16
#define DH 128
#define NBLK 32
#define NKEEP 18
#define BH (B_ * H_)

typedef __attribute__((ext_vector_type(8))) short short8;
typedef __attribute__((ext_vector_type(8))) _Float16 f16x8;
typedef __attribute__((ext_vector_type(4))) _Float16 f16x4;
typedef __attribute__((ext_vector_type(4))) float f32x4;

#define GLOAD16(gp, lp)                                                        \
  __builtin_amdgcn_global_load_lds(                                            \
      (const __attribute__((address_space(1))) unsigned int*)(const void*)(gp),\
      (__attribute__((address_space(3))) unsigned int*)(void*)(lp), 16, 0, 0)

__device__ __forceinline__ unsigned short f32_to_bf16(float f) {
  unsigned u = __float_as_uint(f);
  unsigned r = (u + 0x7fffu + ((u >> 16) & 1u)) >> 16;
  return (unsigned short)r;
}
__device__ __forceinline__ float bf16_to_f32(unsigned short h) {
  return __uint_as_float(((unsigned)h) << 16);
}

// ---------------- proj: threefry2x32 (partitionable) + erfinv ----------------
__device__ __forceinline__ unsigned rotl32(unsigned x, int r) {
  return (x << r) | (x >> (32 - r));
}

__device__ __forceinline__ float erfinv_f32(float x) {
  float w = -log1pf(-x * x);
  float p;
  if (w < 5.0f) {
    w -= 2.5f;
    p = 2.81022636e-08f;
    p = fmaf(p, w, 3.43273939e-07f);
    p = fmaf(p, w, -3.5233877e-06f);
    p = fmaf(p, w, -4.39150654e-06f);
    p = fmaf(p, w, 0.00021858087f);
    p = fmaf(p, w, -0.00125372503f);
    p = fmaf(p, w, -0.00417768164f);
    p = fmaf(p, w, 0.246640727f);
    p = fmaf(p, w, 1.50140941f);
  } else {
    w = sqrtf(w) - 3.0f;
    p = -0.000200214257f;
    p = fmaf(p, w, 0.000100950558f);
    p = fmaf(p, w, 0.00134934322f);
    p = fmaf(p, w, -0.00367342844f);
    p = fmaf(p, w, 0.00573950773f);
    p = fmaf(p, w, -0.0076224613f);
    p = fmaf(p, w, 0.00943887047f);
    p = fmaf(p, w, 1.00167406f);
    p = fmaf(p, w, 2.83297682f);
  }
  return p * x;
}

__device__ __forceinline__ float bits_to_normal(unsigned b) {
  float f = __uint_as_float((b >> 9) | 0x3f800000u) - 1.0f;
  const float lo = -0.9999999403953552f;
  float u = fmaxf(lo, fmaf(f, 2.0f, lo));
  return 1.4142135623730951f * erfinv_f32(u);
}

__global__ void proj_kernel(float* __restrict__ proj) {
  int i = blockIdx.x * blockDim.x + threadIdx.x;
  if (i >= 4096) return;
  unsigned k0 = 0u, k1 = 42u;
  unsigned k2 = 0x1BD11BDAu ^ k0 ^ k1;
  unsigned x0 = 0u, x1 = (unsigned)i;
  x0 += k0; x1 += k1;
#define QR(r) { x0 += x1; x1 = rotl32(x1, r); x1 ^= x0; }
  QR(13) QR(15) QR(26) QR(6)   x0 += k1; x1 += k2 + 1u;
  QR(17) QR(29) QR(16) QR(24)  x0 += k2; x1 += k0 + 2u;
  QR(13) QR(15) QR(26) QR(6)   x0 += k0; x1 += k1 + 3u;
  QR(17) QR(29) QR(16) QR(24)  x0 += k1; x1 += k2 + 4u;
  QR(13) QR(15) QR(26) QR(6)   x0 += k2; x1 += k0 + 5u;
#undef QR
  proj[i] = bits_to_normal(x0 ^ x1) / 5.656854249492381f;
}

// ---------------- RoPE tables ----------------
__global__ void rope_table_kernel(float* __restrict__ cosb, float* __restrict__ sinb) {
  int s = blockIdx.x;
  int j = threadIdx.x;
  double e = (double)(2 * j) / 128.0;
  double invf = 1.0 / pow(10000.0, e);
  float freq = (float)s * (float)invf;
  cosb[s * 64 + j] = (float)cos((double)freq);
  sinb[s * 64 + j] = (float)sin((double)freq);
}

// ---------------- x -> bf16 hi/lo + fp16, single pass ----------------
__global__ __launch_bounds__(256) void split_x3_kernel(const float* __restrict__ in,
                                                       unsigned short* __restrict__ hi,
                                                       unsigned short* __restrict__ lo,
                                                       _Float16* __restrict__ f16,
                                                       int n4) {
  int i = blockIdx.x * blockDim.x + threadIdx.x;
  if (i >= n4) return;
  float4 v = ((const float4*)in)[i];
  ushort4 hv, lv;
  f16x4 fv;
  hv.x = f32_to_bf16(v.x); lv.x = f32_to_bf16(v.x - bf16_to_f32(hv.x)); fv[0] = (_Float16)v.x;
  hv.y = f32_to_bf16(v.y); lv.y = f32_to_bf16(v.y - bf16_to_f32(hv.y)); fv[1] = (_Float16)v.y;
  hv.z = f32_to_bf16(v.z); lv.z = f32_to_bf16(v.z - bf16_to_f32(hv.z)); fv[2] = (_Float16)v.z;
  hv.w = f32_to_bf16(v.w); lv.w = f32_to_bf16(v.w - bf16_to_f32(hv.w)); fv[3] = (_Float16)v.w;
  ((ushort4*)hi)[i] = hv;
  ((ushort4*)lo)[i] = lv;
  ((f16x4*)f16)[i] = fv;
}

// ---------------- fused W split: Wk -> bf16 hi/lo; Wq, Wv -> fp16 ----------
__global__ __launch_bounds__(256) void split_w3_kernel(const float* __restrict__ wk,
                                                       const float* __restrict__ wq,
                                                       const float* __restrict__ wv,
                                                       unsigned short* __restrict__ khi,
                                                       unsigned short* __restrict__ klo,
                                                       _Float16* __restrict__ qf,
                                                       _Float16* __restrict__ vf,
                                                       int n4) {
  int i = blockIdx.x * blockDim.x + threadIdx.x;
  if (i >= n4) return;
  {
    float4 v = ((const float4*)wk)[i];
    ushort4 hv, lv;
    hv.x = f32_to_bf16(v.x); lv.x = f32_to_bf16(v.x - bf16_to_f32(hv.x));
    hv.y = f32_to_bf16(v.y); lv.y = f32_to_bf16(v.y - bf16_to_f32(hv.y));
    hv.z = f32_to_bf16(v.z); lv.z = f32_to_bf16(v.z - bf16_to_f32(hv.z));
    hv.w = f32_to_bf16(v.w); lv.w = f32_to_bf16(v.w - bf16_to_f32(hv.w));
    ((ushort4*)khi)[i] = hv;
    ((ushort4*)klo)[i] = lv;
  }
  {
    float4 v = ((const float4*)wq)[i];
    f16x4 fv;
    fv[0] = (_Float16)v.x; fv[1] = (_Float16)v.y;
    fv[2] = (_Float16)v.z; fv[3] = (_Float16)v.w;
    ((f16x4*)qf)[i] = fv;
  }
  {
    float4 v = ((const float4*)wv)[i];
    f16x4 fv;
    fv[0] = (_Float16)v.x; fv[1] = (_Float16)v.y;
    fv[2] = (_Float16)v.z; fv[3] = (_Float16)v.w;
    ((f16x4*)vf)[i] = fv;
  }
}

// ---------------- W -> fp16 (Wo, late) ----------------
__global__ __launch_bounds__(256) void split_f16_kernel(const float* __restrict__ in,
                                                        _Float16* __restrict__ f16,
                                                        int n4) {
  int i = blockIdx.x * blockDim.x + threadIdx.x;
  if (i >= n4) return;
  float4 v = ((const float4*)in)[i];
  f16x4 fv;
  fv[0] = (_Float16)v.x; fv[1] = (_Float16)v.y;
  fv[2] = (_Float16)v.z; fv[3] = (_Float16)v.w;
  ((f16x4*)f16)[i] = fv;
}

// ---------------- k-GEMM: bf16x3, 256x256, 8 waves, SPLIT-K=2, 4-phase ------
__global__ __launch_bounds__(512, 2) void mfma_gemm_k_sk(const unsigned short* __restrict__ Ahi,
                                                         const unsigned short* __restrict__ Alo,
                                                         const unsigned short* __restrict__ Whi,
                                                         const unsigned short* __restrict__ Wlo,
                                                         float* __restrict__ kp0,
                                                         float* __restrict__ kp1) {
  __shared__ char smem[131072];  // 2 buf x 64K: Ahi 0|Alo 16K|Bhi 32K|Blo 48K
  const int t = threadIdx.x, l = t & 63, w = t >> 6;  // 8 waves
  const int lin = blockIdx.z * 128 + blockIdx.y * 8 + blockIdx.x;
  const int swz = (lin & 7) * 32 + (lin >> 3);        // 256 blocks, bijective
  const int kz = swz >> 7;
  const int idx = swz & 127;
  const int n0 = (idx & 7) * 256;
  const int m0 = (idx >> 3) * 256;
  const int kbase = kz * 1024;
  float* C = kz ? kp1 : kp0;
  const int wm = w >> 2, wn = w & 3;                  // 2M x 4N wave grid
  const int lr = l & 15;
  const int lg8 = (l >> 4) * 8;
  const size_t rstep = (size_t)16 * DM;

  const unsigned short* gAh = Ahi + (size_t)(m0 + w * 32 + lr) * DM + lg8;
  const unsigned short* gAl = Alo + (size_t)(m0 + w * 32 + lr) * DM + lg8;
  const unsigned short* gBh = Whi + (size_t)(n0 + w * 32 + lr) * DM + lg8;
  const unsigned short* gBl = Wlo + (size_t)(n0 + w * 32 + lr) * DM + lg8;

  f32x4 acc[8][4];
#pragma unroll
  for (int i = 0; i < 8; ++i)
#pragma unroll
    for (int j = 0; j < 4; ++j) acc[i][j] = (f32x4){0.f, 0.f, 0.f, 0.f};

  {  // prologue: full stage of tile 0 into buf 0
    char* base = smem + w * 2048;
    GLOAD16(gAh + kbase, base);
    GLOAD16(gAh + rstep + kbase, base + 1024);
    GLOAD16(gAl + kbase, base + 16384);
    GLOAD16(gAl + rstep + kbase, base + 16384 + 1024);
    GLOAD16(gBh + kbase, base + 32768);
    GLOAD16(gBh + rstep + kbase, base + 32768 + 1024);
    GLOAD16(gBl + kbase, base + 49152);
    GLOAD16(gBl + rstep + kbase, base + 49152 + 1024);
  }
  int cur = 0;

#define KQUAD(q)                                                                        \
  {                                                                                     \
    short8 ah0 = *(const short8*)(buf + (wm * 8 + 2 * (q)) * 1024 + l * 16);            \
    short8 ah1 = *(const short8*)(buf + (wm * 8 + 2 * (q) + 1) * 1024 + l * 16);        \
    short8 al0 = *(const short8*)(buf + 16384 + (wm * 8 + 2 * (q)) * 1024 + l * 16);    \
    short8 al1 = *(const short8*)(buf + 16384 + (wm * 8 + 2 * (q) + 1) * 1024 + l * 16);\
    __builtin_amdgcn_s_setprio(1);                                                      \
    _Pragma("unroll")                                                                   \
    for (int n = 0; n < 4; ++n) {                                                       \
      acc[2 * (q)][n] = __builtin_amdgcn_mfma_f32_16x16x32_bf16(ah0, bh[n], acc[2 * (q)][n], 0, 0, 0); \
      acc[2 * (q)][n] = __builtin_amdgcn_mfma_f32_16x16x32_bf16(ah0, bl[n], acc[2 * (q)][n], 0, 0, 0); \
      acc[2 * (q)][n] = __builtin_amdgcn_mfma_f32_16x16x32_bf16(al0, bh[n], acc[2 * (q)][n], 0, 0, 0); \
    }                                                                                   \
    _Pragma("unroll")                                                                   \
    for (int n = 0; n < 4; ++n) {                                                       \
      acc[2 * (q) + 1][n] = __builtin_amdgcn_mfma_f32_16x16x32_bf16(ah1, bh[n], acc[2 * (q) + 1][n], 0, 0, 0); \
      acc[2 * (q) + 1][n] = __builtin_amdgcn_mfma_f32_16x16x32_bf16(ah1, bl[n], acc[2 * (q) + 1][n], 0, 0, 0); \
      acc[2 * (q) + 1][n] = __builtin_amdgcn_mfma_f32_16x16x32_bf16(al1, bh[n], acc[2 * (q) + 1][n], 0, 0, 0); \
    }                                                                                   \
    __builtin_amdgcn_s_setprio(0);                                                      \
  }

  for (int k0 = kbase; k0 < kbase + 1024; k0 += 32) {
    const bool more = (k0 + 32 < kbase + 1024);
    char* buf = smem + cur * 65536;
    char* nb = smem + (cur ^ 1) * 65536 + w * 2048;
    const int kn = k0 + 32;

    if (more) {
      GLOAD16(gBh + kn, nb + 32768);
      GLOAD16(gBh + rstep + kn, nb + 32768 + 1024);
      asm volatile("s_waitcnt vmcnt(2)" ::: "memory");
    } else {
      asm volatile("s_waitcnt vmcnt(0)" ::: "memory");
    }
    __builtin_amdgcn_s_barrier();

    short8 bh[4], bl[4];
#pragma unroll
    for (int f = 0; f < 4; ++f) {
      bh[f] = *(const short8*)(buf + 32768 + (wn * 4 + f) * 1024 + l * 16);
      bl[f] = *(const short8*)(buf + 49152 + (wn * 4 + f) * 1024 + l * 16);
    }
    KQUAD(0);
    __builtin_amdgcn_s_barrier();

    if (more) {
      GLOAD16(gBl + kn, nb + 49152);
      GLOAD16(gBl + rstep + kn, nb + 49152 + 1024);
    }
    KQUAD(1);
    __builtin_amdgcn_s_barrier();

    if (more) {
      GLOAD16(gAh + kn, nb);
      GLOAD16(gAh + rstep + kn, nb + 1024);
    }
    KQUAD(2);
    __builtin_amdgcn_s_barrier();

    if (more) {
      GLOAD16(gAl + kn, nb + 16384);
      GLOAD16(gAl + rstep + kn, nb + 16384 + 1024);
    }
    KQUAD(3);
    __builtin_amdgcn_s_barrier();

    cur ^= 1;
  }
#undef KQUAD

#pragma unroll
  for (int m = 0; m < 8; ++m) {
    int row0 = m0 + wm * 128 + m * 16 + (l >> 4) * 4;
#pragma unroll
    for (int n = 0; n < 4; ++n) {
      int col = n0 + wn * 64 + n * 16 + (l & 15);
      int h = col >> 7, d = col & 127;
#pragma unroll
      for (int r = 0; r < 4; ++r) {
        int mm = row0 + r;
        int b = mm >> 11, s = mm & (S_ - 1);
        C[(((size_t)(b * H_ + h) * S_) + s) * DH + d] = acc[m][n][r];
      }
    }
  }
}

// ---------------- fused q+V fp16 GEMM: 256x256, 8 waves, 2-phase ------------
__global__ __launch_bounds__(512, 2) void mfma_gemm_qv(const _Float16* __restrict__ A,
                                                       const _Float16* __restrict__ W,
                                                       float* __restrict__ Cq,
                                                       _Float16* __restrict__ vt) {
  __shared__ char smem[65536];  // 2 buf x 32K: A frags 0..16K | B frags 16..32K
  const int t = threadIdx.x, l = t & 63, w = t >> 6;  // 8 waves
  const int lin = blockIdx.y * gridDim.x + blockIdx.x;
  const int swz = (lin & 7) * 32 + (lin >> 3);        // 256 blocks, bijective
  const int n0 = (swz & 15) * 256;
  const int m0 = (swz >> 4) * 256;
  const int wm = w >> 2, wn = w & 3;                  // 2M x 4N wave grid
  const int lr = l & 15;
  const int lg8 = (l >> 4) * 8;
  const size_t rstep = (size_t)16 * DM;

  const _Float16* gA = A + (size_t)(m0 + w * 32 + lr) * DM + lg8;
  const _Float16* gB = W + (size_t)(n0 + w * 32 + lr) * DM + lg8;

  f32x4 acc[8][4];
#pragma unroll
  for (int i = 0; i < 8; ++i)
#pragma unroll
    for (int j = 0; j < 4; ++j) acc[i][j] = (f32x4){0.f, 0.f, 0.f, 0.f};

  {  // prologue
    char* base = smem + w * 2048;
    GLOAD16(gA, base);
    GLOAD16(gA + rstep, base + 1024);
    GLOAD16(gB, base + 16384);
    GLOAD16(gB + rstep, base + 16384 + 1024);
  }
  int cur = 0;

  for (int k0 = 0; k0 < DM; k0 += 32) {
    const bool more = (k0 + 32 < DM);
    char* buf = smem + cur * 32768;
    char* nb = smem + (cur ^ 1) * 32768 + w * 2048;
    const int kn = k0 + 32;

    if (more) {
      GLOAD16(gA + kn, nb);
      GLOAD16(gA + rstep + kn, nb + 1024);
      asm volatile("s_waitcnt vmcnt(2)" ::: "memory");
    } else {
      asm volatile("s_waitcnt vmcnt(0)" ::: "memory");
    }
    __builtin_amdgcn_s_barrier();

    f16x8 b[4];
#pragma unroll
    for (int j = 0; j < 4; ++j)
      b[j] = *(const f16x8*)(buf + 16384 + (wn * 4 + j) * 1024 + l * 16);
    __builtin_amdgcn_s_setprio(1);
#pragma unroll
    for (int i = 0; i < 4; ++i) {
      f16x8 a = *(const f16x8*)(buf + (wm * 8 + i) * 1024 + l * 16);
#pragma unroll
      for (int j = 0; j < 4; ++j)
        acc[i][j] = __builtin_amdgcn_mfma_f32_16x16x32_f16(a, b[j], acc[i][j], 0, 0, 0);
    }
    __builtin_amdgcn_s_setprio(0);
    __builtin_amdgcn_s_barrier();

    if (more) {
      GLOAD16(gB + kn, nb + 16384);
      GLOAD16(gB + rstep + kn, nb + 16384 + 1024);
    }
    __builtin_amdgcn_s_setprio(1);
#pragma unroll
    for (int i = 4; i < 8; ++i) {
      f16x8 a = *(const f16x8*)(buf + (wm * 8 + i) * 1024 + l * 16);
#pragma unroll
      for (int j = 0; j < 4; ++j)
        acc[i][j] = __builtin_amdgcn_mfma_f32_16x16x32_f16(a, b[j], acc[i][j], 0, 0, 0);
    }
    __builtin_amdgcn_s_setprio(0);
    __builtin_amdgcn_s_barrier();

    cur ^= 1;
  }

#pragma unroll
  for (int m = 0; m < 8; ++m) {
    int row0 = m0 + wm * 128 + m * 16 + (l >> 4) * 4;
#pragma unroll
    for (int n = 0; n < 4; ++n) {
      int col = n0 + wn * 64 + n * 16 + (l & 15);
      if (col < DM) {
        int h = col >> 7, d = col & 127;
#pragma unroll
        for (int r = 0; r < 4; ++r) {
          int mm = row0 + r;
          int b2 = mm >> 11, s = mm & (S_ - 1);
          Cq[(((size_t)(b2 * H_ + h) * S_) + s) * DH + d] = acc[m][n][r];
        }
      } else {
        int vcol = col - DM;
        int h = vcol >> 7, d = vcol & 127;
        int b2 = row0 >> 11, s0 = row0 & (S_ - 1);
        f16x4 vv;
        vv[0] = (_Float16)acc[m][n][0];
        vv[1] = (_Float16)acc[m][n][1];
        vv[2] = (_Float16)acc[m][n][2];
        vv[3] = (_Float16)acc[m][n][3];
        *(f16x4*)(vt + (((size_t)(b2 * H_ + h)) * DH + d) * S_ + s0) = vv;
      }
    }
  }
}

// ---------------- fp16 single-product GEMM (O), BK=64, 128x128 --------------
template <int MODE>
__global__ __launch_bounds__(256) void mfma_gemm_f16(const _Float16* __restrict__ A,
                                                     const _Float16* __restrict__ W,
                                                     void* __restrict__ Cout) {
  __shared__ char smem[65536];
  const int t = threadIdx.x, l = t & 63, w = t >> 6;
  const int lin = blockIdx.y * gridDim.x + blockIdx.x;
  const int cpx = (gridDim.x * gridDim.y) >> 3;
  const int swz = (lin & 7) * cpx + (lin >> 3);
  const int n0 = (swz % gridDim.x) * 128;
  const int m0 = (swz / gridDim.x) * 128;
  const int wm = w >> 1, wn = w & 1;
  const int lr = l & 15;
  const int lg8 = (l >> 4) * 8;

  auto STAGE = [&](int k0, int c) {
    char* base = smem + c * 32768;
#pragma unroll
    for (int f0 = 0; f0 < 4; ++f0) {
      int f = w * 4 + f0;
      int rb = f >> 1, kh = f & 1;
      GLOAD16(A + (size_t)(m0 + rb * 16 + lr) * DM + k0 + kh * 32 + lg8,
              base + f * 1024);
      GLOAD16(W + (size_t)(n0 + rb * 16 + lr) * DM + k0 + kh * 32 + lg8,
              base + 16384 + f * 1024);
    }
  };

  f32x4 acc[4][4];
#pragma unroll
  for (int i = 0; i < 4; ++i)
#pragma unroll
    for (int j = 0; j < 4; ++j) acc[i][j] = (f32x4){0.f, 0.f, 0.f, 0.f};

  STAGE(0, 0);
  int cur = 0;

  for (int k0 = 0; k0 < DM; k0 += 64) {
    if (k0 + 64 < DM) {
      STAGE(k0 + 64, cur ^ 1);
      asm volatile("s_waitcnt vmcnt(8)" ::: "memory");
    } else {
      asm volatile("s_waitcnt vmcnt(0)" ::: "memory");
    }
    __builtin_amdgcn_s_barrier();

    char* buf = smem + cur * 32768;
    f16x8 a[4][2], b[4][2];
#pragma unroll
    for (int i = 0; i < 4; ++i)
#pragma unroll
      for (int kh = 0; kh < 2; ++kh) {
        a[i][kh] = *(const f16x8*)(buf + ((wm * 4 + i) * 2 + kh) * 1024 + l * 16);
        b[i][kh] = *(const f16x8*)(buf + 16384 + ((wn * 4 + i) * 2 + kh) * 1024 + l * 16);
      }
    __builtin_amdgcn_s_setprio(1);
#pragma unroll
    for (int i = 0; i < 4; ++i)
#pragma unroll
      for (int j = 0; j < 4; ++j) {
        acc[i][j] = __builtin_amdgcn_mfma_f32_16x16x32_f16(a[i][0], b[j][0], acc[i][j], 0, 0, 0);
        acc[i][j] = __builtin_amdgcn_mfma_f32_16x16x32_f16(a[i][1], b[j][1], acc[i][j], 0, 0, 0);
      }
    __builtin_amdgcn_s_setprio(0);
    __builtin_amdgcn_s_barrier();
    cur ^= 1;
  }

#pragma unroll
  for (int i = 0; i < 4; ++i) {
    int row0 = m0 + wm * 64 + i * 16 + (l >> 4) * 4;
#pragma unroll
    for (int j = 0; j < 4; ++j) {
      int col = n0 + wn * 64 + j * 16 + (l & 15);
      if constexpr (MODE == 1) {
        float* C = (float*)Cout;
#pragma unroll
        for (int r = 0; r < 4; ++r)
          C[(size_t)(row0 + r) * DM + col] = acc[i][j][r];
      }
    }
  }
}

// ---------------- RMSNorm + RoPE for K: sums split-K partials, emits fp16 ---
__global__ __launch_bounds__(256) void rmsrope_k_kernel(float* __restrict__ k,
                                                        const float* __restrict__ kp1,
                                                        _Float16* __restrict__ kf,
                                                        const float* __restrict__ cosb,
                                                        const float* __restrict__ sinb) {
  int w = threadIdx.x >> 6;
  int lane = threadIdx.x & 63;
  long r = (long)blockIdx.x * 4 + w;
  float* p = k + r * DH;
  const float* p1 = kp1 + r * DH;
  int s = (int)(r & (S_ - 1));
  float x1 = p[lane] + p1[lane];
  float x2 = p[lane + 64] + p1[lane + 64];
  float ss = fmaf(x1, x1, x2 * x2);
#pragma unroll
  for (int off = 32; off; off >>= 1) ss += __shfl_xor(ss, off);
  float rms = rsqrtf(ss * (1.0f / 128.0f) + 1e-6f);
  float n1 = x1 * rms, n2 = x2 * rms;
  float c = cosb[s * 64 + lane], sn = sinb[s * 64 + lane];
  float o1 = fmaf(n1, c, n2 * sn);
  float o2 = fmaf(-n1, sn, n2 * c);
  p[lane] = o1;
  p[lane + 64] = o2;
  kf[r * DH + lane] = (_Float16)o1;
  kf[r * DH + lane + 64] = (_Float16)o2;
}

// ---------------- RMSNorm + RoPE + gain for Q: emits fp16 scaled by ---------
// SC = (1/sqrt(128))*log2(e) so attn logits land in log2 domain. The uniform
// positive SC cancels exactly in selection's _normalize(mean @ proj).
__global__ __launch_bounds__(256) void rmsrope_q_kernel(const float* __restrict__ q,
                                                        _Float16* __restrict__ qf,
                                                        const float* __restrict__ cosb,
                                                        const float* __restrict__ sinb,
                                                        const float* __restrict__ qg) {
  const float SC = 0.12751743f;  // 1/sqrt(128) * log2(e)
  int w = threadIdx.x >> 6;
  int lane = threadIdx.x & 63;
  long r = (long)blockIdx.x * 4 + w;
  const float* p = q + r * DH;
  int s = (int)(r & (S_ - 1));
  int h = (int)((r >> 11) & (H_ - 1));
  float x1 = p[lane], x2 = p[lane + 64];
  float ss = fmaf(x1, x1, x2 * x2);
#pragma unroll
  for (int off = 32; off; off >>= 1) ss += __shfl_xor(ss, off);
  float rms = rsqrtf(ss * (1.0f / 128.0f) + 1e-6f);
  float n1 = x1 * rms, n2 = x2 * rms;
  float c = cosb[s * 64 + lane], sn = sinb[s * 64 + lane];
  float g = qg[h] * SC;
  float o1 = fmaf(n1, c, n2 * sn) * g;
  float o2 = fmaf(-n1, sn, n2 * c) * g;
  qf[r * DH + lane] = (_Float16)o1;
  qf[r * DH + lane + 64] = (_Float16)o2;
}

// ---------------- selection phase 1: q-mean partial sums (fp16 q) -----------
__global__ __launch_bounds__(256) void qmean_part_kernel(const _Float16* __restrict__ qf,
                                                         float* __restrict__ partial) {
  __shared__ float red[256];
  const int bh = blockIdx.x >> 4, chunk = blockIdx.x & 15;
  const int t = threadIdx.x;
  const int d = t & 127, half = t >> 7;
  const _Float16* qb = qf + ((size_t)bh * S_ + chunk * 128 + half * 64) * DH;
  float sum = 0.0f;
#pragma unroll 4
  for (int s = 0; s < 64; ++s) sum += (float)qb[(size_t)s * DH + d];
  red[t] = sum;
  __syncthreads();
  if (t < 128) partial[(size_t)blockIdx.x * 128 + t] = red[t] + red[t + 128];
}

// ---------------- selection phase 2: finish mean, project, normalize --------
__global__ void qproj_kernel(const float* __restrict__ partial,
                             const float* __restrict__ proj,
                             float* __restrict__ qp) {
  __shared__ float meanq[128];
  __shared__ float qps[32];
  __shared__ float nrm;
  const int bh = blockIdx.x, t = threadIdx.x;
  float s = 0.0f;
#pragma unroll
  for (int c = 0; c < 16; ++c) s += partial[((size_t)bh * 16 + c) * 128 + t];
  meanq[t] = s * (1.0f / 2048.0f);
  __syncthreads();
  if (t < 32) {
    float sum = 0.0f;
    for (int d = 0; d < 128; ++d) sum = fmaf(meanq[d], proj[d * 32 + t], sum);
    qps[t] = sum;
  }
  __syncthreads();
  if (t == 0) {
    float sum = 0.0f;
    for (int j = 0; j < 32; ++j) sum += qps[j] * qps[j];
    nrm = 1.0f / fmaxf(sqrtf(sum), 1e-12f);
  }
  __syncthreads();
  if (t < 32) qp[bh * 32 + t] = qps[t] * nrm;
}

// ---------------- selection phase 3: per-(bh,block) score ----------------
__global__ __launch_bounds__(256) void kscore_kernel(const float* __restrict__ k,
                                                     const float* __restrict__ proj,
                                                     const float* __restrict__ qp,
                                                     float* __restrict__ scores) {
  __shared__ float ps[128][32];
  __shared__ float kp[64][33];
  __shared__ float cent[33];
  __shared__ float nrm;
  const int bh = blockIdx.x >> 5, n = blockIdx.x & 31;
  const int t = threadIdx.x;
  for (int i = t; i < 4096; i += 256) ps[i >> 5][i & 31] = proj[i];
  const float* kn = k + ((size_t)bh * S_ + n * 64) * DH;
  __syncthreads();
  {
    int row = t >> 2, j0 = (t & 3) * 8;
    float accv[8];
#pragma unroll
    for (int jj = 0; jj < 8; ++jj) accv[jj] = 0.0f;
#pragma unroll 4
    for (int d = 0; d < 128; ++d) {
      float kv = kn[(size_t)row * DH + d];
#pragma unroll
      for (int jj = 0; jj < 8; ++jj) accv[jj] = fmaf(kv, ps[d][j0 + jj], accv[jj]);
    }
#pragma unroll
    for (int jj = 0; jj < 8; ++jj) kp[row][j0 + jj] = accv[jj];
  }
  __syncthreads();
  if (t < 64) {
    float sum = 0.0f;
    for (int j = 0; j < 32; ++j) sum += kp[t][j] * kp[t][j];
    float scl = 1.0f / fmaxf(sqrtf(sum), 1e-12f);
    for (int j = 0; j < 32; ++j) kp[t][j] *= scl;
  }
  __syncthreads();
  if (t < 32) {
    float sum = 0.0f;
    for (int r2 = 0; r2 < 64; ++r2) sum += kp[r2][t];
    cent[t] = sum * (1.0f / 64.0f);
  }
  __syncthreads();
  if (t == 0) {
    float sum = 0.0f;
    for (int j = 0; j < 32; ++j) sum += cent[j] * cent[j];
    nrm = 1.0f / fmaxf(sqrtf(sum), 1e-12f);
  }
  __syncthreads();
  if (t < 32) cent[t] *= nrm;
  __syncthreads();
  if (t < 64) {
    float dt = 0.0f;
    for (int j = 0; j < 32; ++j) dt = fmaf(kp[t][j], cent[j], dt);
#pragma unroll
    for (int off = 32; off; off >>= 1) dt = fminf(dt, __shfl_xor(dt, off));
    if (t == 0) {
      float radius = fminf(fmaxf(1.0f - dt, 0.0f), 1.0f);
      float dq = 0.0f;
      for (int j = 0; j < 32; ++j) dq = fmaf(qp[bh * 32 + j], cent[j], dq);
      scores[bh * 32 + n] = dq + radius;
    }
  }
}

// ---------------- selection phase 4: top-18 + sort ----------------
__global__ void topk_kernel(const float* __restrict__ scores, int* __restrict__ top_idx) {
  if (threadIdx.x != 0) return;
  const int bh = blockIdx.x;
  float sc[NBLK];
  for (int j = 0; j < NBLK; ++j) sc[j] = scores[bh * 32 + j];
  sc[NBLK - 2] = INFINITY;
  sc[NBLK - 1] = INFINITY;
  int chosen[NKEEP];
  bool used[NBLK];
  for (int j = 0; j < NBLK; ++j) used[j] = false;
  for (int kk = 0; kk < NKEEP; ++kk) {
    int best = -1;
    float bv = 0.0f;
    for (int j = 0; j < NBLK; ++j)
      if (!used[j] && (best < 0 || sc[j] > bv)) { bv = sc[j]; best = j; }
    used[best] = true;
    chosen[kk] = best;
  }
  for (int a = 1; a < NKEEP; ++a) {
    int v2 = chosen[a], b2 = a - 1;
    while (b2 >= 0 && chosen[b2] > v2) { chosen[b2 + 1] = chosen[b2]; --b2; }
    chosen[b2 + 1] = v2;
  }
  for (int a = 0; a < NKEEP; ++a) top_idx[bh * NKEEP + a] = chosen[a];
}

// ---------------- MFMA attention v7: fp16 q, exp2-domain softmax ------------
__global__ __launch_bounds__(256) void attn_mfma_kernel(const _Float16* __restrict__ qfp,
                                                        const _Float16* __restrict__ kf,
                                                        const _Float16* __restrict__ vt,
                                                        const int* __restrict__ top_idx,
                                                        _Float16* __restrict__ yf) {
  __shared__ char lds[74752];  // buf0 0..32K (K 16K|V 16K), buf1 32..64K, P 64K..
  const int bh = blockIdx.x >> 5;
  const int qt = blockIdx.x & 31;
  const int t = threadIdx.x, l = t & 63, w = t >> 6;
  const int lr = l & 15, lg = l >> 4;
  const float THR2 = 11.5415603f;  // 8 * log2(e)

  f16x8 qf[4];
  {
    const _Float16* qbase = qfp + ((size_t)(bh * S_ + qt * 64 + w * 16 + lr)) * DH + lg * 8;
#pragma unroll
    for (int dc = 0; dc < 4; ++dc)
      qf[dc] = *(const f16x8*)(qbase + dc * 32);
  }

  float m_[4] = {-INFINITY, -INFINITY, -INFINITY, -INFINITY};
  float ls[4] = {0.f, 0.f, 0.f, 0.f};
  f32x4 yacc[8];
#pragma unroll
  for (int dt = 0; dt < 8; ++dt) yacc[dt] = (f32x4){0.f, 0.f, 0.f, 0.f};

  char* Pw = lds + 65536 + w * 2304;  // per-wave P: [16 q][72 fp16]

  const _Float16* kb0 = kf + (size_t)bh * S_ * DH;
  const _Float16* vb0 = vt + (size_t)bh * DH * S_;
  const int* idxp = top_idx + bh * NKEEP;

  auto STAGE = [&](int blk, int c) {
    char* base = lds + c * 32768;
#pragma unroll
    for (int f0 = 0; f0 < 4; ++f0) {
      int f = w * 4 + f0;
      int kt = f >> 2, dc = f & 3;
      GLOAD16(kb0 + (size_t)(blk * 64 + kt * 16 + lr) * DH + dc * 32 + lg * 8,
              base + f * 1024);
      int K0 = f >> 3, dt = f & 7;
      GLOAD16(vb0 + (size_t)(dt * 16 + lr) * S_ + blk * 64 + K0 * 32 + lg * 8,
              base + 16384 + f * 1024);
    }
  };

  int cur = 0;
  STAGE(idxp[0], 0);

  for (int it = 0; it < NKEEP; ++it) {
    if (it + 1 < NKEEP) {
      STAGE(idxp[it + 1], cur ^ 1);
      asm volatile("s_waitcnt vmcnt(8)" ::: "memory");
    } else {
      asm volatile("s_waitcnt vmcnt(0)" ::: "memory");
    }
    __builtin_amdgcn_s_barrier();
    char* buf = lds + cur * 32768;

    f32x4 sacc[4];
#pragma unroll
    for (int kt = 0; kt < 4; ++kt) sacc[kt] = (f32x4){0.f, 0.f, 0.f, 0.f};
    __builtin_amdgcn_s_setprio(1);
#pragma unroll
    for (int kt = 0; kt < 4; ++kt)
#pragma unroll
      for (int dc = 0; dc < 4; ++dc) {
        f16x8 kfr = *(const f16x8*)(buf + (kt * 4 + dc) * 1024 + l * 16);
        sacc[kt] = __builtin_amdgcn_mfma_f32_16x16x32_f16(qf[dc], kfr, sacc[kt], 0, 0, 0);
      }
    __builtin_amdgcn_s_setprio(0);

    // per-row tile max (log2 domain; reduced over the row's 16 lanes)
    float mt[4];
#pragma unroll
    for (int r = 0; r < 4; ++r) {
      float mv = fmaxf(fmaxf(sacc[0][r], sacc[1][r]), fmaxf(sacc[2][r], sacc[3][r]));
#pragma unroll
      for (int off = 1; off < 16; off <<= 1) mv = fmaxf(mv, __shfl_xor(mv, off));
      mt[r] = mv;
    }
    float p[4][4];
    bool ok = (mt[0] <= m_[0] + THR2) && (mt[1] <= m_[1] + THR2) &&
              (mt[2] <= m_[2] + THR2) && (mt[3] <= m_[3] + THR2);
    if (__all(ok)) {
      // defer-max: keep old max, skip corr/rescale (P bounded by 2^THR2 = e^8)
#pragma unroll
      for (int r = 0; r < 4; ++r) {
        float rs = 0.f;
#pragma unroll
        for (int kt = 0; kt < 4; ++kt) {
          p[kt][r] = exp2f(sacc[kt][r] - m_[r]);
          rs += p[kt][r];
        }
#pragma unroll
        for (int off = 1; off < 16; off <<= 1) rs += __shfl_xor(rs, off);
        ls[r] += rs;
      }
    } else {
#pragma unroll
      for (int r = 0; r < 4; ++r) {
        float mn = fmaxf(m_[r], mt[r]);
        float corr = exp2f(m_[r] - mn);
        float rs = 0.f;
#pragma unroll
        for (int kt = 0; kt < 4; ++kt) {
          p[kt][r] = exp2f(sacc[kt][r] - mn);
          rs += p[kt][r];
        }
#pragma unroll
        for (int off = 1; off < 16; off <<= 1) rs += __shfl_xor(rs, off);
        ls[r] = ls[r] * corr + rs;
        m_[r] = mn;
#pragma unroll
        for (int dt = 0; dt < 8; ++dt) yacc[dt][r] *= corr;
      }
    }

#pragma unroll
    for (int kt = 0; kt < 4; ++kt)
#pragma unroll
      for (int r = 0; r < 4; ++r)
        *(_Float16*)(Pw + (lg * 4 + r) * 144 + (kt * 16 + lr) * 2) = (_Float16)p[kt][r];

    __builtin_amdgcn_s_setprio(1);
#pragma unroll
    for (int K0 = 0; K0 < 2; ++K0) {
      f16x8 pa = *(const f16x8*)(Pw + lr * 144 + K0 * 64 + lg * 16);
#pragma unroll
      for (int dt = 0; dt < 8; ++dt) {
        f16x8 vf = *(const f16x8*)(buf + 16384 + (K0 * 8 + dt) * 1024 + l * 16);
        yacc[dt] = __builtin_amdgcn_mfma_f32_16x16x32_f16(pa, vf, yacc[dt], 0, 0, 0);
      }
    }
    __builtin_amdgcn_s_setprio(0);

    __builtin_amdgcn_s_barrier();
    cur ^= 1;
  }

  const int b = bh >> 4, h = bh & (H_ - 1);
  float inv[4];
#pragma unroll
  for (int r = 0; r < 4; ++r) inv[r] = 1.0f / ls[r];
#pragma unroll
  for (int r = 0; r < 4; ++r) {
    int srow = qt * 64 + w * 16 + lg * 4 + r;
    size_t off0 = ((size_t)b * S_ + srow) * DM + h * DH + lr;
#pragma unroll
    for (int dt = 0; dt < 8; ++dt)
      yf[off0 + dt * 16] = (_Float16)(yacc[dt][r] * inv[r]);
  }
}

extern "C" void kernel_launch(void* const* d_in, const int* in_sizes, int n_in,
                              void* d_out, int out_size, void* d_ws, size_t ws_size,
                              hipStream_t stream) {
  const float* x  = (const float*)d_in[0];
  const float* Wq = (const float*)d_in[1];
  const float* Wk = (const float*)d_in[2];
  const float* Wv = (const float*)d_in[3];
  const float* Wo = (const float*)d_in[4];
  const float* qg = (const float*)d_in[5];
  float* out = (float*)d_out;

  const size_t NE = (size_t)BH * S_ * DH;   // 8388608 elements
  const size_t WE = (size_t)DM * DM;        // 4194304 elements per W
  char* p = (char*)d_ws;
  float* q_ws = (float*)p; p += NE * 4;     // kpart1 during k-GEMM, then q f32
  float* k_ws = (float*)p; p += NE * 4;     // kpart0 -> roped k f32
  unsigned short* xhi = (unsigned short*)p; p += NE * 2;  // -> yf16 after k-GEMM
  unsigned short* xlo = (unsigned short*)p; p += NE * 2;  // -> vt after k-GEMM
  _Float16* xf16 = (_Float16*)p; p += NE * 2;             // -> qf16 after qv-GEMM
  unsigned short* wkhi = (unsigned short*)p; p += WE * 2; // \ kf16 spans wkhi+wklo
  unsigned short* wklo = (unsigned short*)p; p += WE * 2; // / (both dead post k-GEMM)
  _Float16* wqv = (_Float16*)p; p += 2 * WE * 2;          // [Wq;Wv] fp16; -> wo
  float* cosb = (float*)p; p += (size_t)S_ * 64 * 4;
  float* sinb = (float*)p; p += (size_t)S_ * 64 * 4;
  float* projb = (float*)p; p += 4096 * 4;
  int* idxb = (int*)p; p += BH * NKEEP * 4;
  float* scores = (float*)p; p += BH * NBLK * 4;
  float* qpbuf = (float*)p; p += BH * 32 * 4;
  // aliases (each with size check, stream-ordered):
  float* qpart = cosb;                   // 262KB <= 1MB; writer after rmsrope_q
  float* kpart1 = q_ws;                  // NE f32 = NE f32; qv writes q after rmsrope_k
  _Float16* kf16 = (_Float16*)wkhi;      // NE fp16 = 16.8MB = wkhi+wklo (16.8MB), both dead
  _Float16* vt = (_Float16*)xlo;         // NE fp16 <= NE ushort; xlo dead after k-GEMM
  _Float16* yf16 = (_Float16*)xhi;       // NE fp16 <= NE ushort; xhi dead after k-GEMM
  _Float16* qf16 = xf16;                 // NE fp16 = NE fp16; xf16 dead after qv-GEMM
  _Float16* wo = wqv;                    // WE fp16 <= 2WE fp16; wqv dead after qv-GEMM
  // total ws use ~152 MB (proven footprint, no growth)

  const int nx4 = (int)(NE / 4);
  const int nw4 = (int)(WE / 4);

  proj_kernel<<<dim3(16), dim3(256), 0, stream>>>(projb);
  rope_table_kernel<<<dim3(S_), dim3(64), 0, stream>>>(cosb, sinb);
  split_x3_kernel<<<dim3(nx4 / 256), dim3(256), 0, stream>>>(x, xhi, xlo, xf16, nx4);
  split_w3_kernel<<<dim3(nw4 / 256), dim3(256), 0, stream>>>(Wk, Wq, Wv, wkhi, wklo,
                                                             wqv, wqv + WE, nw4);

  // k: bf16x3, split-K=2, 8-wave 256^2, 4-phase counted-vmcnt interleave
  mfma_gemm_k_sk<<<dim3(8, 16, 2), dim3(512), 0, stream>>>(xhi, xlo, wkhi, wklo,
                                                           k_ws, kpart1);

  // k finalize: sum partials + RMS + RoPE; writes k f32 (in place) + kf16
  rmsrope_k_kernel<<<dim3((BH * S_) / 4), dim3(256), 0, stream>>>(k_ws, kpart1, kf16, cosb, sinb);

  // q+V fused: fp16, 256^2 8-wave, 2-phase; overwrites kpart1 (=q_ws) — safe now
  mfma_gemm_qv<<<dim3(16, 16), dim3(512), 0, stream>>>(xf16, wqv, q_ws, vt);

  // q finalize: RMS + RoPE + gain, emits fp16 q scaled by scale*log2e
  // (overwrites xf16 region — dead after qv-GEMM, exactly NE fp16)
  rmsrope_q_kernel<<<dim3((BH * S_) / 4), dim3(256), 0, stream>>>(q_ws, qf16, cosb, sinb, qg);

  qmean_part_kernel<<<dim3(BH * 16), dim3(256), 0, stream>>>(qf16, qpart);
  qproj_kernel<<<dim3(BH), dim3(128), 0, stream>>>(qpart, projb, qpbuf);
  kscore_kernel<<<dim3(BH * NBLK), dim3(256), 0, stream>>>(k_ws, projb, qpbuf, scores);
  topk_kernel<<<dim3(BH), dim3(64), 0, stream>>>(scores, idxb);

  // attn v7: fp16 q, exp2 softmax, 4-wave blocks, defer-max
  attn_mfma_kernel<<<dim3(BH * 32), dim3(256), 0, stream>>>(qf16, kf16, vt, idxb, yf16);

  // O: fp16 x1 on yf16 and Wo-f16 (wo overwrites Wq-fp16 region — dead)
  split_f16_kernel<<<dim3(nw4 / 256), dim3(256), 0, stream>>>(Wo, wo, nw4);
  mfma_gemm_f16<1><<<dim3(16, 32), dim3(256), 0, stream>>>(yf16, wo, out);
}

// Round 18
// 430.080 us; speedup vs baseline: 1.0402x; 1.0402x over previous
//
#include <hip/hip_runtime.h>
#include <hip/hip_bf16.h>

#define B_ 2
#define S_ 2048
#define DM 2048
#define H_ 16
#define DH 128
#define NBLK 32
#define NKEEP 18
#define BH (B_ * H_)

typedef __attribute__((ext_vector_type(8))) short short8;
typedef __attribute__((ext_vector_type(8))) _Float16 f16x8;
typedef __attribute__((ext_vector_type(4))) _Float16 f16x4;
typedef __attribute__((ext_vector_type(4))) float f32x4;

#define GLOAD16(gp, lp)                                                        \
  __builtin_amdgcn_global_load_lds(                                            \
      (const __attribute__((address_space(1))) unsigned int*)(const void*)(gp),\
      (__attribute__((address_space(3))) unsigned int*)(void*)(lp), 16, 0, 0)

__device__ __forceinline__ unsigned short f32_to_bf16(float f) {
  unsigned u = __float_as_uint(f);
  unsigned r = (u + 0x7fffu + ((u >> 16) & 1u)) >> 16;
  return (unsigned short)r;
}
__device__ __forceinline__ float bf16_to_f32(unsigned short h) {
  return __uint_as_float(((unsigned)h) << 16);
}
// raw HW 2^x (logits pre-scaled into log2 domain); no libm fixup code
__device__ __forceinline__ float fexp2(float x) {
  float r;
  asm("v_exp_f32 %0, %1" : "=v"(r) : "v"(x));
  return r;
}

// ---------------- proj: threefry2x32 (partitionable) + erfinv ----------------
__device__ __forceinline__ unsigned rotl32(unsigned x, int r) {
  return (x << r) | (x >> (32 - r));
}

__device__ __forceinline__ float erfinv_f32(float x) {
  float w = -log1pf(-x * x);
  float p;
  if (w < 5.0f) {
    w -= 2.5f;
    p = 2.81022636e-08f;
    p = fmaf(p, w, 3.43273939e-07f);
    p = fmaf(p, w, -3.5233877e-06f);
    p = fmaf(p, w, -4.39150654e-06f);
    p = fmaf(p, w, 0.00021858087f);
    p = fmaf(p, w, -0.00125372503f);
    p = fmaf(p, w, -0.00417768164f);
    p = fmaf(p, w, 0.246640727f);
    p = fmaf(p, w, 1.50140941f);
  } else {
    w = sqrtf(w) - 3.0f;
    p = -0.000200214257f;
    p = fmaf(p, w, 0.000100950558f);
    p = fmaf(p, w, 0.00134934322f);
    p = fmaf(p, w, -0.00367342844f);
    p = fmaf(p, w, 0.00573950773f);
    p = fmaf(p, w, -0.0076224613f);
    p = fmaf(p, w, 0.00943887047f);
    p = fmaf(p, w, 1.00167406f);
    p = fmaf(p, w, 2.83297682f);
  }
  return p * x;
}

__device__ __forceinline__ float bits_to_normal(unsigned b) {
  float f = __uint_as_float((b >> 9) | 0x3f800000u) - 1.0f;
  const float lo = -0.9999999403953552f;
  float u = fmaxf(lo, fmaf(f, 2.0f, lo));
  return 1.4142135623730951f * erfinv_f32(u);
}

__global__ void proj_kernel(float* __restrict__ proj) {
  int i = blockIdx.x * blockDim.x + threadIdx.x;
  if (i >= 4096) return;
  unsigned k0 = 0u, k1 = 42u;
  unsigned k2 = 0x1BD11BDAu ^ k0 ^ k1;
  unsigned x0 = 0u, x1 = (unsigned)i;
  x0 += k0; x1 += k1;
#define QR(r) { x0 += x1; x1 = rotl32(x1, r); x1 ^= x0; }
  QR(13) QR(15) QR(26) QR(6)   x0 += k1; x1 += k2 + 1u;
  QR(17) QR(29) QR(16) QR(24)  x0 += k2; x1 += k0 + 2u;
  QR(13) QR(15) QR(26) QR(6)   x0 += k0; x1 += k1 + 3u;
  QR(17) QR(29) QR(16) QR(24)  x0 += k1; x1 += k2 + 4u;
  QR(13) QR(15) QR(26) QR(6)   x0 += k2; x1 += k0 + 5u;
#undef QR
  proj[i] = bits_to_normal(x0 ^ x1) / 5.656854249492381f;
}

// ---------------- RoPE tables ----------------
__global__ void rope_table_kernel(float* __restrict__ cosb, float* __restrict__ sinb) {
  int s = blockIdx.x;
  int j = threadIdx.x;
  double e = (double)(2 * j) / 128.0;
  double invf = 1.0 / pow(10000.0, e);
  float freq = (float)s * (float)invf;
  cosb[s * 64 + j] = (float)cos((double)freq);
  sinb[s * 64 + j] = (float)sin((double)freq);
}

// ---------------- x -> bf16 hi/lo + fp16, single pass ----------------
__global__ __launch_bounds__(256) void split_x3_kernel(const float* __restrict__ in,
                                                       unsigned short* __restrict__ hi,
                                                       unsigned short* __restrict__ lo,
                                                       _Float16* __restrict__ f16,
                                                       int n4) {
  int i = blockIdx.x * blockDim.x + threadIdx.x;
  if (i >= n4) return;
  float4 v = ((const float4*)in)[i];
  ushort4 hv, lv;
  f16x4 fv;
  hv.x = f32_to_bf16(v.x); lv.x = f32_to_bf16(v.x - bf16_to_f32(hv.x)); fv[0] = (_Float16)v.x;
  hv.y = f32_to_bf16(v.y); lv.y = f32_to_bf16(v.y - bf16_to_f32(hv.y)); fv[1] = (_Float16)v.y;
  hv.z = f32_to_bf16(v.z); lv.z = f32_to_bf16(v.z - bf16_to_f32(hv.z)); fv[2] = (_Float16)v.z;
  hv.w = f32_to_bf16(v.w); lv.w = f32_to_bf16(v.w - bf16_to_f32(hv.w)); fv[3] = (_Float16)v.w;
  ((ushort4*)hi)[i] = hv;
  ((ushort4*)lo)[i] = lv;
  ((f16x4*)f16)[i] = fv;
}

// ---------------- fused W split: Wk -> bf16 hi/lo; Wq, Wv -> fp16 ----------
__global__ __launch_bounds__(256) void split_w3_kernel(const float* __restrict__ wk,
                                                       const float* __restrict__ wq,
                                                       const float* __restrict__ wv,
                                                       unsigned short* __restrict__ khi,
                                                       unsigned short* __restrict__ klo,
                                                       _Float16* __restrict__ qf,
                                                       _Float16* __restrict__ vf,
                                                       int n4) {
  int i = blockIdx.x * blockDim.x + threadIdx.x;
  if (i >= n4) return;
  {
    float4 v = ((const float4*)wk)[i];
    ushort4 hv, lv;
    hv.x = f32_to_bf16(v.x); lv.x = f32_to_bf16(v.x - bf16_to_f32(hv.x));
    hv.y = f32_to_bf16(v.y); lv.y = f32_to_bf16(v.y - bf16_to_f32(hv.y));
    hv.z = f32_to_bf16(v.z); lv.z = f32_to_bf16(v.z - bf16_to_f32(hv.z));
    hv.w = f32_to_bf16(v.w); lv.w = f32_to_bf16(v.w - bf16_to_f32(hv.w));
    ((ushort4*)khi)[i] = hv;
    ((ushort4*)klo)[i] = lv;
  }
  {
    float4 v = ((const float4*)wq)[i];
    f16x4 fv;
    fv[0] = (_Float16)v.x; fv[1] = (_Float16)v.y;
    fv[2] = (_Float16)v.z; fv[3] = (_Float16)v.w;
    ((f16x4*)qf)[i] = fv;
  }
  {
    float4 v = ((const float4*)wv)[i];
    f16x4 fv;
    fv[0] = (_Float16)v.x; fv[1] = (_Float16)v.y;
    fv[2] = (_Float16)v.z; fv[3] = (_Float16)v.w;
    ((f16x4*)vf)[i] = fv;
  }
}

// ---------------- W -> fp16 (Wo, late) ----------------
__global__ __launch_bounds__(256) void split_f16_kernel(const float* __restrict__ in,
                                                        _Float16* __restrict__ f16,
                                                        int n4) {
  int i = blockIdx.x * blockDim.x + threadIdx.x;
  if (i >= n4) return;
  float4 v = ((const float4*)in)[i];
  f16x4 fv;
  fv[0] = (_Float16)v.x; fv[1] = (_Float16)v.y;
  fv[2] = (_Float16)v.z; fv[3] = (_Float16)v.w;
  ((f16x4*)f16)[i] = fv;
}

// ---------------- k-GEMM: bf16x3, 256x256, 8 waves, SPLIT-K=2, 4-phase ------
__global__ __launch_bounds__(512, 2) void mfma_gemm_k_sk(const unsigned short* __restrict__ Ahi,
                                                         const unsigned short* __restrict__ Alo,
                                                         const unsigned short* __restrict__ Whi,
                                                         const unsigned short* __restrict__ Wlo,
                                                         float* __restrict__ kp0,
                                                         float* __restrict__ kp1) {
  __shared__ char smem[131072];  // 2 buf x 64K: Ahi 0|Alo 16K|Bhi 32K|Blo 48K
  const int t = threadIdx.x, l = t & 63, w = t >> 6;  // 8 waves
  const int lin = blockIdx.z * 128 + blockIdx.y * 8 + blockIdx.x;
  const int swz = (lin & 7) * 32 + (lin >> 3);        // 256 blocks, bijective
  const int kz = swz >> 7;
  const int idx = swz & 127;
  const int n0 = (idx & 7) * 256;
  const int m0 = (idx >> 3) * 256;
  const int kbase = kz * 1024;
  float* C = kz ? kp1 : kp0;
  const int wm = w >> 2, wn = w & 3;                  // 2M x 4N wave grid
  const int lr = l & 15;
  const int lg8 = (l >> 4) * 8;
  const size_t rstep = (size_t)16 * DM;

  const unsigned short* gAh = Ahi + (size_t)(m0 + w * 32 + lr) * DM + lg8;
  const unsigned short* gAl = Alo + (size_t)(m0 + w * 32 + lr) * DM + lg8;
  const unsigned short* gBh = Whi + (size_t)(n0 + w * 32 + lr) * DM + lg8;
  const unsigned short* gBl = Wlo + (size_t)(n0 + w * 32 + lr) * DM + lg8;

  f32x4 acc[8][4];
#pragma unroll
  for (int i = 0; i < 8; ++i)
#pragma unroll
    for (int j = 0; j < 4; ++j) acc[i][j] = (f32x4){0.f, 0.f, 0.f, 0.f};

  {  // prologue: full stage of tile 0 into buf 0
    char* base = smem + w * 2048;
    GLOAD16(gAh + kbase, base);
    GLOAD16(gAh + rstep + kbase, base + 1024);
    GLOAD16(gAl + kbase, base + 16384);
    GLOAD16(gAl + rstep + kbase, base + 16384 + 1024);
    GLOAD16(gBh + kbase, base + 32768);
    GLOAD16(gBh + rstep + kbase, base + 32768 + 1024);
    GLOAD16(gBl + kbase, base + 49152);
    GLOAD16(gBl + rstep + kbase, base + 49152 + 1024);
  }
  int cur = 0;

#define KQUAD(q)                                                                        \
  {                                                                                     \
    short8 ah0 = *(const short8*)(buf + (wm * 8 + 2 * (q)) * 1024 + l * 16);            \
    short8 ah1 = *(const short8*)(buf + (wm * 8 + 2 * (q) + 1) * 1024 + l * 16);        \
    short8 al0 = *(const short8*)(buf + 16384 + (wm * 8 + 2 * (q)) * 1024 + l * 16);    \
    short8 al1 = *(const short8*)(buf + 16384 + (wm * 8 + 2 * (q) + 1) * 1024 + l * 16);\
    __builtin_amdgcn_s_setprio(1);                                                      \
    _Pragma("unroll")                                                                   \
    for (int n = 0; n < 4; ++n) {                                                       \
      acc[2 * (q)][n] = __builtin_amdgcn_mfma_f32_16x16x32_bf16(ah0, bh[n], acc[2 * (q)][n], 0, 0, 0); \
      acc[2 * (q)][n] = __builtin_amdgcn_mfma_f32_16x16x32_bf16(ah0, bl[n], acc[2 * (q)][n], 0, 0, 0); \
      acc[2 * (q)][n] = __builtin_amdgcn_mfma_f32_16x16x32_bf16(al0, bh[n], acc[2 * (q)][n], 0, 0, 0); \
    }                                                                                   \
    _Pragma("unroll")                                                                   \
    for (int n = 0; n < 4; ++n) {                                                       \
      acc[2 * (q) + 1][n] = __builtin_amdgcn_mfma_f32_16x16x32_bf16(ah1, bh[n], acc[2 * (q) + 1][n], 0, 0, 0); \
      acc[2 * (q) + 1][n] = __builtin_amdgcn_mfma_f32_16x16x32_bf16(ah1, bl[n], acc[2 * (q) + 1][n], 0, 0, 0); \
      acc[2 * (q) + 1][n] = __builtin_amdgcn_mfma_f32_16x16x32_bf16(al1, bh[n], acc[2 * (q) + 1][n], 0, 0, 0); \
    }                                                                                   \
    __builtin_amdgcn_s_setprio(0);                                                      \
  }

  for (int k0 = kbase; k0 < kbase + 1024; k0 += 32) {
    const bool more = (k0 + 32 < kbase + 1024);
    char* buf = smem + cur * 65536;
    char* nb = smem + (cur ^ 1) * 65536 + w * 2048;
    const int kn = k0 + 32;

    if (more) {
      GLOAD16(gBh + kn, nb + 32768);
      GLOAD16(gBh + rstep + kn, nb + 32768 + 1024);
      asm volatile("s_waitcnt vmcnt(2)" ::: "memory");
    } else {
      asm volatile("s_waitcnt vmcnt(0)" ::: "memory");
    }
    __builtin_amdgcn_s_barrier();

    short8 bh[4], bl[4];
#pragma unroll
    for (int f = 0; f < 4; ++f) {
      bh[f] = *(const short8*)(buf + 32768 + (wn * 4 + f) * 1024 + l * 16);
      bl[f] = *(const short8*)(buf + 49152 + (wn * 4 + f) * 1024 + l * 16);
    }
    KQUAD(0);
    __builtin_amdgcn_s_barrier();

    if (more) {
      GLOAD16(gBl + kn, nb + 49152);
      GLOAD16(gBl + rstep + kn, nb + 49152 + 1024);
    }
    KQUAD(1);
    __builtin_amdgcn_s_barrier();

    if (more) {
      GLOAD16(gAh + kn, nb);
      GLOAD16(gAh + rstep + kn, nb + 1024);
    }
    KQUAD(2);
    __builtin_amdgcn_s_barrier();

    if (more) {
      GLOAD16(gAl + kn, nb + 16384);
      GLOAD16(gAl + rstep + kn, nb + 16384 + 1024);
    }
    KQUAD(3);
    __builtin_amdgcn_s_barrier();

    cur ^= 1;
  }
#undef KQUAD

#pragma unroll
  for (int m = 0; m < 8; ++m) {
    int row0 = m0 + wm * 128 + m * 16 + (l >> 4) * 4;
#pragma unroll
    for (int n = 0; n < 4; ++n) {
      int col = n0 + wn * 64 + n * 16 + (l & 15);
      int h = col >> 7, d = col & 127;
#pragma unroll
      for (int r = 0; r < 4; ++r) {
        int mm = row0 + r;
        int b = mm >> 11, s = mm & (S_ - 1);
        C[(((size_t)(b * H_ + h) * S_) + s) * DH + d] = acc[m][n][r];
      }
    }
  }
}

// ---------------- fused q+V fp16 GEMM: 256x256, 8 waves, 2-phase ------------
__global__ __launch_bounds__(512, 2) void mfma_gemm_qv(const _Float16* __restrict__ A,
                                                       const _Float16* __restrict__ W,
                                                       float* __restrict__ Cq,
                                                       _Float16* __restrict__ vt) {
  __shared__ char smem[65536];  // 2 buf x 32K: A frags 0..16K | B frags 16..32K
  const int t = threadIdx.x, l = t & 63, w = t >> 6;  // 8 waves
  const int lin = blockIdx.y * gridDim.x + blockIdx.x;
  const int swz = (lin & 7) * 32 + (lin >> 3);        // 256 blocks, bijective
  const int n0 = (swz & 15) * 256;
  const int m0 = (swz >> 4) * 256;
  const int wm = w >> 2, wn = w & 3;                  // 2M x 4N wave grid
  const int lr = l & 15;
  const int lg8 = (l >> 4) * 8;
  const size_t rstep = (size_t)16 * DM;

  const _Float16* gA = A + (size_t)(m0 + w * 32 + lr) * DM + lg8;
  const _Float16* gB = W + (size_t)(n0 + w * 32 + lr) * DM + lg8;

  f32x4 acc[8][4];
#pragma unroll
  for (int i = 0; i < 8; ++i)
#pragma unroll
    for (int j = 0; j < 4; ++j) acc[i][j] = (f32x4){0.f, 0.f, 0.f, 0.f};

  {  // prologue
    char* base = smem + w * 2048;
    GLOAD16(gA, base);
    GLOAD16(gA + rstep, base + 1024);
    GLOAD16(gB, base + 16384);
    GLOAD16(gB + rstep, base + 16384 + 1024);
  }
  int cur = 0;

  for (int k0 = 0; k0 < DM; k0 += 32) {
    const bool more = (k0 + 32 < DM);
    char* buf = smem + cur * 32768;
    char* nb = smem + (cur ^ 1) * 32768 + w * 2048;
    const int kn = k0 + 32;

    if (more) {
      GLOAD16(gA + kn, nb);
      GLOAD16(gA + rstep + kn, nb + 1024);
      asm volatile("s_waitcnt vmcnt(2)" ::: "memory");
    } else {
      asm volatile("s_waitcnt vmcnt(0)" ::: "memory");
    }
    __builtin_amdgcn_s_barrier();

    f16x8 b[4];
#pragma unroll
    for (int j = 0; j < 4; ++j)
      b[j] = *(const f16x8*)(buf + 16384 + (wn * 4 + j) * 1024 + l * 16);
    __builtin_amdgcn_s_setprio(1);
#pragma unroll
    for (int i = 0; i < 4; ++i) {
      f16x8 a = *(const f16x8*)(buf + (wm * 8 + i) * 1024 + l * 16);
#pragma unroll
      for (int j = 0; j < 4; ++j)
        acc[i][j] = __builtin_amdgcn_mfma_f32_16x16x32_f16(a, b[j], acc[i][j], 0, 0, 0);
    }
    __builtin_amdgcn_s_setprio(0);
    __builtin_amdgcn_s_barrier();

    if (more) {
      GLOAD16(gB + kn, nb + 16384);
      GLOAD16(gB + rstep + kn, nb + 16384 + 1024);
    }
    __builtin_amdgcn_s_setprio(1);
#pragma unroll
    for (int i = 4; i < 8; ++i) {
      f16x8 a = *(const f16x8*)(buf + (wm * 8 + i) * 1024 + l * 16);
#pragma unroll
      for (int j = 0; j < 4; ++j)
        acc[i][j] = __builtin_amdgcn_mfma_f32_16x16x32_f16(a, b[j], acc[i][j], 0, 0, 0);
    }
    __builtin_amdgcn_s_setprio(0);
    __builtin_amdgcn_s_barrier();

    cur ^= 1;
  }

#pragma unroll
  for (int m = 0; m < 8; ++m) {
    int row0 = m0 + wm * 128 + m * 16 + (l >> 4) * 4;
#pragma unroll
    for (int n = 0; n < 4; ++n) {
      int col = n0 + wn * 64 + n * 16 + (l & 15);
      if (col < DM) {
        int h = col >> 7, d = col & 127;
#pragma unroll
        for (int r = 0; r < 4; ++r) {
          int mm = row0 + r;
          int b2 = mm >> 11, s = mm & (S_ - 1);
          Cq[(((size_t)(b2 * H_ + h) * S_) + s) * DH + d] = acc[m][n][r];
        }
      } else {
        int vcol = col - DM;
        int h = vcol >> 7, d = vcol & 127;
        int b2 = row0 >> 11, s0 = row0 & (S_ - 1);
        f16x4 vv;
        vv[0] = (_Float16)acc[m][n][0];
        vv[1] = (_Float16)acc[m][n][1];
        vv[2] = (_Float16)acc[m][n][2];
        vv[3] = (_Float16)acc[m][n][3];
        *(f16x4*)(vt + (((size_t)(b2 * H_ + h)) * DH + d) * S_ + s0) = vv;
      }
    }
  }
}

// ---------------- fp16 single-product GEMM (O), BK=64, 128x128 --------------
template <int MODE>
__global__ __launch_bounds__(256) void mfma_gemm_f16(const _Float16* __restrict__ A,
                                                     const _Float16* __restrict__ W,
                                                     void* __restrict__ Cout) {
  __shared__ char smem[65536];
  const int t = threadIdx.x, l = t & 63, w = t >> 6;
  const int lin = blockIdx.y * gridDim.x + blockIdx.x;
  const int cpx = (gridDim.x * gridDim.y) >> 3;
  const int swz = (lin & 7) * cpx + (lin >> 3);
  const int n0 = (swz % gridDim.x) * 128;
  const int m0 = (swz / gridDim.x) * 128;
  const int wm = w >> 1, wn = w & 1;
  const int lr = l & 15;
  const int lg8 = (l >> 4) * 8;

  auto STAGE = [&](int k0, int c) {
    char* base = smem + c * 32768;
#pragma unroll
    for (int f0 = 0; f0 < 4; ++f0) {
      int f = w * 4 + f0;
      int rb = f >> 1, kh = f & 1;
      GLOAD16(A + (size_t)(m0 + rb * 16 + lr) * DM + k0 + kh * 32 + lg8,
              base + f * 1024);
      GLOAD16(W + (size_t)(n0 + rb * 16 + lr) * DM + k0 + kh * 32 + lg8,
              base + 16384 + f * 1024);
    }
  };

  f32x4 acc[4][4];
#pragma unroll
  for (int i = 0; i < 4; ++i)
#pragma unroll
    for (int j = 0; j < 4; ++j) acc[i][j] = (f32x4){0.f, 0.f, 0.f, 0.f};

  STAGE(0, 0);
  int cur = 0;

  for (int k0 = 0; k0 < DM; k0 += 64) {
    if (k0 + 64 < DM) {
      STAGE(k0 + 64, cur ^ 1);
      asm volatile("s_waitcnt vmcnt(8)" ::: "memory");
    } else {
      asm volatile("s_waitcnt vmcnt(0)" ::: "memory");
    }
    __builtin_amdgcn_s_barrier();

    char* buf = smem + cur * 32768;
    f16x8 a[4][2], b[4][2];
#pragma unroll
    for (int i = 0; i < 4; ++i)
#pragma unroll
      for (int kh = 0; kh < 2; ++kh) {
        a[i][kh] = *(const f16x8*)(buf + ((wm * 4 + i) * 2 + kh) * 1024 + l * 16);
        b[i][kh] = *(const f16x8*)(buf + 16384 + ((wn * 4 + i) * 2 + kh) * 1024 + l * 16);
      }
    __builtin_amdgcn_s_setprio(1);
#pragma unroll
    for (int i = 0; i < 4; ++i)
#pragma unroll
      for (int j = 0; j < 4; ++j) {
        acc[i][j] = __builtin_amdgcn_mfma_f32_16x16x32_f16(a[i][0], b[j][0], acc[i][j], 0, 0, 0);
        acc[i][j] = __builtin_amdgcn_mfma_f32_16x16x32_f16(a[i][1], b[j][1], acc[i][j], 0, 0, 0);
      }
    __builtin_amdgcn_s_setprio(0);
    __builtin_amdgcn_s_barrier();
    cur ^= 1;
  }

#pragma unroll
  for (int i = 0; i < 4; ++i) {
    int row0 = m0 + wm * 64 + i * 16 + (l >> 4) * 4;
#pragma unroll
    for (int j = 0; j < 4; ++j) {
      int col = n0 + wn * 64 + j * 16 + (l & 15);
      if constexpr (MODE == 1) {
        float* C = (float*)Cout;
#pragma unroll
        for (int r = 0; r < 4; ++r)
          C[(size_t)(row0 + r) * DM + col] = acc[i][j][r];
      }
    }
  }
}

// ---------------- RMSNorm + RoPE for K: sums split-K partials, emits fp16 ---
__global__ __launch_bounds__(256) void rmsrope_k_kernel(float* __restrict__ k,
                                                        const float* __restrict__ kp1,
                                                        _Float16* __restrict__ kf,
                                                        const float* __restrict__ cosb,
                                                        const float* __restrict__ sinb) {
  int w = threadIdx.x >> 6;
  int lane = threadIdx.x & 63;
  long r = (long)blockIdx.x * 4 + w;
  float* p = k + r * DH;
  const float* p1 = kp1 + r * DH;
  int s = (int)(r & (S_ - 1));
  float x1 = p[lane] + p1[lane];
  float x2 = p[lane + 64] + p1[lane + 64];
  float ss = fmaf(x1, x1, x2 * x2);
#pragma unroll
  for (int off = 32; off; off >>= 1) ss += __shfl_xor(ss, off);
  float rms = rsqrtf(ss * (1.0f / 128.0f) + 1e-6f);
  float n1 = x1 * rms, n2 = x2 * rms;
  float c = cosb[s * 64 + lane], sn = sinb[s * 64 + lane];
  float o1 = fmaf(n1, c, n2 * sn);
  float o2 = fmaf(-n1, sn, n2 * c);
  p[lane] = o1;
  p[lane + 64] = o2;
  kf[r * DH + lane] = (_Float16)o1;
  kf[r * DH + lane + 64] = (_Float16)o2;
}

// ---------------- RMSNorm + RoPE + gain for Q: emits fp16 scaled by ---------
// SC = (1/sqrt(128))*log2(e) so attn logits land in log2 domain. The uniform
// positive SC cancels exactly in selection's _normalize(mean @ proj).
__global__ __launch_bounds__(256) void rmsrope_q_kernel(const float* __restrict__ q,
                                                        _Float16* __restrict__ qf,
                                                        const float* __restrict__ cosb,
                                                        const float* __restrict__ sinb,
                                                        const float* __restrict__ qg) {
  const float SC = 0.12751743f;  // 1/sqrt(128) * log2(e)
  int w = threadIdx.x >> 6;
  int lane = threadIdx.x & 63;
  long r = (long)blockIdx.x * 4 + w;
  const float* p = q + r * DH;
  int s = (int)(r & (S_ - 1));
  int h = (int)((r >> 11) & (H_ - 1));
  float x1 = p[lane], x2 = p[lane + 64];
  float ss = fmaf(x1, x1, x2 * x2);
#pragma unroll
  for (int off = 32; off; off >>= 1) ss += __shfl_xor(ss, off);
  float rms = rsqrtf(ss * (1.0f / 128.0f) + 1e-6f);
  float n1 = x1 * rms, n2 = x2 * rms;
  float c = cosb[s * 64 + lane], sn = sinb[s * 64 + lane];
  float g = qg[h] * SC;
  float o1 = fmaf(n1, c, n2 * sn) * g;
  float o2 = fmaf(-n1, sn, n2 * c) * g;
  qf[r * DH + lane] = (_Float16)o1;
  qf[r * DH + lane + 64] = (_Float16)o2;
}

// ---------------- selection phase 1: q-mean partial sums (fp16 q) -----------
__global__ __launch_bounds__(256) void qmean_part_kernel(const _Float16* __restrict__ qf,
                                                         float* __restrict__ partial) {
  __shared__ float red[256];
  const int bh = blockIdx.x >> 4, chunk = blockIdx.x & 15;
  const int t = threadIdx.x;
  const int d = t & 127, half = t >> 7;
  const _Float16* qb = qf + ((size_t)bh * S_ + chunk * 128 + half * 64) * DH;
  float sum = 0.0f;
#pragma unroll 4
  for (int s = 0; s < 64; ++s) sum += (float)qb[(size_t)s * DH + d];
  red[t] = sum;
  __syncthreads();
  if (t < 128) partial[(size_t)blockIdx.x * 128 + t] = red[t] + red[t + 128];
}

// ---------------- selection phase 2: finish mean, project, normalize --------
__global__ void qproj_kernel(const float* __restrict__ partial,
                             const float* __restrict__ proj,
                             float* __restrict__ qp) {
  __shared__ float meanq[128];
  __shared__ float qps[32];
  __shared__ float nrm;
  const int bh = blockIdx.x, t = threadIdx.x;
  float s = 0.0f;
#pragma unroll
  for (int c = 0; c < 16; ++c) s += partial[((size_t)bh * 16 + c) * 128 + t];
  meanq[t] = s * (1.0f / 2048.0f);
  __syncthreads();
  if (t < 32) {
    float sum = 0.0f;
    for (int d = 0; d < 128; ++d) sum = fmaf(meanq[d], proj[d * 32 + t], sum);
    qps[t] = sum;
  }
  __syncthreads();
  if (t == 0) {
    float sum = 0.0f;
    for (int j = 0; j < 32; ++j) sum += qps[j] * qps[j];
    nrm = 1.0f / fmaxf(sqrtf(sum), 1e-12f);
  }
  __syncthreads();
  if (t < 32) qp[bh * 32 + t] = qps[t] * nrm;
}

// ---------------- selection phase 3: per-(bh,block) score ----------------
__global__ __launch_bounds__(256) void kscore_kernel(const float* __restrict__ k,
                                                     const float* __restrict__ proj,
                                                     const float* __restrict__ qp,
                                                     float* __restrict__ scores) {
  __shared__ float ps[128][32];
  __shared__ float kp[64][33];
  __shared__ float cent[33];
  __shared__ float nrm;
  const int bh = blockIdx.x >> 5, n = blockIdx.x & 31;
  const int t = threadIdx.x;
  for (int i = t; i < 4096; i += 256) ps[i >> 5][i & 31] = proj[i];
  const float* kn = k + ((size_t)bh * S_ + n * 64) * DH;
  __syncthreads();
  {
    int row = t >> 2, j0 = (t & 3) * 8;
    float accv[8];
#pragma unroll
    for (int jj = 0; jj < 8; ++jj) accv[jj] = 0.0f;
#pragma unroll 4
    for (int d = 0; d < 128; ++d) {
      float kv = kn[(size_t)row * DH + d];
#pragma unroll
      for (int jj = 0; jj < 8; ++jj) accv[jj] = fmaf(kv, ps[d][j0 + jj], accv[jj]);
    }
#pragma unroll
    for (int jj = 0; jj < 8; ++jj) kp[row][j0 + jj] = accv[jj];
  }
  __syncthreads();
  if (t < 64) {
    float sum = 0.0f;
    for (int j = 0; j < 32; ++j) sum += kp[t][j] * kp[t][j];
    float scl = 1.0f / fmaxf(sqrtf(sum), 1e-12f);
    for (int j = 0; j < 32; ++j) kp[t][j] *= scl;
  }
  __syncthreads();
  if (t < 32) {
    float sum = 0.0f;
    for (int r2 = 0; r2 < 64; ++r2) sum += kp[r2][t];
    cent[t] = sum * (1.0f / 64.0f);
  }
  __syncthreads();
  if (t == 0) {
    float sum = 0.0f;
    for (int j = 0; j < 32; ++j) sum += cent[j] * cent[j];
    nrm = 1.0f / fmaxf(sqrtf(sum), 1e-12f);
  }
  __syncthreads();
  if (t < 32) cent[t] *= nrm;
  __syncthreads();
  if (t < 64) {
    float dt = 0.0f;
    for (int j = 0; j < 32; ++j) dt = fmaf(kp[t][j], cent[j], dt);
#pragma unroll
    for (int off = 32; off; off >>= 1) dt = fminf(dt, __shfl_xor(dt, off));
    if (t == 0) {
      float radius = fminf(fmaxf(1.0f - dt, 0.0f), 1.0f);
      float dq = 0.0f;
      for (int j = 0; j < 32; ++j) dq = fmaf(qp[bh * 32 + j], cent[j], dq);
      scores[bh * 32 + n] = dq + radius;
    }
  }
}

// ---------------- selection phase 4: top-18 + sort ----------------
__global__ void topk_kernel(const float* __restrict__ scores, int* __restrict__ top_idx) {
  if (threadIdx.x != 0) return;
  const int bh = blockIdx.x;
  float sc[NBLK];
  for (int j = 0; j < NBLK; ++j) sc[j] = scores[bh * 32 + j];
  sc[NBLK - 2] = INFINITY;
  sc[NBLK - 1] = INFINITY;
  int chosen[NKEEP];
  bool used[NBLK];
  for (int j = 0; j < NBLK; ++j) used[j] = false;
  for (int kk = 0; kk < NKEEP; ++kk) {
    int best = -1;
    float bv = 0.0f;
    for (int j = 0; j < NBLK; ++j)
      if (!used[j] && (best < 0 || sc[j] > bv)) { bv = sc[j]; best = j; }
    used[best] = true;
    chosen[kk] = best;
  }
  for (int a = 1; a < NKEEP; ++a) {
    int v2 = chosen[a], b2 = a - 1;
    while (b2 >= 0 && chosen[b2] > v2) { chosen[b2 + 1] = chosen[b2]; --b2; }
    chosen[b2 + 1] = v2;
  }
  for (int a = 0; a < NKEEP; ++a) top_idx[bh * NKEEP + a] = chosen[a];
}

// ---------------- MFMA attention v8: raw v_exp, lazy max-reduce -------------
// fp16 q pre-scaled into log2 domain; p = v_exp(sacc - m). Defer-max decision
// uses per-lane LOCAL max (equivalent to row-max check under __all); the
// 16-lane shuffle max-reduce is only paid on the rare rescale path.
__global__ __launch_bounds__(256) void attn_mfma_kernel(const _Float16* __restrict__ qfp,
                                                        const _Float16* __restrict__ kf,
                                                        const _Float16* __restrict__ vt,
                                                        const int* __restrict__ top_idx,
                                                        _Float16* __restrict__ yf) {
  __shared__ char lds[74752];  // buf0 0..32K (K 16K|V 16K), buf1 32..64K, P 64K..
  const int bh = blockIdx.x >> 5;
  const int qt = blockIdx.x & 31;
  const int t = threadIdx.x, l = t & 63, w = t >> 6;
  const int lr = l & 15, lg = l >> 4;
  const float THR2 = 11.5415603f;  // 8 * log2(e)

  f16x8 qf[4];
  {
    const _Float16* qbase = qfp + ((size_t)(bh * S_ + qt * 64 + w * 16 + lr)) * DH + lg * 8;
#pragma unroll
    for (int dc = 0; dc < 4; ++dc)
      qf[dc] = *(const f16x8*)(qbase + dc * 32);
  }

  float m_[4] = {-INFINITY, -INFINITY, -INFINITY, -INFINITY};
  float ls[4] = {0.f, 0.f, 0.f, 0.f};
  f32x4 yacc[8];
#pragma unroll
  for (int dt = 0; dt < 8; ++dt) yacc[dt] = (f32x4){0.f, 0.f, 0.f, 0.f};

  char* Pw = lds + 65536 + w * 2304;  // per-wave P: [16 q][72 fp16]

  const _Float16* kb0 = kf + (size_t)bh * S_ * DH;
  const _Float16* vb0 = vt + (size_t)bh * DH * S_;
  const int* idxp = top_idx + bh * NKEEP;

  auto STAGE = [&](int blk, int c) {
    char* base = lds + c * 32768;
#pragma unroll
    for (int f0 = 0; f0 < 4; ++f0) {
      int f = w * 4 + f0;
      int kt = f >> 2, dc = f & 3;
      GLOAD16(kb0 + (size_t)(blk * 64 + kt * 16 + lr) * DH + dc * 32 + lg * 8,
              base + f * 1024);
      int K0 = f >> 3, dt = f & 7;
      GLOAD16(vb0 + (size_t)(dt * 16 + lr) * S_ + blk * 64 + K0 * 32 + lg * 8,
              base + 16384 + f * 1024);
    }
  };

  int cur = 0;
  STAGE(idxp[0], 0);

  for (int it = 0; it < NKEEP; ++it) {
    if (it + 1 < NKEEP) {
      STAGE(idxp[it + 1], cur ^ 1);
      asm volatile("s_waitcnt vmcnt(8)" ::: "memory");
    } else {
      asm volatile("s_waitcnt vmcnt(0)" ::: "memory");
    }
    __builtin_amdgcn_s_barrier();
    char* buf = lds + cur * 32768;

    f32x4 sacc[4];
#pragma unroll
    for (int kt = 0; kt < 4; ++kt) sacc[kt] = (f32x4){0.f, 0.f, 0.f, 0.f};
    __builtin_amdgcn_s_setprio(1);
#pragma unroll
    for (int kt = 0; kt < 4; ++kt)
#pragma unroll
      for (int dc = 0; dc < 4; ++dc) {
        f16x8 kfr = *(const f16x8*)(buf + (kt * 4 + dc) * 1024 + l * 16);
        sacc[kt] = __builtin_amdgcn_mfma_f32_16x16x32_f16(qf[dc], kfr, sacc[kt], 0, 0, 0);
      }
    __builtin_amdgcn_s_setprio(0);

    // per-lane LOCAL max (no reduce); __all makes the defer decision exactly
    // equivalent to the row-max check (row max = max over lanes of local max)
    float lmax[4];
#pragma unroll
    for (int r = 0; r < 4; ++r)
      lmax[r] = fmaxf(fmaxf(sacc[0][r], sacc[1][r]), fmaxf(sacc[2][r], sacc[3][r]));
    bool ok = (lmax[0] <= m_[0] + THR2) && (lmax[1] <= m_[1] + THR2) &&
              (lmax[2] <= m_[2] + THR2) && (lmax[3] <= m_[3] + THR2);
    float p[4][4];
    if (__all(ok)) {
      // defer-max: keep old max, skip max-reduce + corr/rescale (P <= e^8)
#pragma unroll
      for (int r = 0; r < 4; ++r) {
        float rs = 0.f;
#pragma unroll
        for (int kt = 0; kt < 4; ++kt) {
          p[kt][r] = fexp2(sacc[kt][r] - m_[r]);
          rs += p[kt][r];
        }
#pragma unroll
        for (int off = 1; off < 16; off <<= 1) rs += __shfl_xor(rs, off);
        ls[r] += rs;
      }
    } else {
#pragma unroll
      for (int r = 0; r < 4; ++r) {
        float mv = lmax[r];
#pragma unroll
        for (int off = 1; off < 16; off <<= 1) mv = fmaxf(mv, __shfl_xor(mv, off));
        float mn = fmaxf(m_[r], mv);
        float corr = fexp2(m_[r] - mn);
        float rs = 0.f;
#pragma unroll
        for (int kt = 0; kt < 4; ++kt) {
          p[kt][r] = fexp2(sacc[kt][r] - mn);
          rs += p[kt][r];
        }
#pragma unroll
        for (int off = 1; off < 16; off <<= 1) rs += __shfl_xor(rs, off);
        ls[r] = ls[r] * corr + rs;
        m_[r] = mn;
#pragma unroll
        for (int dt = 0; dt < 8; ++dt) yacc[dt][r] *= corr;
      }
    }

#pragma unroll
    for (int kt = 0; kt < 4; ++kt)
#pragma unroll
      for (int r = 0; r < 4; ++r)
        *(_Float16*)(Pw + (lg * 4 + r) * 144 + (kt * 16 + lr) * 2) = (_Float16)p[kt][r];

    __builtin_amdgcn_s_setprio(1);
#pragma unroll
    for (int K0 = 0; K0 < 2; ++K0) {
      f16x8 pa = *(const f16x8*)(Pw + lr * 144 + K0 * 64 + lg * 16);
#pragma unroll
      for (int dt = 0; dt < 8; ++dt) {
        f16x8 vf = *(const f16x8*)(buf + 16384 + (K0 * 8 + dt) * 1024 + l * 16);
        yacc[dt] = __builtin_amdgcn_mfma_f32_16x16x32_f16(pa, vf, yacc[dt], 0, 0, 0);
      }
    }
    __builtin_amdgcn_s_setprio(0);

    __builtin_amdgcn_s_barrier();
    cur ^= 1;
  }

  const int b = bh >> 4, h = bh & (H_ - 1);
  float inv[4];
#pragma unroll
  for (int r = 0; r < 4; ++r) inv[r] = 1.0f / ls[r];
#pragma unroll
  for (int r = 0; r < 4; ++r) {
    int srow = qt * 64 + w * 16 + lg * 4 + r;
    size_t off0 = ((size_t)b * S_ + srow) * DM + h * DH + lr;
#pragma unroll
    for (int dt = 0; dt < 8; ++dt)
      yf[off0 + dt * 16] = (_Float16)(yacc[dt][r] * inv[r]);
  }
}

extern "C" void kernel_launch(void* const* d_in, const int* in_sizes, int n_in,
                              void* d_out, int out_size, void* d_ws, size_t ws_size,
                              hipStream_t stream) {
  const float* x  = (const float*)d_in[0];
  const float* Wq = (const float*)d_in[1];
  const float* Wk = (const float*)d_in[2];
  const float* Wv = (const float*)d_in[3];
  const float* Wo = (const float*)d_in[4];
  const float* qg = (const float*)d_in[5];
  float* out = (float*)d_out;

  const size_t NE = (size_t)BH * S_ * DH;   // 8388608 elements
  const size_t WE = (size_t)DM * DM;        // 4194304 elements per W
  char* p = (char*)d_ws;
  float* q_ws = (float*)p; p += NE * 4;     // kpart1 during k-GEMM, then q f32
  float* k_ws = (float*)p; p += NE * 4;     // kpart0 -> roped k f32
  unsigned short* xhi = (unsigned short*)p; p += NE * 2;  // -> yf16 after k-GEMM
  unsigned short* xlo = (unsigned short*)p; p += NE * 2;  // -> vt after k-GEMM
  _Float16* xf16 = (_Float16*)p; p += NE * 2;             // -> qf16 after qv-GEMM
  unsigned short* wkhi = (unsigned short*)p; p += WE * 2; // \ kf16 spans wkhi+wklo
  unsigned short* wklo = (unsigned short*)p; p += WE * 2; // / (both dead post k-GEMM)
  _Float16* wqv = (_Float16*)p; p += 2 * WE * 2;          // [Wq;Wv] fp16; -> wo
  float* cosb = (float*)p; p += (size_t)S_ * 64 * 4;
  float* sinb = (float*)p; p += (size_t)S_ * 64 * 4;
  float* projb = (float*)p; p += 4096 * 4;
  int* idxb = (int*)p; p += BH * NKEEP * 4;
  float* scores = (float*)p; p += BH * NBLK * 4;
  float* qpbuf = (float*)p; p += BH * 32 * 4;
  // aliases (each with size check, stream-ordered):
  float* qpart = cosb;                   // 262KB <= 1MB; writer after rmsrope_q
  float* kpart1 = q_ws;                  // NE f32 = NE f32; qv writes q after rmsrope_k
  _Float16* kf16 = (_Float16*)wkhi;      // NE fp16 = 16.8MB = wkhi+wklo (16.8MB), both dead
  _Float16* vt = (_Float16*)xlo;         // NE fp16 <= NE ushort; xlo dead after k-GEMM
  _Float16* yf16 = (_Float16*)xhi;       // NE fp16 <= NE ushort; xhi dead after k-GEMM
  _Float16* qf16 = xf16;                 // NE fp16 = NE fp16; xf16 dead after qv-GEMM
  _Float16* wo = wqv;                    // WE fp16 <= 2WE fp16; wqv dead after qv-GEMM
  // total ws use ~152 MB (proven footprint, no growth)

  const int nx4 = (int)(NE / 4);
  const int nw4 = (int)(WE / 4);

  proj_kernel<<<dim3(16), dim3(256), 0, stream>>>(projb);
  rope_table_kernel<<<dim3(S_), dim3(64), 0, stream>>>(cosb, sinb);
  split_x3_kernel<<<dim3(nx4 / 256), dim3(256), 0, stream>>>(x, xhi, xlo, xf16, nx4);
  split_w3_kernel<<<dim3(nw4 / 256), dim3(256), 0, stream>>>(Wk, Wq, Wv, wkhi, wklo,
                                                             wqv, wqv + WE, nw4);

  // k: bf16x3, split-K=2, 8-wave 256^2, 4-phase counted-vmcnt interleave
  mfma_gemm_k_sk<<<dim3(8, 16, 2), dim3(512), 0, stream>>>(xhi, xlo, wkhi, wklo,
                                                           k_ws, kpart1);

  // k finalize: sum partials + RMS + RoPE; writes k f32 (in place) + kf16
  rmsrope_k_kernel<<<dim3((BH * S_) / 4), dim3(256), 0, stream>>>(k_ws, kpart1, kf16, cosb, sinb);

  // q+V fused: fp16, 256^2 8-wave, 2-phase; overwrites kpart1 (=q_ws) — safe now
  mfma_gemm_qv<<<dim3(16, 16), dim3(512), 0, stream>>>(xf16, wqv, q_ws, vt);

  // q finalize: RMS + RoPE + gain, emits fp16 q scaled by scale*log2e
  rmsrope_q_kernel<<<dim3((BH * S_) / 4), dim3(256), 0, stream>>>(q_ws, qf16, cosb, sinb, qg);

  qmean_part_kernel<<<dim3(BH * 16), dim3(256), 0, stream>>>(qf16, qpart);
  qproj_kernel<<<dim3(BH), dim3(128), 0, stream>>>(qpart, projb, qpbuf);
  kscore_kernel<<<dim3(BH * NBLK), dim3(256), 0, stream>>>(k_ws, projb, qpbuf, scores);
  topk_kernel<<<dim3(BH), dim3(64), 0, stream>>>(scores, idxb);

  // attn v8: raw v_exp softmax, lazy max-reduce defer
  attn_mfma_kernel<<<dim3(BH * 32), dim3(256), 0, stream>>>(qf16, kf16, vt, idxb, yf16);

  // O: fp16 x1 on yf16 and Wo-f16
  split_f16_kernel<<<dim3(nw4 / 256), dim3(256), 0, stream>>>(Wo, wo, nw4);
  mfma_gemm_f16<1><<<dim3(16, 32), dim3(256), 0, stream>>>(yf16, wo, out);
}

// Round 19
// 428.842 us; speedup vs baseline: 1.0432x; 1.0029x over previous
//
#include <hip/hip_runtime.h>
#include <hip/hip_bf16.h>

#define B_ 2
#define S_ 2048
#define DM 2048
#define H_ 16
#define DH 128
#define NBLK 32
#define NKEEP 18
#define BH (B_ * H_)

typedef __attribute__((ext_vector_type(8))) short short8;
typedef __attribute__((ext_vector_type(8))) _Float16 f16x8;
typedef __attribute__((ext_vector_type(4))) _Float16 f16x4;
typedef __attribute__((ext_vector_type(4))) float f32x4;

#define GLOAD16(gp, lp)                                                        \
  __builtin_amdgcn_global_load_lds(                                            \
      (const __attribute__((address_space(1))) unsigned int*)(const void*)(gp),\
      (__attribute__((address_space(3))) unsigned int*)(void*)(lp), 16, 0, 0)

__device__ __forceinline__ unsigned short f32_to_bf16(float f) {
  unsigned u = __float_as_uint(f);
  unsigned r = (u + 0x7fffu + ((u >> 16) & 1u)) >> 16;
  return (unsigned short)r;
}
__device__ __forceinline__ float bf16_to_f32(unsigned short h) {
  return __uint_as_float(((unsigned)h) << 16);
}
// raw HW 2^x (logits pre-scaled into log2 domain); no libm fixup code
__device__ __forceinline__ float fexp2(float x) {
  float r;
  asm("v_exp_f32 %0, %1" : "=v"(r) : "v"(x));
  return r;
}

// ---------------- proj: threefry2x32 (partitionable) + erfinv ----------------
__device__ __forceinline__ unsigned rotl32(unsigned x, int r) {
  return (x << r) | (x >> (32 - r));
}

__device__ __forceinline__ float erfinv_f32(float x) {
  float w = -log1pf(-x * x);
  float p;
  if (w < 5.0f) {
    w -= 2.5f;
    p = 2.81022636e-08f;
    p = fmaf(p, w, 3.43273939e-07f);
    p = fmaf(p, w, -3.5233877e-06f);
    p = fmaf(p, w, -4.39150654e-06f);
    p = fmaf(p, w, 0.00021858087f);
    p = fmaf(p, w, -0.00125372503f);
    p = fmaf(p, w, -0.00417768164f);
    p = fmaf(p, w, 0.246640727f);
    p = fmaf(p, w, 1.50140941f);
  } else {
    w = sqrtf(w) - 3.0f;
    p = -0.000200214257f;
    p = fmaf(p, w, 0.000100950558f);
    p = fmaf(p, w, 0.00134934322f);
    p = fmaf(p, w, -0.00367342844f);
    p = fmaf(p, w, 0.00573950773f);
    p = fmaf(p, w, -0.0076224613f);
    p = fmaf(p, w, 0.00943887047f);
    p = fmaf(p, w, 1.00167406f);
    p = fmaf(p, w, 2.83297682f);
  }
  return p * x;
}

__device__ __forceinline__ float bits_to_normal(unsigned b) {
  float f = __uint_as_float((b >> 9) | 0x3f800000u) - 1.0f;
  const float lo = -0.9999999403953552f;
  float u = fmaxf(lo, fmaf(f, 2.0f, lo));
  return 1.4142135623730951f * erfinv_f32(u);
}

__global__ void proj_kernel(float* __restrict__ proj) {
  int i = blockIdx.x * blockDim.x + threadIdx.x;
  if (i >= 4096) return;
  unsigned k0 = 0u, k1 = 42u;
  unsigned k2 = 0x1BD11BDAu ^ k0 ^ k1;
  unsigned x0 = 0u, x1 = (unsigned)i;
  x0 += k0; x1 += k1;
#define QR(r) { x0 += x1; x1 = rotl32(x1, r); x1 ^= x0; }
  QR(13) QR(15) QR(26) QR(6)   x0 += k1; x1 += k2 + 1u;
  QR(17) QR(29) QR(16) QR(24)  x0 += k2; x1 += k0 + 2u;
  QR(13) QR(15) QR(26) QR(6)   x0 += k0; x1 += k1 + 3u;
  QR(17) QR(29) QR(16) QR(24)  x0 += k1; x1 += k2 + 4u;
  QR(13) QR(15) QR(26) QR(6)   x0 += k2; x1 += k0 + 5u;
#undef QR
  proj[i] = bits_to_normal(x0 ^ x1) / 5.656854249492381f;
}

// ---------------- RoPE tables ----------------
__global__ void rope_table_kernel(float* __restrict__ cosb, float* __restrict__ sinb) {
  int s = blockIdx.x;
  int j = threadIdx.x;
  double e = (double)(2 * j) / 128.0;
  double invf = 1.0 / pow(10000.0, e);
  float freq = (float)s * (float)invf;
  cosb[s * 64 + j] = (float)cos((double)freq);
  sinb[s * 64 + j] = (float)sin((double)freq);
}

// ---------------- x -> bf16 hi/lo + fp16, single pass ----------------
__global__ __launch_bounds__(256) void split_x3_kernel(const float* __restrict__ in,
                                                       unsigned short* __restrict__ hi,
                                                       unsigned short* __restrict__ lo,
                                                       _Float16* __restrict__ f16,
                                                       int n4) {
  int i = blockIdx.x * blockDim.x + threadIdx.x;
  if (i >= n4) return;
  float4 v = ((const float4*)in)[i];
  ushort4 hv, lv;
  f16x4 fv;
  hv.x = f32_to_bf16(v.x); lv.x = f32_to_bf16(v.x - bf16_to_f32(hv.x)); fv[0] = (_Float16)v.x;
  hv.y = f32_to_bf16(v.y); lv.y = f32_to_bf16(v.y - bf16_to_f32(hv.y)); fv[1] = (_Float16)v.y;
  hv.z = f32_to_bf16(v.z); lv.z = f32_to_bf16(v.z - bf16_to_f32(hv.z)); fv[2] = (_Float16)v.z;
  hv.w = f32_to_bf16(v.w); lv.w = f32_to_bf16(v.w - bf16_to_f32(hv.w)); fv[3] = (_Float16)v.w;
  ((ushort4*)hi)[i] = hv;
  ((ushort4*)lo)[i] = lv;
  ((f16x4*)f16)[i] = fv;
}

// ---------------- fused W split: Wk -> bf16 hi/lo; Wq, Wv -> fp16 ----------
__global__ __launch_bounds__(256) void split_w3_kernel(const float* __restrict__ wk,
                                                       const float* __restrict__ wq,
                                                       const float* __restrict__ wv,
                                                       unsigned short* __restrict__ khi,
                                                       unsigned short* __restrict__ klo,
                                                       _Float16* __restrict__ qf,
                                                       _Float16* __restrict__ vf,
                                                       int n4) {
  int i = blockIdx.x * blockDim.x + threadIdx.x;
  if (i >= n4) return;
  {
    float4 v = ((const float4*)wk)[i];
    ushort4 hv, lv;
    hv.x = f32_to_bf16(v.x); lv.x = f32_to_bf16(v.x - bf16_to_f32(hv.x));
    hv.y = f32_to_bf16(v.y); lv.y = f32_to_bf16(v.y - bf16_to_f32(hv.y));
    hv.z = f32_to_bf16(v.z); lv.z = f32_to_bf16(v.z - bf16_to_f32(hv.z));
    hv.w = f32_to_bf16(v.w); lv.w = f32_to_bf16(v.w - bf16_to_f32(hv.w));
    ((ushort4*)khi)[i] = hv;
    ((ushort4*)klo)[i] = lv;
  }
  {
    float4 v = ((const float4*)wq)[i];
    f16x4 fv;
    fv[0] = (_Float16)v.x; fv[1] = (_Float16)v.y;
    fv[2] = (_Float16)v.z; fv[3] = (_Float16)v.w;
    ((f16x4*)qf)[i] = fv;
  }
  {
    float4 v = ((const float4*)wv)[i];
    f16x4 fv;
    fv[0] = (_Float16)v.x; fv[1] = (_Float16)v.y;
    fv[2] = (_Float16)v.z; fv[3] = (_Float16)v.w;
    ((f16x4*)vf)[i] = fv;
  }
}

// ---------------- W -> fp16 (Wo, late) ----------------
__global__ __launch_bounds__(256) void split_f16_kernel(const float* __restrict__ in,
                                                        _Float16* __restrict__ f16,
                                                        int n4) {
  int i = blockIdx.x * blockDim.x + threadIdx.x;
  if (i >= n4) return;
  float4 v = ((const float4*)in)[i];
  f16x4 fv;
  fv[0] = (_Float16)v.x; fv[1] = (_Float16)v.y;
  fv[2] = (_Float16)v.z; fv[3] = (_Float16)v.w;
  ((f16x4*)f16)[i] = fv;
}

// ---------------- k-GEMM: bf16x3, 256x256, 8 waves, SPLIT-K=2, 4-phase ------
__global__ __launch_bounds__(512, 2) void mfma_gemm_k_sk(const unsigned short* __restrict__ Ahi,
                                                         const unsigned short* __restrict__ Alo,
                                                         const unsigned short* __restrict__ Whi,
                                                         const unsigned short* __restrict__ Wlo,
                                                         float* __restrict__ kp0,
                                                         float* __restrict__ kp1) {
  __shared__ char smem[131072];  // 2 buf x 64K: Ahi 0|Alo 16K|Bhi 32K|Blo 48K
  const int t = threadIdx.x, l = t & 63, w = t >> 6;  // 8 waves
  const int lin = blockIdx.z * 128 + blockIdx.y * 8 + blockIdx.x;
  const int swz = (lin & 7) * 32 + (lin >> 3);        // 256 blocks, bijective
  const int kz = swz >> 7;
  const int idx = swz & 127;
  const int n0 = (idx & 7) * 256;
  const int m0 = (idx >> 3) * 256;
  const int kbase = kz * 1024;
  float* C = kz ? kp1 : kp0;
  const int wm = w >> 2, wn = w & 3;                  // 2M x 4N wave grid
  const int lr = l & 15;
  const int lg8 = (l >> 4) * 8;
  const size_t rstep = (size_t)16 * DM;

  const unsigned short* gAh = Ahi + (size_t)(m0 + w * 32 + lr) * DM + lg8;
  const unsigned short* gAl = Alo + (size_t)(m0 + w * 32 + lr) * DM + lg8;
  const unsigned short* gBh = Whi + (size_t)(n0 + w * 32 + lr) * DM + lg8;
  const unsigned short* gBl = Wlo + (size_t)(n0 + w * 32 + lr) * DM + lg8;

  f32x4 acc[8][4];
#pragma unroll
  for (int i = 0; i < 8; ++i)
#pragma unroll
    for (int j = 0; j < 4; ++j) acc[i][j] = (f32x4){0.f, 0.f, 0.f, 0.f};

  {  // prologue: full stage of tile 0 into buf 0
    char* base = smem + w * 2048;
    GLOAD16(gAh + kbase, base);
    GLOAD16(gAh + rstep + kbase, base + 1024);
    GLOAD16(gAl + kbase, base + 16384);
    GLOAD16(gAl + rstep + kbase, base + 16384 + 1024);
    GLOAD16(gBh + kbase, base + 32768);
    GLOAD16(gBh + rstep + kbase, base + 32768 + 1024);
    GLOAD16(gBl + kbase, base + 49152);
    GLOAD16(gBl + rstep + kbase, base + 49152 + 1024);
  }
  int cur = 0;

#define KQUAD(q)                                                                        \
  {                                                                                     \
    short8 ah0 = *(const short8*)(buf + (wm * 8 + 2 * (q)) * 1024 + l * 16);            \
    short8 ah1 = *(const short8*)(buf + (wm * 8 + 2 * (q) + 1) * 1024 + l * 16);        \
    short8 al0 = *(const short8*)(buf + 16384 + (wm * 8 + 2 * (q)) * 1024 + l * 16);    \
    short8 al1 = *(const short8*)(buf + 16384 + (wm * 8 + 2 * (q) + 1) * 1024 + l * 16);\
    __builtin_amdgcn_s_setprio(1);                                                      \
    _Pragma("unroll")                                                                   \
    for (int n = 0; n < 4; ++n) {                                                       \
      acc[2 * (q)][n] = __builtin_amdgcn_mfma_f32_16x16x32_bf16(ah0, bh[n], acc[2 * (q)][n], 0, 0, 0); \
      acc[2 * (q)][n] = __builtin_amdgcn_mfma_f32_16x16x32_bf16(ah0, bl[n], acc[2 * (q)][n], 0, 0, 0); \
      acc[2 * (q)][n] = __builtin_amdgcn_mfma_f32_16x16x32_bf16(al0, bh[n], acc[2 * (q)][n], 0, 0, 0); \
    }                                                                                   \
    _Pragma("unroll")                                                                   \
    for (int n = 0; n < 4; ++n) {                                                       \
      acc[2 * (q) + 1][n] = __builtin_amdgcn_mfma_f32_16x16x32_bf16(ah1, bh[n], acc[2 * (q) + 1][n], 0, 0, 0); \
      acc[2 * (q) + 1][n] = __builtin_amdgcn_mfma_f32_16x16x32_bf16(ah1, bl[n], acc[2 * (q) + 1][n], 0, 0, 0); \
      acc[2 * (q) + 1][n] = __builtin_amdgcn_mfma_f32_16x16x32_bf16(al1, bh[n], acc[2 * (q) + 1][n], 0, 0, 0); \
    }                                                                                   \
    __builtin_amdgcn_s_setprio(0);                                                      \
  }

  for (int k0 = kbase; k0 < kbase + 1024; k0 += 32) {
    const bool more = (k0 + 32 < kbase + 1024);
    char* buf = smem + cur * 65536;
    char* nb = smem + (cur ^ 1) * 65536 + w * 2048;
    const int kn = k0 + 32;

    if (more) {
      GLOAD16(gBh + kn, nb + 32768);
      GLOAD16(gBh + rstep + kn, nb + 32768 + 1024);
      asm volatile("s_waitcnt vmcnt(2)" ::: "memory");
    } else {
      asm volatile("s_waitcnt vmcnt(0)" ::: "memory");
    }
    __builtin_amdgcn_s_barrier();

    short8 bh[4], bl[4];
#pragma unroll
    for (int f = 0; f < 4; ++f) {
      bh[f] = *(const short8*)(buf + 32768 + (wn * 4 + f) * 1024 + l * 16);
      bl[f] = *(const short8*)(buf + 49152 + (wn * 4 + f) * 1024 + l * 16);
    }
    KQUAD(0);
    __builtin_amdgcn_s_barrier();

    if (more) {
      GLOAD16(gBl + kn, nb + 49152);
      GLOAD16(gBl + rstep + kn, nb + 49152 + 1024);
    }
    KQUAD(1);
    __builtin_amdgcn_s_barrier();

    if (more) {
      GLOAD16(gAh + kn, nb);
      GLOAD16(gAh + rstep + kn, nb + 1024);
    }
    KQUAD(2);
    __builtin_amdgcn_s_barrier();

    if (more) {
      GLOAD16(gAl + kn, nb + 16384);
      GLOAD16(gAl + rstep + kn, nb + 16384 + 1024);
    }
    KQUAD(3);
    __builtin_amdgcn_s_barrier();

    cur ^= 1;
  }
#undef KQUAD

#pragma unroll
  for (int m = 0; m < 8; ++m) {
    int row0 = m0 + wm * 128 + m * 16 + (l >> 4) * 4;
#pragma unroll
    for (int n = 0; n < 4; ++n) {
      int col = n0 + wn * 64 + n * 16 + (l & 15);
      int h = col >> 7, d = col & 127;
#pragma unroll
      for (int r = 0; r < 4; ++r) {
        int mm = row0 + r;
        int b = mm >> 11, s = mm & (S_ - 1);
        C[(((size_t)(b * H_ + h) * S_) + s) * DH + d] = acc[m][n][r];
      }
    }
  }
}

// ---------------- fused q+V fp16 GEMM: 256x256, 8 waves, 4-phase ------------
__global__ __launch_bounds__(512, 2) void mfma_gemm_qv(const _Float16* __restrict__ A,
                                                       const _Float16* __restrict__ W,
                                                       float* __restrict__ Cq,
                                                       _Float16* __restrict__ vt) {
  __shared__ char smem[65536];  // 2 buf x 32K: A frags 0..16K | B frags 16..32K
  const int t = threadIdx.x, l = t & 63, w = t >> 6;  // 8 waves
  const int lin = blockIdx.y * gridDim.x + blockIdx.x;
  const int swz = (lin & 7) * 32 + (lin >> 3);        // 256 blocks, bijective
  const int n0 = (swz & 15) * 256;
  const int m0 = (swz >> 4) * 256;
  const int wm = w >> 2, wn = w & 3;                  // 2M x 4N wave grid
  const int lr = l & 15;
  const int lg8 = (l >> 4) * 8;
  const size_t rstep = (size_t)16 * DM;

  const _Float16* gA = A + (size_t)(m0 + w * 32 + lr) * DM + lg8;
  const _Float16* gB = W + (size_t)(n0 + w * 32 + lr) * DM + lg8;

  f32x4 acc[8][4];
#pragma unroll
  for (int i = 0; i < 8; ++i)
#pragma unroll
    for (int j = 0; j < 4; ++j) acc[i][j] = (f32x4){0.f, 0.f, 0.f, 0.f};

  {  // prologue
    char* base = smem + w * 2048;
    GLOAD16(gA, base);
    GLOAD16(gA + rstep, base + 1024);
    GLOAD16(gB, base + 16384);
    GLOAD16(gB + rstep, base + 16384 + 1024);
  }
  int cur = 0;

#define QVPAIR(i0)                                                                     \
  {                                                                                    \
    __builtin_amdgcn_s_setprio(1);                                                     \
    _Pragma("unroll")                                                                  \
    for (int i = (i0); i < (i0) + 2; ++i) {                                            \
      f16x8 a = *(const f16x8*)(buf + (wm * 8 + i) * 1024 + l * 16);                   \
      _Pragma("unroll")                                                                \
      for (int j = 0; j < 4; ++j)                                                      \
        acc[i][j] = __builtin_amdgcn_mfma_f32_16x16x32_f16(a, b[j], acc[i][j], 0, 0, 0);\
    }                                                                                  \
    __builtin_amdgcn_s_setprio(0);                                                     \
  }

  for (int k0 = 0; k0 < DM; k0 += 32) {
    const bool more = (k0 + 32 < DM);
    char* buf = smem + cur * 32768;
    char* nb = smem + (cur ^ 1) * 32768 + w * 2048;
    const int kn = k0 + 32;

    // phase 0: 1 gload; wait current tile landed; read B regs; m-frags 0,1
    if (more) {
      GLOAD16(gA + kn, nb);
      asm volatile("s_waitcnt vmcnt(1)" ::: "memory");
    } else {
      asm volatile("s_waitcnt vmcnt(0)" ::: "memory");
    }
    __builtin_amdgcn_s_barrier();

    f16x8 b[4];
#pragma unroll
    for (int j = 0; j < 4; ++j)
      b[j] = *(const f16x8*)(buf + 16384 + (wn * 4 + j) * 1024 + l * 16);
    QVPAIR(0);
    __builtin_amdgcn_s_barrier();

    // phase 1
    if (more) GLOAD16(gA + rstep + kn, nb + 1024);
    QVPAIR(2);
    __builtin_amdgcn_s_barrier();

    // phase 2
    if (more) GLOAD16(gB + kn, nb + 16384);
    QVPAIR(4);
    __builtin_amdgcn_s_barrier();

    // phase 3
    if (more) GLOAD16(gB + rstep + kn, nb + 16384 + 1024);
    QVPAIR(6);
    __builtin_amdgcn_s_barrier();

    cur ^= 1;
  }
#undef QVPAIR

#pragma unroll
  for (int m = 0; m < 8; ++m) {
    int row0 = m0 + wm * 128 + m * 16 + (l >> 4) * 4;
#pragma unroll
    for (int n = 0; n < 4; ++n) {
      int col = n0 + wn * 64 + n * 16 + (l & 15);
      if (col < DM) {
        int h = col >> 7, d = col & 127;
#pragma unroll
        for (int r = 0; r < 4; ++r) {
          int mm = row0 + r;
          int b2 = mm >> 11, s = mm & (S_ - 1);
          Cq[(((size_t)(b2 * H_ + h) * S_) + s) * DH + d] = acc[m][n][r];
        }
      } else {
        int vcol = col - DM;
        int h = vcol >> 7, d = vcol & 127;
        int b2 = row0 >> 11, s0 = row0 & (S_ - 1);
        f16x4 vv;
        vv[0] = (_Float16)acc[m][n][0];
        vv[1] = (_Float16)acc[m][n][1];
        vv[2] = (_Float16)acc[m][n][2];
        vv[3] = (_Float16)acc[m][n][3];
        *(f16x4*)(vt + (((size_t)(b2 * H_ + h)) * DH + d) * S_ + s0) = vv;
      }
    }
  }
}

// ---------------- fp16 single-product GEMM (O), BK=64, 128x128 --------------
template <int MODE>
__global__ __launch_bounds__(256) void mfma_gemm_f16(const _Float16* __restrict__ A,
                                                     const _Float16* __restrict__ W,
                                                     void* __restrict__ Cout) {
  __shared__ char smem[65536];
  const int t = threadIdx.x, l = t & 63, w = t >> 6;
  const int lin = blockIdx.y * gridDim.x + blockIdx.x;
  const int cpx = (gridDim.x * gridDim.y) >> 3;
  const int swz = (lin & 7) * cpx + (lin >> 3);
  const int n0 = (swz % gridDim.x) * 128;
  const int m0 = (swz / gridDim.x) * 128;
  const int wm = w >> 1, wn = w & 1;
  const int lr = l & 15;
  const int lg8 = (l >> 4) * 8;

  auto STAGE = [&](int k0, int c) {
    char* base = smem + c * 32768;
#pragma unroll
    for (int f0 = 0; f0 < 4; ++f0) {
      int f = w * 4 + f0;
      int rb = f >> 1, kh = f & 1;
      GLOAD16(A + (size_t)(m0 + rb * 16 + lr) * DM + k0 + kh * 32 + lg8,
              base + f * 1024);
      GLOAD16(W + (size_t)(n0 + rb * 16 + lr) * DM + k0 + kh * 32 + lg8,
              base + 16384 + f * 1024);
    }
  };

  f32x4 acc[4][4];
#pragma unroll
  for (int i = 0; i < 4; ++i)
#pragma unroll
    for (int j = 0; j < 4; ++j) acc[i][j] = (f32x4){0.f, 0.f, 0.f, 0.f};

  STAGE(0, 0);
  int cur = 0;

  for (int k0 = 0; k0 < DM; k0 += 64) {
    if (k0 + 64 < DM) {
      STAGE(k0 + 64, cur ^ 1);
      asm volatile("s_waitcnt vmcnt(8)" ::: "memory");
    } else {
      asm volatile("s_waitcnt vmcnt(0)" ::: "memory");
    }
    __builtin_amdgcn_s_barrier();

    char* buf = smem + cur * 32768;
    f16x8 a[4][2], b[4][2];
#pragma unroll
    for (int i = 0; i < 4; ++i)
#pragma unroll
      for (int kh = 0; kh < 2; ++kh) {
        a[i][kh] = *(const f16x8*)(buf + ((wm * 4 + i) * 2 + kh) * 1024 + l * 16);
        b[i][kh] = *(const f16x8*)(buf + 16384 + ((wn * 4 + i) * 2 + kh) * 1024 + l * 16);
      }
    __builtin_amdgcn_s_setprio(1);
#pragma unroll
    for (int i = 0; i < 4; ++i)
#pragma unroll
      for (int j = 0; j < 4; ++j) {
        acc[i][j] = __builtin_amdgcn_mfma_f32_16x16x32_f16(a[i][0], b[j][0], acc[i][j], 0, 0, 0);
        acc[i][j] = __builtin_amdgcn_mfma_f32_16x16x32_f16(a[i][1], b[j][1], acc[i][j], 0, 0, 0);
      }
    __builtin_amdgcn_s_setprio(0);
    __builtin_amdgcn_s_barrier();
    cur ^= 1;
  }

#pragma unroll
  for (int i = 0; i < 4; ++i) {
    int row0 = m0 + wm * 64 + i * 16 + (l >> 4) * 4;
#pragma unroll
    for (int j = 0; j < 4; ++j) {
      int col = n0 + wn * 64 + j * 16 + (l & 15);
      if constexpr (MODE == 1) {
        float* C = (float*)Cout;
#pragma unroll
        for (int r = 0; r < 4; ++r)
          C[(size_t)(row0 + r) * DM + col] = acc[i][j][r];
      }
    }
  }
}

// ---------------- RMSNorm + RoPE for K: sums split-K partials, emits fp16 ---
__global__ __launch_bounds__(256) void rmsrope_k_kernel(float* __restrict__ k,
                                                        const float* __restrict__ kp1,
                                                        _Float16* __restrict__ kf,
                                                        const float* __restrict__ cosb,
                                                        const float* __restrict__ sinb) {
  int w = threadIdx.x >> 6;
  int lane = threadIdx.x & 63;
  long r = (long)blockIdx.x * 4 + w;
  float* p = k + r * DH;
  const float* p1 = kp1 + r * DH;
  int s = (int)(r & (S_ - 1));
  float x1 = p[lane] + p1[lane];
  float x2 = p[lane + 64] + p1[lane + 64];
  float ss = fmaf(x1, x1, x2 * x2);
#pragma unroll
  for (int off = 32; off; off >>= 1) ss += __shfl_xor(ss, off);
  float rms = rsqrtf(ss * (1.0f / 128.0f) + 1e-6f);
  float n1 = x1 * rms, n2 = x2 * rms;
  float c = cosb[s * 64 + lane], sn = sinb[s * 64 + lane];
  float o1 = fmaf(n1, c, n2 * sn);
  float o2 = fmaf(-n1, sn, n2 * c);
  p[lane] = o1;
  p[lane + 64] = o2;
  kf[r * DH + lane] = (_Float16)o1;
  kf[r * DH + lane + 64] = (_Float16)o2;
}

// ---------------- RMSNorm + RoPE + gain for Q: emits fp16 scaled by ---------
// SC = (1/sqrt(128))*log2(e) so attn logits land in log2 domain. The uniform
// positive SC cancels exactly in selection's _normalize(mean @ proj).
__global__ __launch_bounds__(256) void rmsrope_q_kernel(const float* __restrict__ q,
                                                        _Float16* __restrict__ qf,
                                                        const float* __restrict__ cosb,
                                                        const float* __restrict__ sinb,
                                                        const float* __restrict__ qg) {
  const float SC = 0.12751743f;  // 1/sqrt(128) * log2(e)
  int w = threadIdx.x >> 6;
  int lane = threadIdx.x & 63;
  long r = (long)blockIdx.x * 4 + w;
  const float* p = q + r * DH;
  int s = (int)(r & (S_ - 1));
  int h = (int)((r >> 11) & (H_ - 1));
  float x1 = p[lane], x2 = p[lane + 64];
  float ss = fmaf(x1, x1, x2 * x2);
#pragma unroll
  for (int off = 32; off; off >>= 1) ss += __shfl_xor(ss, off);
  float rms = rsqrtf(ss * (1.0f / 128.0f) + 1e-6f);
  float n1 = x1 * rms, n2 = x2 * rms;
  float c = cosb[s * 64 + lane], sn = sinb[s * 64 + lane];
  float g = qg[h] * SC;
  float o1 = fmaf(n1, c, n2 * sn) * g;
  float o2 = fmaf(-n1, sn, n2 * c) * g;
  qf[r * DH + lane] = (_Float16)o1;
  qf[r * DH + lane + 64] = (_Float16)o2;
}

// ---------------- selection phase 1: q-mean partial sums (fp16 q) -----------
__global__ __launch_bounds__(256) void qmean_part_kernel(const _Float16* __restrict__ qf,
                                                         float* __restrict__ partial) {
  __shared__ float red[256];
  const int bh = blockIdx.x >> 4, chunk = blockIdx.x & 15;
  const int t = threadIdx.x;
  const int d = t & 127, half = t >> 7;
  const _Float16* qb = qf + ((size_t)bh * S_ + chunk * 128 + half * 64) * DH;
  float sum = 0.0f;
#pragma unroll 4
  for (int s = 0; s < 64; ++s) sum += (float)qb[(size_t)s * DH + d];
  red[t] = sum;
  __syncthreads();
  if (t < 128) partial[(size_t)blockIdx.x * 128 + t] = red[t] + red[t + 128];
}

// ---------------- selection phase 2: finish mean, project, normalize --------
__global__ void qproj_kernel(const float* __restrict__ partial,
                             const float* __restrict__ proj,
                             float* __restrict__ qp) {
  __shared__ float meanq[128];
  __shared__ float qps[32];
  __shared__ float nrm;
  const int bh = blockIdx.x, t = threadIdx.x;
  float s = 0.0f;
#pragma unroll
  for (int c = 0; c < 16; ++c) s += partial[((size_t)bh * 16 + c) * 128 + t];
  meanq[t] = s * (1.0f / 2048.0f);
  __syncthreads();
  if (t < 32) {
    float sum = 0.0f;
    for (int d = 0; d < 128; ++d) sum = fmaf(meanq[d], proj[d * 32 + t], sum);
    qps[t] = sum;
  }
  __syncthreads();
  if (t == 0) {
    float sum = 0.0f;
    for (int j = 0; j < 32; ++j) sum += qps[j] * qps[j];
    nrm = 1.0f / fmaxf(sqrtf(sum), 1e-12f);
  }
  __syncthreads();
  if (t < 32) qp[bh * 32 + t] = qps[t] * nrm;
}

// ---------------- selection phase 3: per-(bh,block) score ----------------
__global__ __launch_bounds__(256) void kscore_kernel(const float* __restrict__ k,
                                                     const float* __restrict__ proj,
                                                     const float* __restrict__ qp,
                                                     float* __restrict__ scores) {
  __shared__ float ps[128][32];
  __shared__ float kp[64][33];
  __shared__ float cent[33];
  __shared__ float nrm;
  const int bh = blockIdx.x >> 5, n = blockIdx.x & 31;
  const int t = threadIdx.x;
  for (int i = t; i < 4096; i += 256) ps[i >> 5][i & 31] = proj[i];
  const float* kn = k + ((size_t)bh * S_ + n * 64) * DH;
  __syncthreads();
  {
    int row = t >> 2, j0 = (t & 3) * 8;
    float accv[8];
#pragma unroll
    for (int jj = 0; jj < 8; ++jj) accv[jj] = 0.0f;
#pragma unroll 4
    for (int d = 0; d < 128; ++d) {
      float kv = kn[(size_t)row * DH + d];
#pragma unroll
      for (int jj = 0; jj < 8; ++jj) accv[jj] = fmaf(kv, ps[d][j0 + jj], accv[jj]);
    }
#pragma unroll
    for (int jj = 0; jj < 8; ++jj) kp[row][j0 + jj] = accv[jj];
  }
  __syncthreads();
  if (t < 64) {
    float sum = 0.0f;
    for (int j = 0; j < 32; ++j) sum += kp[t][j] * kp[t][j];
    float scl = 1.0f / fmaxf(sqrtf(sum), 1e-12f);
    for (int j = 0; j < 32; ++j) kp[t][j] *= scl;
  }
  __syncthreads();
  if (t < 32) {
    float sum = 0.0f;
    for (int r2 = 0; r2 < 64; ++r2) sum += kp[r2][t];
    cent[t] = sum * (1.0f / 64.0f);
  }
  __syncthreads();
  if (t == 0) {
    float sum = 0.0f;
    for (int j = 0; j < 32; ++j) sum += cent[j] * cent[j];
    nrm = 1.0f / fmaxf(sqrtf(sum), 1e-12f);
  }
  __syncthreads();
  if (t < 32) cent[t] *= nrm;
  __syncthreads();
  if (t < 64) {
    float dt = 0.0f;
    for (int j = 0; j < 32; ++j) dt = fmaf(kp[t][j], cent[j], dt);
#pragma unroll
    for (int off = 32; off; off >>= 1) dt = fminf(dt, __shfl_xor(dt, off));
    if (t == 0) {
      float radius = fminf(fmaxf(1.0f - dt, 0.0f), 1.0f);
      float dq = 0.0f;
      for (int j = 0; j < 32; ++j) dq = fmaf(qp[bh * 32 + j], cent[j], dq);
      scores[bh * 32 + n] = dq + radius;
    }
  }
}

// ---------------- selection phase 4: top-18 + sort ----------------
__global__ void topk_kernel(const float* __restrict__ scores, int* __restrict__ top_idx) {
  if (threadIdx.x != 0) return;
  const int bh = blockIdx.x;
  float sc[NBLK];
  for (int j = 0; j < NBLK; ++j) sc[j] = scores[bh * 32 + j];
  sc[NBLK - 2] = INFINITY;
  sc[NBLK - 1] = INFINITY;
  int chosen[NKEEP];
  bool used[NBLK];
  for (int j = 0; j < NBLK; ++j) used[j] = false;
  for (int kk = 0; kk < NKEEP; ++kk) {
    int best = -1;
    float bv = 0.0f;
    for (int j = 0; j < NBLK; ++j)
      if (!used[j] && (best < 0 || sc[j] > bv)) { bv = sc[j]; best = j; }
    used[best] = true;
    chosen[kk] = best;
  }
  for (int a = 1; a < NKEEP; ++a) {
    int v2 = chosen[a], b2 = a - 1;
    while (b2 >= 0 && chosen[b2] > v2) { chosen[b2 + 1] = chosen[b2]; --b2; }
    chosen[b2 + 1] = v2;
  }
  for (int a = 0; a < NKEEP; ++a) top_idx[bh * NKEEP + a] = chosen[a];
}

// ---------------- MFMA attention v9: per-lane ls partials (deferred reduce) -
// fp16 q pre-scaled into log2 domain; p = v_exp(sacc - m). ls is kept as a
// PER-LANE partial sum (corr is uniform across the row's 16 lanes, so scaling
// the partial preserves exactness); one 4-shuffle reduce at the epilogue
// replaces 4 shuffles/row/iteration.
__global__ __launch_bounds__(256) void attn_mfma_kernel(const _Float16* __restrict__ qfp,
                                                        const _Float16* __restrict__ kf,
                                                        const _Float16* __restrict__ vt,
                                                        const int* __restrict__ top_idx,
                                                        _Float16* __restrict__ yf) {
  __shared__ char lds[74752];  // buf0 0..32K (K 16K|V 16K), buf1 32..64K, P 64K..
  const int bh = blockIdx.x >> 5;
  const int qt = blockIdx.x & 31;
  const int t = threadIdx.x, l = t & 63, w = t >> 6;
  const int lr = l & 15, lg = l >> 4;
  const float THR2 = 11.5415603f;  // 8 * log2(e)

  f16x8 qf[4];
  {
    const _Float16* qbase = qfp + ((size_t)(bh * S_ + qt * 64 + w * 16 + lr)) * DH + lg * 8;
#pragma unroll
    for (int dc = 0; dc < 4; ++dc)
      qf[dc] = *(const f16x8*)(qbase + dc * 32);
  }

  float m_[4] = {-INFINITY, -INFINITY, -INFINITY, -INFINITY};
  float ls[4] = {0.f, 0.f, 0.f, 0.f};  // PER-LANE partial sums
  f32x4 yacc[8];
#pragma unroll
  for (int dt = 0; dt < 8; ++dt) yacc[dt] = (f32x4){0.f, 0.f, 0.f, 0.f};

  char* Pw = lds + 65536 + w * 2304;  // per-wave P: [16 q][72 fp16]

  const _Float16* kb0 = kf + (size_t)bh * S_ * DH;
  const _Float16* vb0 = vt + (size_t)bh * DH * S_;
  const int* idxp = top_idx + bh * NKEEP;

  auto STAGE = [&](int blk, int c) {
    char* base = lds + c * 32768;
#pragma unroll
    for (int f0 = 0; f0 < 4; ++f0) {
      int f = w * 4 + f0;
      int kt = f >> 2, dc = f & 3;
      GLOAD16(kb0 + (size_t)(blk * 64 + kt * 16 + lr) * DH + dc * 32 + lg * 8,
              base + f * 1024);
      int K0 = f >> 3, dt = f & 7;
      GLOAD16(vb0 + (size_t)(dt * 16 + lr) * S_ + blk * 64 + K0 * 32 + lg * 8,
              base + 16384 + f * 1024);
    }
  };

  int cur = 0;
  STAGE(idxp[0], 0);

  for (int it = 0; it < NKEEP; ++it) {
    if (it + 1 < NKEEP) {
      STAGE(idxp[it + 1], cur ^ 1);
      asm volatile("s_waitcnt vmcnt(8)" ::: "memory");
    } else {
      asm volatile("s_waitcnt vmcnt(0)" ::: "memory");
    }
    __builtin_amdgcn_s_barrier();
    char* buf = lds + cur * 32768;

    f32x4 sacc[4];
#pragma unroll
    for (int kt = 0; kt < 4; ++kt) sacc[kt] = (f32x4){0.f, 0.f, 0.f, 0.f};
    __builtin_amdgcn_s_setprio(1);
#pragma unroll
    for (int kt = 0; kt < 4; ++kt)
#pragma unroll
      for (int dc = 0; dc < 4; ++dc) {
        f16x8 kfr = *(const f16x8*)(buf + (kt * 4 + dc) * 1024 + l * 16);
        sacc[kt] = __builtin_amdgcn_mfma_f32_16x16x32_f16(qf[dc], kfr, sacc[kt], 0, 0, 0);
      }
    __builtin_amdgcn_s_setprio(0);

    // per-lane LOCAL max (no reduce); __all makes the defer decision exactly
    // equivalent to the row-max check (row max = max over lanes of local max)
    float lmax[4];
#pragma unroll
    for (int r = 0; r < 4; ++r)
      lmax[r] = fmaxf(fmaxf(sacc[0][r], sacc[1][r]), fmaxf(sacc[2][r], sacc[3][r]));
    bool ok = (lmax[0] <= m_[0] + THR2) && (lmax[1] <= m_[1] + THR2) &&
              (lmax[2] <= m_[2] + THR2) && (lmax[3] <= m_[3] + THR2);
    float p[4][4];
    if (__all(ok)) {
      // defer-max: keep old max; accumulate per-lane ls partials (no shuffles)
#pragma unroll
      for (int r = 0; r < 4; ++r) {
#pragma unroll
        for (int kt = 0; kt < 4; ++kt) {
          p[kt][r] = fexp2(sacc[kt][r] - m_[r]);
          ls[r] += p[kt][r];
        }
      }
    } else {
#pragma unroll
      for (int r = 0; r < 4; ++r) {
        float mv = lmax[r];
#pragma unroll
        for (int off = 1; off < 16; off <<= 1) mv = fmaxf(mv, __shfl_xor(mv, off));
        float mn = fmaxf(m_[r], mv);
        float corr = fexp2(m_[r] - mn);   // uniform across the row's lanes
        float rs = 0.f;
#pragma unroll
        for (int kt = 0; kt < 4; ++kt) {
          p[kt][r] = fexp2(sacc[kt][r] - mn);
          rs += p[kt][r];
        }
        ls[r] = ls[r] * corr + rs;        // per-lane partial, scaled uniformly
        m_[r] = mn;
#pragma unroll
        for (int dt = 0; dt < 8; ++dt) yacc[dt][r] *= corr;
      }
    }

#pragma unroll
    for (int kt = 0; kt < 4; ++kt)
#pragma unroll
      for (int r = 0; r < 4; ++r)
        *(_Float16*)(Pw + (lg * 4 + r) * 144 + (kt * 16 + lr) * 2) = (_Float16)p[kt][r];

    __builtin_amdgcn_s_setprio(1);
#pragma unroll
    for (int K0 = 0; K0 < 2; ++K0) {
      f16x8 pa = *(const f16x8*)(Pw + lr * 144 + K0 * 64 + lg * 16);
#pragma unroll
      for (int dt = 0; dt < 8; ++dt) {
        f16x8 vf = *(const f16x8*)(buf + 16384 + (K0 * 8 + dt) * 1024 + l * 16);
        yacc[dt] = __builtin_amdgcn_mfma_f32_16x16x32_f16(pa, vf, yacc[dt], 0, 0, 0);
      }
    }
    __builtin_amdgcn_s_setprio(0);

    __builtin_amdgcn_s_barrier();
    cur ^= 1;
  }

  // epilogue: reduce per-lane ls partials across the row's 16 lanes (once)
  const int b = bh >> 4, h = bh & (H_ - 1);
  float inv[4];
#pragma unroll
  for (int r = 0; r < 4; ++r) {
    float s = ls[r];
#pragma unroll
    for (int off = 1; off < 16; off <<= 1) s += __shfl_xor(s, off);
    inv[r] = 1.0f / s;
  }
#pragma unroll
  for (int r = 0; r < 4; ++r) {
    int srow = qt * 64 + w * 16 + lg * 4 + r;
    size_t off0 = ((size_t)b * S_ + srow) * DM + h * DH + lr;
#pragma unroll
    for (int dt = 0; dt < 8; ++dt)
      yf[off0 + dt * 16] = (_Float16)(yacc[dt][r] * inv[r]);
  }
}

extern "C" void kernel_launch(void* const* d_in, const int* in_sizes, int n_in,
                              void* d_out, int out_size, void* d_ws, size_t ws_size,
                              hipStream_t stream) {
  const float* x  = (const float*)d_in[0];
  const float* Wq = (const float*)d_in[1];
  const float* Wk = (const float*)d_in[2];
  const float* Wv = (const float*)d_in[3];
  const float* Wo = (const float*)d_in[4];
  const float* qg = (const float*)d_in[5];
  float* out = (float*)d_out;

  const size_t NE = (size_t)BH * S_ * DH;   // 8388608 elements
  const size_t WE = (size_t)DM * DM;        // 4194304 elements per W
  char* p = (char*)d_ws;
  float* q_ws = (float*)p; p += NE * 4;     // kpart1 during k-GEMM, then q f32
  float* k_ws = (float*)p; p += NE * 4;     // kpart0 -> roped k f32
  unsigned short* xhi = (unsigned short*)p; p += NE * 2;  // -> yf16 after k-GEMM
  unsigned short* xlo = (unsigned short*)p; p += NE * 2;  // -> vt after k-GEMM
  _Float16* xf16 = (_Float16*)p; p += NE * 2;             // -> qf16 after qv-GEMM
  unsigned short* wkhi = (unsigned short*)p; p += WE * 2; // \ kf16 spans wkhi+wklo
  unsigned short* wklo = (unsigned short*)p; p += WE * 2; // / (both dead post k-GEMM)
  _Float16* wqv = (_Float16*)p; p += 2 * WE * 2;          // [Wq;Wv] fp16; -> wo
  float* cosb = (float*)p; p += (size_t)S_ * 64 * 4;
  float* sinb = (float*)p; p += (size_t)S_ * 64 * 4;
  float* projb = (float*)p; p += 4096 * 4;
  int* idxb = (int*)p; p += BH * NKEEP * 4;
  float* scores = (float*)p; p += BH * NBLK * 4;
  float* qpbuf = (float*)p; p += BH * 32 * 4;
  // aliases (each with size check, stream-ordered):
  float* qpart = cosb;                   // 262KB <= 1MB; writer after rmsrope_q
  float* kpart1 = q_ws;                  // NE f32 = NE f32; qv writes q after rmsrope_k
  _Float16* kf16 = (_Float16*)wkhi;      // NE fp16 = 16.8MB = wkhi+wklo (16.8MB), both dead
  _Float16* vt = (_Float16*)xlo;         // NE fp16 <= NE ushort; xlo dead after k-GEMM
  _Float16* yf16 = (_Float16*)xhi;       // NE fp16 <= NE ushort; xhi dead after k-GEMM
  _Float16* qf16 = xf16;                 // NE fp16 = NE fp16; xf16 dead after qv-GEMM
  _Float16* wo = wqv;                    // WE fp16 <= 2WE fp16; wqv dead after qv-GEMM
  // total ws use ~152 MB (proven footprint, no growth)

  const int nx4 = (int)(NE / 4);
  const int nw4 = (int)(WE / 4);

  proj_kernel<<<dim3(16), dim3(256), 0, stream>>>(projb);
  rope_table_kernel<<<dim3(S_), dim3(64), 0, stream>>>(cosb, sinb);
  split_x3_kernel<<<dim3(nx4 / 256), dim3(256), 0, stream>>>(x, xhi, xlo, xf16, nx4);
  split_w3_kernel<<<dim3(nw4 / 256), dim3(256), 0, stream>>>(Wk, Wq, Wv, wkhi, wklo,
                                                             wqv, wqv + WE, nw4);

  // k: bf16x3, split-K=2, 8-wave 256^2, 4-phase counted-vmcnt interleave
  mfma_gemm_k_sk<<<dim3(8, 16, 2), dim3(512), 0, stream>>>(xhi, xlo, wkhi, wklo,
                                                           k_ws, kpart1);

  // k finalize: sum partials + RMS + RoPE; writes k f32 (in place) + kf16
  rmsrope_k_kernel<<<dim3((BH * S_) / 4), dim3(256), 0, stream>>>(k_ws, kpart1, kf16, cosb, sinb);

  // q+V fused: fp16, 256^2 8-wave, 4-phase; overwrites kpart1 (=q_ws) — safe now
  mfma_gemm_qv<<<dim3(16, 16), dim3(512), 0, stream>>>(xf16, wqv, q_ws, vt);

  // q finalize: RMS + RoPE + gain, emits fp16 q scaled by scale*log2e
  rmsrope_q_kernel<<<dim3((BH * S_) / 4), dim3(256), 0, stream>>>(q_ws, qf16, cosb, sinb, qg);

  qmean_part_kernel<<<dim3(BH * 16), dim3(256), 0, stream>>>(qf16, qpart);
  qproj_kernel<<<dim3(BH), dim3(128), 0, stream>>>(qpart, projb, qpbuf);
  kscore_kernel<<<dim3(BH * NBLK), dim3(256), 0, stream>>>(k_ws, projb, qpbuf, scores);
  topk_kernel<<<dim3(BH), dim3(64), 0, stream>>>(scores, idxb);

  // attn v9: per-lane ls partials, raw v_exp softmax, lazy max-reduce defer
  attn_mfma_kernel<<<dim3(BH * 32), dim3(256), 0, stream>>>(qf16, kf16, vt, idxb, yf16);

  // O: fp16 x1 on yf16 and Wo-f16
  split_f16_kernel<<<dim3(nw4 / 256), dim3(256), 0, stream>>>(Wo, wo, nw4);
  mfma_gemm_f16<1><<<dim3(16, 32), dim3(256), 0, stream>>>(yf16, wo, out);
}

// Round 20
// 422.768 us; speedup vs baseline: 1.0582x; 1.0144x over previous
//
#include <hip/hip_runtime.h>
#include <hip/hip_bf16.h>

#define B_ 2
#define S_ 2048
#define DM 2048
#define H_ 16
#define DH 128
#define NBLK 32
#define NKEEP 18
#define BH (B_ * H_)

typedef __attribute__((ext_vector_type(8))) short short8;
typedef __attribute__((ext_vector_type(8))) _Float16 f16x8;
typedef __attribute__((ext_vector_type(4))) _Float16 f16x4;
typedef __attribute__((ext_vector_type(4))) float f32x4;

#define GLOAD16(gp, lp)                                                        \
  __builtin_amdgcn_global_load_lds(                                            \
      (const __attribute__((address_space(1))) unsigned int*)(const void*)(gp),\
      (__attribute__((address_space(3))) unsigned int*)(void*)(lp), 16, 0, 0)

__device__ __forceinline__ unsigned short f32_to_bf16(float f) {
  unsigned u = __float_as_uint(f);
  unsigned r = (u + 0x7fffu + ((u >> 16) & 1u)) >> 16;
  return (unsigned short)r;
}
__device__ __forceinline__ float bf16_to_f32(unsigned short h) {
  return __uint_as_float(((unsigned)h) << 16);
}
// raw HW 2^x (logits pre-scaled into log2 domain); no libm fixup code
__device__ __forceinline__ float fexp2(float x) {
  float r;
  asm("v_exp_f32 %0, %1" : "=v"(r) : "v"(x));
  return r;
}

// ---------------- proj: threefry2x32 (partitionable) + erfinv ----------------
__device__ __forceinline__ unsigned rotl32(unsigned x, int r) {
  return (x << r) | (x >> (32 - r));
}

__device__ __forceinline__ float erfinv_f32(float x) {
  float w = -log1pf(-x * x);
  float p;
  if (w < 5.0f) {
    w -= 2.5f;
    p = 2.81022636e-08f;
    p = fmaf(p, w, 3.43273939e-07f);
    p = fmaf(p, w, -3.5233877e-06f);
    p = fmaf(p, w, -4.39150654e-06f);
    p = fmaf(p, w, 0.00021858087f);
    p = fmaf(p, w, -0.00125372503f);
    p = fmaf(p, w, -0.00417768164f);
    p = fmaf(p, w, 0.246640727f);
    p = fmaf(p, w, 1.50140941f);
  } else {
    w = sqrtf(w) - 3.0f;
    p = -0.000200214257f;
    p = fmaf(p, w, 0.000100950558f);
    p = fmaf(p, w, 0.00134934322f);
    p = fmaf(p, w, -0.00367342844f);
    p = fmaf(p, w, 0.00573950773f);
    p = fmaf(p, w, -0.0076224613f);
    p = fmaf(p, w, 0.00943887047f);
    p = fmaf(p, w, 1.00167406f);
    p = fmaf(p, w, 2.83297682f);
  }
  return p * x;
}

__device__ __forceinline__ float bits_to_normal(unsigned b) {
  float f = __uint_as_float((b >> 9) | 0x3f800000u) - 1.0f;
  const float lo = -0.9999999403953552f;
  float u = fmaxf(lo, fmaf(f, 2.0f, lo));
  return 1.4142135623730951f * erfinv_f32(u);
}

__global__ void proj_kernel(float* __restrict__ proj) {
  int i = blockIdx.x * blockDim.x + threadIdx.x;
  if (i >= 4096) return;
  unsigned k0 = 0u, k1 = 42u;
  unsigned k2 = 0x1BD11BDAu ^ k0 ^ k1;
  unsigned x0 = 0u, x1 = (unsigned)i;
  x0 += k0; x1 += k1;
#define QR(r) { x0 += x1; x1 = rotl32(x1, r); x1 ^= x0; }
  QR(13) QR(15) QR(26) QR(6)   x0 += k1; x1 += k2 + 1u;
  QR(17) QR(29) QR(16) QR(24)  x0 += k2; x1 += k0 + 2u;
  QR(13) QR(15) QR(26) QR(6)   x0 += k0; x1 += k1 + 3u;
  QR(17) QR(29) QR(16) QR(24)  x0 += k1; x1 += k2 + 4u;
  QR(13) QR(15) QR(26) QR(6)   x0 += k2; x1 += k0 + 5u;
#undef QR
  proj[i] = bits_to_normal(x0 ^ x1) / 5.656854249492381f;
}

// ---------------- RoPE tables ----------------
__global__ void rope_table_kernel(float* __restrict__ cosb, float* __restrict__ sinb) {
  int s = blockIdx.x;
  int j = threadIdx.x;
  double e = (double)(2 * j) / 128.0;
  double invf = 1.0 / pow(10000.0, e);
  float freq = (float)s * (float)invf;
  cosb[s * 64 + j] = (float)cos((double)freq);
  sinb[s * 64 + j] = (float)sin((double)freq);
}

// ---------------- x -> bf16 hi/lo + fp16, single pass ----------------
__global__ __launch_bounds__(256) void split_x3_kernel(const float* __restrict__ in,
                                                       unsigned short* __restrict__ hi,
                                                       unsigned short* __restrict__ lo,
                                                       _Float16* __restrict__ f16,
                                                       int n4) {
  int i = blockIdx.x * blockDim.x + threadIdx.x;
  if (i >= n4) return;
  float4 v = ((const float4*)in)[i];
  ushort4 hv, lv;
  f16x4 fv;
  hv.x = f32_to_bf16(v.x); lv.x = f32_to_bf16(v.x - bf16_to_f32(hv.x)); fv[0] = (_Float16)v.x;
  hv.y = f32_to_bf16(v.y); lv.y = f32_to_bf16(v.y - bf16_to_f32(hv.y)); fv[1] = (_Float16)v.y;
  hv.z = f32_to_bf16(v.z); lv.z = f32_to_bf16(v.z - bf16_to_f32(hv.z)); fv[2] = (_Float16)v.z;
  hv.w = f32_to_bf16(v.w); lv.w = f32_to_bf16(v.w - bf16_to_f32(hv.w)); fv[3] = (_Float16)v.w;
  ((ushort4*)hi)[i] = hv;
  ((ushort4*)lo)[i] = lv;
  ((f16x4*)f16)[i] = fv;
}

// ---------------- fused W split: Wk -> bf16 hi/lo; Wq, Wv -> fp16 ----------
__global__ __launch_bounds__(256) void split_w3_kernel(const float* __restrict__ wk,
                                                       const float* __restrict__ wq,
                                                       const float* __restrict__ wv,
                                                       unsigned short* __restrict__ khi,
                                                       unsigned short* __restrict__ klo,
                                                       _Float16* __restrict__ qf,
                                                       _Float16* __restrict__ vf,
                                                       int n4) {
  int i = blockIdx.x * blockDim.x + threadIdx.x;
  if (i >= n4) return;
  {
    float4 v = ((const float4*)wk)[i];
    ushort4 hv, lv;
    hv.x = f32_to_bf16(v.x); lv.x = f32_to_bf16(v.x - bf16_to_f32(hv.x));
    hv.y = f32_to_bf16(v.y); lv.y = f32_to_bf16(v.y - bf16_to_f32(hv.y));
    hv.z = f32_to_bf16(v.z); lv.z = f32_to_bf16(v.z - bf16_to_f32(hv.z));
    hv.w = f32_to_bf16(v.w); lv.w = f32_to_bf16(v.w - bf16_to_f32(hv.w));
    ((ushort4*)khi)[i] = hv;
    ((ushort4*)klo)[i] = lv;
  }
  {
    float4 v = ((const float4*)wq)[i];
    f16x4 fv;
    fv[0] = (_Float16)v.x; fv[1] = (_Float16)v.y;
    fv[2] = (_Float16)v.z; fv[3] = (_Float16)v.w;
    ((f16x4*)qf)[i] = fv;
  }
  {
    float4 v = ((const float4*)wv)[i];
    f16x4 fv;
    fv[0] = (_Float16)v.x; fv[1] = (_Float16)v.y;
    fv[2] = (_Float16)v.z; fv[3] = (_Float16)v.w;
    ((f16x4*)vf)[i] = fv;
  }
}

// ---------------- W -> fp16 (Wo, late) ----------------
__global__ __launch_bounds__(256) void split_f16_kernel(const float* __restrict__ in,
                                                        _Float16* __restrict__ f16,
                                                        int n4) {
  int i = blockIdx.x * blockDim.x + threadIdx.x;
  if (i >= n4) return;
  float4 v = ((const float4*)in)[i];
  f16x4 fv;
  fv[0] = (_Float16)v.x; fv[1] = (_Float16)v.y;
  fv[2] = (_Float16)v.z; fv[3] = (_Float16)v.w;
  ((f16x4*)f16)[i] = fv;
}

// ---------------- k-GEMM: bf16x3, 256x256, 8 waves, SPLIT-K=2, 4-phase ------
__global__ __launch_bounds__(512, 2) void mfma_gemm_k_sk(const unsigned short* __restrict__ Ahi,
                                                         const unsigned short* __restrict__ Alo,
                                                         const unsigned short* __restrict__ Whi,
                                                         const unsigned short* __restrict__ Wlo,
                                                         float* __restrict__ kp0,
                                                         float* __restrict__ kp1) {
  __shared__ char smem[131072];  // 2 buf x 64K: Ahi 0|Alo 16K|Bhi 32K|Blo 48K
  const int t = threadIdx.x, l = t & 63, w = t >> 6;  // 8 waves
  const int lin = blockIdx.z * 128 + blockIdx.y * 8 + blockIdx.x;
  const int swz = (lin & 7) * 32 + (lin >> 3);        // 256 blocks, bijective
  const int kz = swz >> 7;
  const int idx = swz & 127;
  const int n0 = (idx & 7) * 256;
  const int m0 = (idx >> 3) * 256;
  const int kbase = kz * 1024;
  float* C = kz ? kp1 : kp0;
  const int wm = w >> 2, wn = w & 3;                  // 2M x 4N wave grid
  const int lr = l & 15;
  const int lg8 = (l >> 4) * 8;
  const size_t rstep = (size_t)16 * DM;

  const unsigned short* gAh = Ahi + (size_t)(m0 + w * 32 + lr) * DM + lg8;
  const unsigned short* gAl = Alo + (size_t)(m0 + w * 32 + lr) * DM + lg8;
  const unsigned short* gBh = Whi + (size_t)(n0 + w * 32 + lr) * DM + lg8;
  const unsigned short* gBl = Wlo + (size_t)(n0 + w * 32 + lr) * DM + lg8;

  f32x4 acc[8][4];
#pragma unroll
  for (int i = 0; i < 8; ++i)
#pragma unroll
    for (int j = 0; j < 4; ++j) acc[i][j] = (f32x4){0.f, 0.f, 0.f, 0.f};

  {  // prologue: full stage of tile 0 into buf 0
    char* base = smem + w * 2048;
    GLOAD16(gAh + kbase, base);
    GLOAD16(gAh + rstep + kbase, base + 1024);
    GLOAD16(gAl + kbase, base + 16384);
    GLOAD16(gAl + rstep + kbase, base + 16384 + 1024);
    GLOAD16(gBh + kbase, base + 32768);
    GLOAD16(gBh + rstep + kbase, base + 32768 + 1024);
    GLOAD16(gBl + kbase, base + 49152);
    GLOAD16(gBl + rstep + kbase, base + 49152 + 1024);
  }
  int cur = 0;

#define KQUAD(q)                                                                        \
  {                                                                                     \
    short8 ah0 = *(const short8*)(buf + (wm * 8 + 2 * (q)) * 1024 + l * 16);            \
    short8 ah1 = *(const short8*)(buf + (wm * 8 + 2 * (q) + 1) * 1024 + l * 16);        \
    short8 al0 = *(const short8*)(buf + 16384 + (wm * 8 + 2 * (q)) * 1024 + l * 16);    \
    short8 al1 = *(const short8*)(buf + 16384 + (wm * 8 + 2 * (q) + 1) * 1024 + l * 16);\
    __builtin_amdgcn_s_setprio(1);                                                      \
    _Pragma("unroll")                                                                   \
    for (int n = 0; n < 4; ++n) {                                                       \
      acc[2 * (q)][n] = __builtin_amdgcn_mfma_f32_16x16x32_bf16(ah0, bh[n], acc[2 * (q)][n], 0, 0, 0); \
      acc[2 * (q)][n] = __builtin_amdgcn_mfma_f32_16x16x32_bf16(ah0, bl[n], acc[2 * (q)][n], 0, 0, 0); \
      acc[2 * (q)][n] = __builtin_amdgcn_mfma_f32_16x16x32_bf16(al0, bh[n], acc[2 * (q)][n], 0, 0, 0); \
    }                                                                                   \
    _Pragma("unroll")                                                                   \
    for (int n = 0; n < 4; ++n) {                                                       \
      acc[2 * (q) + 1][n] = __builtin_amdgcn_mfma_f32_16x16x32_bf16(ah1, bh[n], acc[2 * (q) + 1][n], 0, 0, 0); \
      acc[2 * (q) + 1][n] = __builtin_amdgcn_mfma_f32_16x16x32_bf16(ah1, bl[n], acc[2 * (q) + 1][n], 0, 0, 0); \
      acc[2 * (q) + 1][n] = __builtin_amdgcn_mfma_f32_16x16x32_bf16(al1, bh[n], acc[2 * (q) + 1][n], 0, 0, 0); \
    }                                                                                   \
    __builtin_amdgcn_s_setprio(0);                                                      \
  }

  for (int k0 = kbase; k0 < kbase + 1024; k0 += 32) {
    const bool more = (k0 + 32 < kbase + 1024);
    char* buf = smem + cur * 65536;
    char* nb = smem + (cur ^ 1) * 65536 + w * 2048;
    const int kn = k0 + 32;

    if (more) {
      GLOAD16(gBh + kn, nb + 32768);
      GLOAD16(gBh + rstep + kn, nb + 32768 + 1024);
      asm volatile("s_waitcnt vmcnt(2)" ::: "memory");
    } else {
      asm volatile("s_waitcnt vmcnt(0)" ::: "memory");
    }
    __builtin_amdgcn_s_barrier();

    short8 bh[4], bl[4];
#pragma unroll
    for (int f = 0; f < 4; ++f) {
      bh[f] = *(const short8*)(buf + 32768 + (wn * 4 + f) * 1024 + l * 16);
      bl[f] = *(const short8*)(buf + 49152 + (wn * 4 + f) * 1024 + l * 16);
    }
    KQUAD(0);
    __builtin_amdgcn_s_barrier();

    if (more) {
      GLOAD16(gBl + kn, nb + 49152);
      GLOAD16(gBl + rstep + kn, nb + 49152 + 1024);
    }
    KQUAD(1);
    __builtin_amdgcn_s_barrier();

    if (more) {
      GLOAD16(gAh + kn, nb);
      GLOAD16(gAh + rstep + kn, nb + 1024);
    }
    KQUAD(2);
    __builtin_amdgcn_s_barrier();

    if (more) {
      GLOAD16(gAl + kn, nb + 16384);
      GLOAD16(gAl + rstep + kn, nb + 16384 + 1024);
    }
    KQUAD(3);
    __builtin_amdgcn_s_barrier();

    cur ^= 1;
  }
#undef KQUAD

#pragma unroll
  for (int m = 0; m < 8; ++m) {
    int row0 = m0 + wm * 128 + m * 16 + (l >> 4) * 4;
#pragma unroll
    for (int n = 0; n < 4; ++n) {
      int col = n0 + wn * 64 + n * 16 + (l & 15);
      int h = col >> 7, d = col & 127;
#pragma unroll
      for (int r = 0; r < 4; ++r) {
        int mm = row0 + r;
        int b = mm >> 11, s = mm & (S_ - 1);
        C[(((size_t)(b * H_ + h) * S_) + s) * DH + d] = acc[m][n][r];
      }
    }
  }
}

// ---------------- fused q+V fp16 GEMM: 256x256, 8 waves, 2-phase ------------
__global__ __launch_bounds__(512, 2) void mfma_gemm_qv(const _Float16* __restrict__ A,
                                                       const _Float16* __restrict__ W,
                                                       float* __restrict__ Cq,
                                                       _Float16* __restrict__ vt) {
  __shared__ char smem[65536];  // 2 buf x 32K: A frags 0..16K | B frags 16..32K
  const int t = threadIdx.x, l = t & 63, w = t >> 6;  // 8 waves
  const int lin = blockIdx.y * gridDim.x + blockIdx.x;
  const int swz = (lin & 7) * 32 + (lin >> 3);        // 256 blocks, bijective
  const int n0 = (swz & 15) * 256;
  const int m0 = (swz >> 4) * 256;
  const int wm = w >> 2, wn = w & 3;                  // 2M x 4N wave grid
  const int lr = l & 15;
  const int lg8 = (l >> 4) * 8;
  const size_t rstep = (size_t)16 * DM;

  const _Float16* gA = A + (size_t)(m0 + w * 32 + lr) * DM + lg8;
  const _Float16* gB = W + (size_t)(n0 + w * 32 + lr) * DM + lg8;

  f32x4 acc[8][4];
#pragma unroll
  for (int i = 0; i < 8; ++i)
#pragma unroll
    for (int j = 0; j < 4; ++j) acc[i][j] = (f32x4){0.f, 0.f, 0.f, 0.f};

  {  // prologue
    char* base = smem + w * 2048;
    GLOAD16(gA, base);
    GLOAD16(gA + rstep, base + 1024);
    GLOAD16(gB, base + 16384);
    GLOAD16(gB + rstep, base + 16384 + 1024);
  }
  int cur = 0;

  for (int k0 = 0; k0 < DM; k0 += 32) {
    const bool more = (k0 + 32 < DM);
    char* buf = smem + cur * 32768;
    char* nb = smem + (cur ^ 1) * 32768 + w * 2048;
    const int kn = k0 + 32;

    // phase 0: stage next A pair; wait current; read B; m-frags 0..3
    if (more) {
      GLOAD16(gA + kn, nb);
      GLOAD16(gA + rstep + kn, nb + 1024);
      asm volatile("s_waitcnt vmcnt(2)" ::: "memory");
    } else {
      asm volatile("s_waitcnt vmcnt(0)" ::: "memory");
    }
    __builtin_amdgcn_s_barrier();

    f16x8 b[4];
#pragma unroll
    for (int j = 0; j < 4; ++j)
      b[j] = *(const f16x8*)(buf + 16384 + (wn * 4 + j) * 1024 + l * 16);
    __builtin_amdgcn_s_setprio(1);
#pragma unroll
    for (int i = 0; i < 4; ++i) {
      f16x8 a = *(const f16x8*)(buf + (wm * 8 + i) * 1024 + l * 16);
#pragma unroll
      for (int j = 0; j < 4; ++j)
        acc[i][j] = __builtin_amdgcn_mfma_f32_16x16x32_f16(a, b[j], acc[i][j], 0, 0, 0);
    }
    __builtin_amdgcn_s_setprio(0);
    __builtin_amdgcn_s_barrier();

    // phase 1: stage next B pair; m-frags 4..7
    if (more) {
      GLOAD16(gB + kn, nb + 16384);
      GLOAD16(gB + rstep + kn, nb + 16384 + 1024);
    }
    __builtin_amdgcn_s_setprio(1);
#pragma unroll
    for (int i = 4; i < 8; ++i) {
      f16x8 a = *(const f16x8*)(buf + (wm * 8 + i) * 1024 + l * 16);
#pragma unroll
      for (int j = 0; j < 4; ++j)
        acc[i][j] = __builtin_amdgcn_mfma_f32_16x16x32_f16(a, b[j], acc[i][j], 0, 0, 0);
    }
    __builtin_amdgcn_s_setprio(0);
    __builtin_amdgcn_s_barrier();

    cur ^= 1;
  }

#pragma unroll
  for (int m = 0; m < 8; ++m) {
    int row0 = m0 + wm * 128 + m * 16 + (l >> 4) * 4;
#pragma unroll
    for (int n = 0; n < 4; ++n) {
      int col = n0 + wn * 64 + n * 16 + (l & 15);
      if (col < DM) {
        int h = col >> 7, d = col & 127;
#pragma unroll
        for (int r = 0; r < 4; ++r) {
          int mm = row0 + r;
          int b2 = mm >> 11, s = mm & (S_ - 1);
          Cq[(((size_t)(b2 * H_ + h) * S_) + s) * DH + d] = acc[m][n][r];
        }
      } else {
        int vcol = col - DM;
        int h = vcol >> 7, d = vcol & 127;
        int b2 = row0 >> 11, s0 = row0 & (S_ - 1);
        f16x4 vv;
        vv[0] = (_Float16)acc[m][n][0];
        vv[1] = (_Float16)acc[m][n][1];
        vv[2] = (_Float16)acc[m][n][2];
        vv[3] = (_Float16)acc[m][n][3];
        *(f16x4*)(vt + (((size_t)(b2 * H_ + h)) * DH + d) * S_ + s0) = vv;
      }
    }
  }
}

// ---------------- fp16 single-product GEMM (O), BK=64, 128x128 --------------
template <int MODE>
__global__ __launch_bounds__(256) void mfma_gemm_f16(const _Float16* __restrict__ A,
                                                     const _Float16* __restrict__ W,
                                                     void* __restrict__ Cout) {
  __shared__ char smem[65536];
  const int t = threadIdx.x, l = t & 63, w = t >> 6;
  const int lin = blockIdx.y * gridDim.x + blockIdx.x;
  const int cpx = (gridDim.x * gridDim.y) >> 3;
  const int swz = (lin & 7) * cpx + (lin >> 3);
  const int n0 = (swz % gridDim.x) * 128;
  const int m0 = (swz / gridDim.x) * 128;
  const int wm = w >> 1, wn = w & 1;
  const int lr = l & 15;
  const int lg8 = (l >> 4) * 8;

  auto STAGE = [&](int k0, int c) {
    char* base = smem + c * 32768;
#pragma unroll
    for (int f0 = 0; f0 < 4; ++f0) {
      int f = w * 4 + f0;
      int rb = f >> 1, kh = f & 1;
      GLOAD16(A + (size_t)(m0 + rb * 16 + lr) * DM + k0 + kh * 32 + lg8,
              base + f * 1024);
      GLOAD16(W + (size_t)(n0 + rb * 16 + lr) * DM + k0 + kh * 32 + lg8,
              base + 16384 + f * 1024);
    }
  };

  f32x4 acc[4][4];
#pragma unroll
  for (int i = 0; i < 4; ++i)
#pragma unroll
    for (int j = 0; j < 4; ++j) acc[i][j] = (f32x4){0.f, 0.f, 0.f, 0.f};

  STAGE(0, 0);
  int cur = 0;

  for (int k0 = 0; k0 < DM; k0 += 64) {
    if (k0 + 64 < DM) {
      STAGE(k0 + 64, cur ^ 1);
      asm volatile("s_waitcnt vmcnt(8)" ::: "memory");
    } else {
      asm volatile("s_waitcnt vmcnt(0)" ::: "memory");
    }
    __builtin_amdgcn_s_barrier();

    char* buf = smem + cur * 32768;
    f16x8 a[4][2], b[4][2];
#pragma unroll
    for (int i = 0; i < 4; ++i)
#pragma unroll
      for (int kh = 0; kh < 2; ++kh) {
        a[i][kh] = *(const f16x8*)(buf + ((wm * 4 + i) * 2 + kh) * 1024 + l * 16);
        b[i][kh] = *(const f16x8*)(buf + 16384 + ((wn * 4 + i) * 2 + kh) * 1024 + l * 16);
      }
    __builtin_amdgcn_s_setprio(1);
#pragma unroll
    for (int i = 0; i < 4; ++i)
#pragma unroll
      for (int j = 0; j < 4; ++j) {
        acc[i][j] = __builtin_amdgcn_mfma_f32_16x16x32_f16(a[i][0], b[j][0], acc[i][j], 0, 0, 0);
        acc[i][j] = __builtin_amdgcn_mfma_f32_16x16x32_f16(a[i][1], b[j][1], acc[i][j], 0, 0, 0);
      }
    __builtin_amdgcn_s_setprio(0);
    __builtin_amdgcn_s_barrier();
    cur ^= 1;
  }

#pragma unroll
  for (int i = 0; i < 4; ++i) {
    int row0 = m0 + wm * 64 + i * 16 + (l >> 4) * 4;
#pragma unroll
    for (int j = 0; j < 4; ++j) {
      int col = n0 + wn * 64 + j * 16 + (l & 15);
      if constexpr (MODE == 1) {
        float* C = (float*)Cout;
#pragma unroll
        for (int r = 0; r < 4; ++r)
          C[(size_t)(row0 + r) * DM + col] = acc[i][j][r];
      }
    }
  }
}

// ---------------- RMSNorm + RoPE for K: sums split-K partials, emits fp16 ---
__global__ __launch_bounds__(256) void rmsrope_k_kernel(float* __restrict__ k,
                                                        const float* __restrict__ kp1,
                                                        _Float16* __restrict__ kf,
                                                        const float* __restrict__ cosb,
                                                        const float* __restrict__ sinb) {
  int w = threadIdx.x >> 6;
  int lane = threadIdx.x & 63;
  long r = (long)blockIdx.x * 4 + w;
  float* p = k + r * DH;
  const float* p1 = kp1 + r * DH;
  int s = (int)(r & (S_ - 1));
  float x1 = p[lane] + p1[lane];
  float x2 = p[lane + 64] + p1[lane + 64];
  float ss = fmaf(x1, x1, x2 * x2);
#pragma unroll
  for (int off = 32; off; off >>= 1) ss += __shfl_xor(ss, off);
  float rms = rsqrtf(ss * (1.0f / 128.0f) + 1e-6f);
  float n1 = x1 * rms, n2 = x2 * rms;
  float c = cosb[s * 64 + lane], sn = sinb[s * 64 + lane];
  float o1 = fmaf(n1, c, n2 * sn);
  float o2 = fmaf(-n1, sn, n2 * c);
  p[lane] = o1;
  p[lane + 64] = o2;
  kf[r * DH + lane] = (_Float16)o1;
  kf[r * DH + lane + 64] = (_Float16)o2;
}

// ---------------- RMSNorm + RoPE + gain for Q: emits fp16 scaled by ---------
// SC = (1/sqrt(128))*log2(e) so attn logits land in log2 domain. The uniform
// positive SC cancels exactly in selection's _normalize(mean @ proj).
__global__ __launch_bounds__(256) void rmsrope_q_kernel(const float* __restrict__ q,
                                                        _Float16* __restrict__ qf,
                                                        const float* __restrict__ cosb,
                                                        const float* __restrict__ sinb,
                                                        const float* __restrict__ qg) {
  const float SC = 0.12751743f;  // 1/sqrt(128) * log2(e)
  int w = threadIdx.x >> 6;
  int lane = threadIdx.x & 63;
  long r = (long)blockIdx.x * 4 + w;
  const float* p = q + r * DH;
  int s = (int)(r & (S_ - 1));
  int h = (int)((r >> 11) & (H_ - 1));
  float x1 = p[lane], x2 = p[lane + 64];
  float ss = fmaf(x1, x1, x2 * x2);
#pragma unroll
  for (int off = 32; off; off >>= 1) ss += __shfl_xor(ss, off);
  float rms = rsqrtf(ss * (1.0f / 128.0f) + 1e-6f);
  float n1 = x1 * rms, n2 = x2 * rms;
  float c = cosb[s * 64 + lane], sn = sinb[s * 64 + lane];
  float g = qg[h] * SC;
  float o1 = fmaf(n1, c, n2 * sn) * g;
  float o2 = fmaf(-n1, sn, n2 * c) * g;
  qf[r * DH + lane] = (_Float16)o1;
  qf[r * DH + lane + 64] = (_Float16)o2;
}

// ---------------- selection phase 1: q-mean partial sums (fp16 q) -----------
__global__ __launch_bounds__(256) void qmean_part_kernel(const _Float16* __restrict__ qf,
                                                         float* __restrict__ partial) {
  __shared__ float red[256];
  const int bh = blockIdx.x >> 4, chunk = blockIdx.x & 15;
  const int t = threadIdx.x;
  const int d = t & 127, half = t >> 7;
  const _Float16* qb = qf + ((size_t)bh * S_ + chunk * 128 + half * 64) * DH;
  float sum = 0.0f;
#pragma unroll 4
  for (int s = 0; s < 64; ++s) sum += (float)qb[(size_t)s * DH + d];
  red[t] = sum;
  __syncthreads();
  if (t < 128) partial[(size_t)blockIdx.x * 128 + t] = red[t] + red[t + 128];
}

// ---------------- selection phase 2: finish mean, project, normalize --------
__global__ void qproj_kernel(const float* __restrict__ partial,
                             const float* __restrict__ proj,
                             float* __restrict__ qp) {
  __shared__ float meanq[128];
  __shared__ float qps[32];
  __shared__ float nrm;
  const int bh = blockIdx.x, t = threadIdx.x;
  float s = 0.0f;
#pragma unroll
  for (int c = 0; c < 16; ++c) s += partial[((size_t)bh * 16 + c) * 128 + t];
  meanq[t] = s * (1.0f / 2048.0f);
  __syncthreads();
  if (t < 32) {
    float sum = 0.0f;
    for (int d = 0; d < 128; ++d) sum = fmaf(meanq[d], proj[d * 32 + t], sum);
    qps[t] = sum;
  }
  __syncthreads();
  if (t == 0) {
    float sum = 0.0f;
    for (int j = 0; j < 32; ++j) sum += qps[j] * qps[j];
    nrm = 1.0f / fmaxf(sqrtf(sum), 1e-12f);
  }
  __syncthreads();
  if (t < 32) qp[bh * 32 + t] = qps[t] * nrm;
}

// ---------------- selection phase 3: per-(bh,block) score ----------------
__global__ __launch_bounds__(256) void kscore_kernel(const float* __restrict__ k,
                                                     const float* __restrict__ proj,
                                                     const float* __restrict__ qp,
                                                     float* __restrict__ scores) {
  __shared__ float ps[128][32];
  __shared__ float kp[64][33];
  __shared__ float cent[33];
  __shared__ float nrm;
  const int bh = blockIdx.x >> 5, n = blockIdx.x & 31;
  const int t = threadIdx.x;
  for (int i = t; i < 4096; i += 256) ps[i >> 5][i & 31] = proj[i];
  const float* kn = k + ((size_t)bh * S_ + n * 64) * DH;
  __syncthreads();
  {
    int row = t >> 2, j0 = (t & 3) * 8;
    float accv[8];
#pragma unroll
    for (int jj = 0; jj < 8; ++jj) accv[jj] = 0.0f;
#pragma unroll 4
    for (int d = 0; d < 128; ++d) {
      float kv = kn[(size_t)row * DH + d];
#pragma unroll
      for (int jj = 0; jj < 8; ++jj) accv[jj] = fmaf(kv, ps[d][j0 + jj], accv[jj]);
    }
#pragma unroll
    for (int jj = 0; jj < 8; ++jj) kp[row][j0 + jj] = accv[jj];
  }
  __syncthreads();
  if (t < 64) {
    float sum = 0.0f;
    for (int j = 0; j < 32; ++j) sum += kp[t][j] * kp[t][j];
    float scl = 1.0f / fmaxf(sqrtf(sum), 1e-12f);
    for (int j = 0; j < 32; ++j) kp[t][j] *= scl;
  }
  __syncthreads();
  if (t < 32) {
    float sum = 0.0f;
    for (int r2 = 0; r2 < 64; ++r2) sum += kp[r2][t];
    cent[t] = sum * (1.0f / 64.0f);
  }
  __syncthreads();
  if (t == 0) {
    float sum = 0.0f;
    for (int j = 0; j < 32; ++j) sum += cent[j] * cent[j];
    nrm = 1.0f / fmaxf(sqrtf(sum), 1e-12f);
  }
  __syncthreads();
  if (t < 32) cent[t] *= nrm;
  __syncthreads();
  if (t < 64) {
    float dt = 0.0f;
    for (int j = 0; j < 32; ++j) dt = fmaf(kp[t][j], cent[j], dt);
#pragma unroll
    for (int off = 32; off; off >>= 1) dt = fminf(dt, __shfl_xor(dt, off));
    if (t == 0) {
      float radius = fminf(fmaxf(1.0f - dt, 0.0f), 1.0f);
      float dq = 0.0f;
      for (int j = 0; j < 32; ++j) dq = fmaf(qp[bh * 32 + j], cent[j], dq);
      scores[bh * 32 + n] = dq + radius;
    }
  }
}

// ---------------- selection phase 4: top-18 + sort ----------------
__global__ void topk_kernel(const float* __restrict__ scores, int* __restrict__ top_idx) {
  if (threadIdx.x != 0) return;
  const int bh = blockIdx.x;
  float sc[NBLK];
  for (int j = 0; j < NBLK; ++j) sc[j] = scores[bh * 32 + j];
  sc[NBLK - 2] = INFINITY;
  sc[NBLK - 1] = INFINITY;
  int chosen[NKEEP];
  bool used[NBLK];
  for (int j = 0; j < NBLK; ++j) used[j] = false;
  for (int kk = 0; kk < NKEEP; ++kk) {
    int best = -1;
    float bv = 0.0f;
    for (int j = 0; j < NBLK; ++j)
      if (!used[j] && (best < 0 || sc[j] > bv)) { bv = sc[j]; best = j; }
    used[best] = true;
    chosen[kk] = best;
  }
  for (int a = 1; a < NKEEP; ++a) {
    int v2 = chosen[a], b2 = a - 1;
    while (b2 >= 0 && chosen[b2] > v2) { chosen[b2 + 1] = chosen[b2]; --b2; }
    chosen[b2 + 1] = v2;
  }
  for (int a = 0; a < NKEEP; ++a) top_idx[bh * NKEEP + a] = chosen[a];
}

// ---------------- MFMA attention v9: per-lane ls partials (deferred reduce) -
__global__ __launch_bounds__(256) void attn_mfma_kernel(const _Float16* __restrict__ qfp,
                                                        const _Float16* __restrict__ kf,
                                                        const _Float16* __restrict__ vt,
                                                        const int* __restrict__ top_idx,
                                                        _Float16* __restrict__ yf) {
  __shared__ char lds[74752];  // buf0 0..32K (K 16K|V 16K), buf1 32..64K, P 64K..
  const int bh = blockIdx.x >> 5;
  const int qt = blockIdx.x & 31;
  const int t = threadIdx.x, l = t & 63, w = t >> 6;
  const int lr = l & 15, lg = l >> 4;
  const float THR2 = 11.5415603f;  // 8 * log2(e)

  f16x8 qf[4];
  {
    const _Float16* qbase = qfp + ((size_t)(bh * S_ + qt * 64 + w * 16 + lr)) * DH + lg * 8;
#pragma unroll
    for (int dc = 0; dc < 4; ++dc)
      qf[dc] = *(const f16x8*)(qbase + dc * 32);
  }

  float m_[4] = {-INFINITY, -INFINITY, -INFINITY, -INFINITY};
  float ls[4] = {0.f, 0.f, 0.f, 0.f};  // PER-LANE partial sums
  f32x4 yacc[8];
#pragma unroll
  for (int dt = 0; dt < 8; ++dt) yacc[dt] = (f32x4){0.f, 0.f, 0.f, 0.f};

  char* Pw = lds + 65536 + w * 2304;  // per-wave P: [16 q][72 fp16]

  const _Float16* kb0 = kf + (size_t)bh * S_ * DH;
  const _Float16* vb0 = vt + (size_t)bh * DH * S_;
  const int* idxp = top_idx + bh * NKEEP;

  auto STAGE = [&](int blk, int c) {
    char* base = lds + c * 32768;
#pragma unroll
    for (int f0 = 0; f0 < 4; ++f0) {
      int f = w * 4 + f0;
      int kt = f >> 2, dc = f & 3;
      GLOAD16(kb0 + (size_t)(blk * 64 + kt * 16 + lr) * DH + dc * 32 + lg * 8,
              base + f * 1024);
      int K0 = f >> 3, dt = f & 7;
      GLOAD16(vb0 + (size_t)(dt * 16 + lr) * S_ + blk * 64 + K0 * 32 + lg * 8,
              base + 16384 + f * 1024);
    }
  };

  int cur = 0;
  STAGE(idxp[0], 0);

  for (int it = 0; it < NKEEP; ++it) {
    if (it + 1 < NKEEP) {
      STAGE(idxp[it + 1], cur ^ 1);
      asm volatile("s_waitcnt vmcnt(8)" ::: "memory");
    } else {
      asm volatile("s_waitcnt vmcnt(0)" ::: "memory");
    }
    __builtin_amdgcn_s_barrier();
    char* buf = lds + cur * 32768;

    f32x4 sacc[4];
#pragma unroll
    for (int kt = 0; kt < 4; ++kt) sacc[kt] = (f32x4){0.f, 0.f, 0.f, 0.f};
    __builtin_amdgcn_s_setprio(1);
#pragma unroll
    for (int kt = 0; kt < 4; ++kt)
#pragma unroll
      for (int dc = 0; dc < 4; ++dc) {
        f16x8 kfr = *(const f16x8*)(buf + (kt * 4 + dc) * 1024 + l * 16);
        sacc[kt] = __builtin_amdgcn_mfma_f32_16x16x32_f16(qf[dc], kfr, sacc[kt], 0, 0, 0);
      }
    __builtin_amdgcn_s_setprio(0);

    // per-lane LOCAL max (no reduce); __all makes the defer decision exactly
    // equivalent to the row-max check (row max = max over lanes of local max)
    float lmax[4];
#pragma unroll
    for (int r = 0; r < 4; ++r)
      lmax[r] = fmaxf(fmaxf(sacc[0][r], sacc[1][r]), fmaxf(sacc[2][r], sacc[3][r]));
    bool ok = (lmax[0] <= m_[0] + THR2) && (lmax[1] <= m_[1] + THR2) &&
              (lmax[2] <= m_[2] + THR2) && (lmax[3] <= m_[3] + THR2);
    float p[4][4];
    if (__all(ok)) {
      // defer-max: keep old max; accumulate per-lane ls partials (no shuffles)
#pragma unroll
      for (int r = 0; r < 4; ++r) {
#pragma unroll
        for (int kt = 0; kt < 4; ++kt) {
          p[kt][r] = fexp2(sacc[kt][r] - m_[r]);
          ls[r] += p[kt][r];
        }
      }
    } else {
#pragma unroll
      for (int r = 0; r < 4; ++r) {
        float mv = lmax[r];
#pragma unroll
        for (int off = 1; off < 16; off <<= 1) mv = fmaxf(mv, __shfl_xor(mv, off));
        float mn = fmaxf(m_[r], mv);
        float corr = fexp2(m_[r] - mn);   // uniform across the row's lanes
        float rs = 0.f;
#pragma unroll
        for (int kt = 0; kt < 4; ++kt) {
          p[kt][r] = fexp2(sacc[kt][r] - mn);
          rs += p[kt][r];
        }
        ls[r] = ls[r] * corr + rs;        // per-lane partial, scaled uniformly
        m_[r] = mn;
#pragma unroll
        for (int dt = 0; dt < 8; ++dt) yacc[dt][r] *= corr;
      }
    }

#pragma unroll
    for (int kt = 0; kt < 4; ++kt)
#pragma unroll
      for (int r = 0; r < 4; ++r)
        *(_Float16*)(Pw + (lg * 4 + r) * 144 + (kt * 16 + lr) * 2) = (_Float16)p[kt][r];

    __builtin_amdgcn_s_setprio(1);
#pragma unroll
    for (int K0 = 0; K0 < 2; ++K0) {
      f16x8 pa = *(const f16x8*)(Pw + lr * 144 + K0 * 64 + lg * 16);
#pragma unroll
      for (int dt = 0; dt < 8; ++dt) {
        f16x8 vf = *(const f16x8*)(buf + 16384 + (K0 * 8 + dt) * 1024 + l * 16);
        yacc[dt] = __builtin_amdgcn_mfma_f32_16x16x32_f16(pa, vf, yacc[dt], 0, 0, 0);
      }
    }
    __builtin_amdgcn_s_setprio(0);

    __builtin_amdgcn_s_barrier();
    cur ^= 1;
  }

  // epilogue: reduce per-lane ls partials across the row's 16 lanes (once)
  const int b = bh >> 4, h = bh & (H_ - 1);
  float inv[4];
#pragma unroll
  for (int r = 0; r < 4; ++r) {
    float s = ls[r];
#pragma unroll
    for (int off = 1; off < 16; off <<= 1) s += __shfl_xor(s, off);
    inv[r] = 1.0f / s;
  }
#pragma unroll
  for (int r = 0; r < 4; ++r) {
    int srow = qt * 64 + w * 16 + lg * 4 + r;
    size_t off0 = ((size_t)b * S_ + srow) * DM + h * DH + lr;
#pragma unroll
    for (int dt = 0; dt < 8; ++dt)
      yf[off0 + dt * 16] = (_Float16)(yacc[dt][r] * inv[r]);
  }
}

extern "C" void kernel_launch(void* const* d_in, const int* in_sizes, int n_in,
                              void* d_out, int out_size, void* d_ws, size_t ws_size,
                              hipStream_t stream) {
  const float* x  = (const float*)d_in[0];
  const float* Wq = (const float*)d_in[1];
  const float* Wk = (const float*)d_in[2];
  const float* Wv = (const float*)d_in[3];
  const float* Wo = (const float*)d_in[4];
  const float* qg = (const float*)d_in[5];
  float* out = (float*)d_out;

  const size_t NE = (size_t)BH * S_ * DH;   // 8388608 elements
  const size_t WE = (size_t)DM * DM;        // 4194304 elements per W
  char* p = (char*)d_ws;
  float* q_ws = (float*)p; p += NE * 4;     // kpart1 during k-GEMM, then q f32
  float* k_ws = (float*)p; p += NE * 4;     // kpart0 -> roped k f32
  unsigned short* xhi = (unsigned short*)p; p += NE * 2;  // -> yf16 after k-GEMM
  unsigned short* xlo = (unsigned short*)p; p += NE * 2;  // -> vt after k-GEMM
  _Float16* xf16 = (_Float16*)p; p += NE * 2;             // -> qf16 after qv-GEMM
  unsigned short* wkhi = (unsigned short*)p; p += WE * 2; // \ kf16 spans wkhi+wklo
  unsigned short* wklo = (unsigned short*)p; p += WE * 2; // / (both dead post k-GEMM)
  _Float16* wqv = (_Float16*)p; p += 2 * WE * 2;          // [Wq;Wv] fp16; -> wo
  float* cosb = (float*)p; p += (size_t)S_ * 64 * 4;
  float* sinb = (float*)p; p += (size_t)S_ * 64 * 4;
  float* projb = (float*)p; p += 4096 * 4;
  int* idxb = (int*)p; p += BH * NKEEP * 4;
  float* scores = (float*)p; p += BH * NBLK * 4;
  float* qpbuf = (float*)p; p += BH * 32 * 4;
  // aliases (each with size check, stream-ordered):
  float* qpart = cosb;                   // 262KB <= 1MB; writer after rmsrope_q
  float* kpart1 = q_ws;                  // NE f32 = NE f32; qv writes q after rmsrope_k
  _Float16* kf16 = (_Float16*)wkhi;      // NE fp16 = 16.8MB = wkhi+wklo (16.8MB), both dead
  _Float16* vt = (_Float16*)xlo;         // NE fp16 <= NE ushort; xlo dead after k-GEMM
  _Float16* yf16 = (_Float16*)xhi;       // NE fp16 <= NE ushort; xhi dead after k-GEMM
  _Float16* qf16 = xf16;                 // NE fp16 = NE fp16; xf16 dead after qv-GEMM
  _Float16* wo = wqv;                    // WE fp16 <= 2WE fp16; wqv dead after qv-GEMM
  // total ws use ~152 MB (proven footprint, no growth)

  const int nx4 = (int)(NE / 4);
  const int nw4 = (int)(WE / 4);

  proj_kernel<<<dim3(16), dim3(256), 0, stream>>>(projb);
  rope_table_kernel<<<dim3(S_), dim3(64), 0, stream>>>(cosb, sinb);
  split_x3_kernel<<<dim3(nx4 / 256), dim3(256), 0, stream>>>(x, xhi, xlo, xf16, nx4);
  split_w3_kernel<<<dim3(nw4 / 256), dim3(256), 0, stream>>>(Wk, Wq, Wv, wkhi, wklo,
                                                             wqv, wqv + WE, nw4);

  // k: bf16x3, split-K=2, 8-wave 256^2, 4-phase counted-vmcnt interleave
  mfma_gemm_k_sk<<<dim3(8, 16, 2), dim3(512), 0, stream>>>(xhi, xlo, wkhi, wklo,
                                                           k_ws, kpart1);

  // k finalize: sum partials + RMS + RoPE; writes k f32 (in place) + kf16
  rmsrope_k_kernel<<<dim3((BH * S_) / 4), dim3(256), 0, stream>>>(k_ws, kpart1, kf16, cosb, sinb);

  // q+V fused: fp16, 256^2 8-wave, 2-phase (R18-proven); overwrites kpart1 — safe now
  mfma_gemm_qv<<<dim3(16, 16), dim3(512), 0, stream>>>(xf16, wqv, q_ws, vt);

  // q finalize: RMS + RoPE + gain, emits fp16 q scaled by scale*log2e
  rmsrope_q_kernel<<<dim3((BH * S_) / 4), dim3(256), 0, stream>>>(q_ws, qf16, cosb, sinb, qg);

  qmean_part_kernel<<<dim3(BH * 16), dim3(256), 0, stream>>>(qf16, qpart);
  qproj_kernel<<<dim3(BH), dim3(128), 0, stream>>>(qpart, projb, qpbuf);
  kscore_kernel<<<dim3(BH * NBLK), dim3(256), 0, stream>>>(k_ws, projb, qpbuf, scores);
  topk_kernel<<<dim3(BH), dim3(64), 0, stream>>>(scores, idxb);

  // attn v9: per-lane ls partials, raw v_exp softmax, lazy max-reduce defer
  attn_mfma_kernel<<<dim3(BH * 32), dim3(256), 0, stream>>>(qf16, kf16, vt, idxb, yf16);

  // O: fp16 x1 on yf16 and Wo-f16
  split_f16_kernel<<<dim3(nw4 / 256), dim3(256), 0, stream>>>(Wo, wo, nw4);
  mfma_gemm_f16<1><<<dim3(16, 32), dim3(256), 0, stream>>>(yf16, wo, out);
}

// Round 21
// 418.206 us; speedup vs baseline: 1.0697x; 1.0109x over previous
//
#include <hip/hip_runtime.h>
#include <hip/hip_bf16.h>

#define B_ 2
#define S_ 2048
#define DM 2048
#define H_ 16
#define DH 128
#define NBLK 32
#define NKEEP 18
#define BH (B_ * H_)

typedef __attribute__((ext_vector_type(8))) short short8;
typedef __attribute__((ext_vector_type(8))) _Float16 f16x8;
typedef __attribute__((ext_vector_type(4))) _Float16 f16x4;
typedef __attribute__((ext_vector_type(4))) float f32x4;

#define GLOAD16(gp, lp)                                                        \
  __builtin_amdgcn_global_load_lds(                                            \
      (const __attribute__((address_space(1))) unsigned int*)(const void*)(gp),\
      (__attribute__((address_space(3))) unsigned int*)(void*)(lp), 16, 0, 0)

__device__ __forceinline__ unsigned short f32_to_bf16(float f) {
  unsigned u = __float_as_uint(f);
  unsigned r = (u + 0x7fffu + ((u >> 16) & 1u)) >> 16;
  return (unsigned short)r;
}
__device__ __forceinline__ float bf16_to_f32(unsigned short h) {
  return __uint_as_float(((unsigned)h) << 16);
}
// raw HW 2^x (logits pre-scaled into log2 domain); no libm fixup code
__device__ __forceinline__ float fexp2(float x) {
  float r;
  asm("v_exp_f32 %0, %1" : "=v"(r) : "v"(x));
  return r;
}

// ---------------- proj: threefry2x32 (partitionable) + erfinv ----------------
__device__ __forceinline__ unsigned rotl32(unsigned x, int r) {
  return (x << r) | (x >> (32 - r));
}

__device__ __forceinline__ float erfinv_f32(float x) {
  float w = -log1pf(-x * x);
  float p;
  if (w < 5.0f) {
    w -= 2.5f;
    p = 2.81022636e-08f;
    p = fmaf(p, w, 3.43273939e-07f);
    p = fmaf(p, w, -3.5233877e-06f);
    p = fmaf(p, w, -4.39150654e-06f);
    p = fmaf(p, w, 0.00021858087f);
    p = fmaf(p, w, -0.00125372503f);
    p = fmaf(p, w, -0.00417768164f);
    p = fmaf(p, w, 0.246640727f);
    p = fmaf(p, w, 1.50140941f);
  } else {
    w = sqrtf(w) - 3.0f;
    p = -0.000200214257f;
    p = fmaf(p, w, 0.000100950558f);
    p = fmaf(p, w, 0.00134934322f);
    p = fmaf(p, w, -0.00367342844f);
    p = fmaf(p, w, 0.00573950773f);
    p = fmaf(p, w, -0.0076224613f);
    p = fmaf(p, w, 0.00943887047f);
    p = fmaf(p, w, 1.00167406f);
    p = fmaf(p, w, 2.83297682f);
  }
  return p * x;
}

__device__ __forceinline__ float bits_to_normal(unsigned b) {
  float f = __uint_as_float((b >> 9) | 0x3f800000u) - 1.0f;
  const float lo = -0.9999999403953552f;
  float u = fmaxf(lo, fmaf(f, 2.0f, lo));
  return 1.4142135623730951f * erfinv_f32(u);
}

__global__ void proj_kernel(float* __restrict__ proj) {
  int i = blockIdx.x * blockDim.x + threadIdx.x;
  if (i >= 4096) return;
  unsigned k0 = 0u, k1 = 42u;
  unsigned k2 = 0x1BD11BDAu ^ k0 ^ k1;
  unsigned x0 = 0u, x1 = (unsigned)i;
  x0 += k0; x1 += k1;
#define QR(r) { x0 += x1; x1 = rotl32(x1, r); x1 ^= x0; }
  QR(13) QR(15) QR(26) QR(6)   x0 += k1; x1 += k2 + 1u;
  QR(17) QR(29) QR(16) QR(24)  x0 += k2; x1 += k0 + 2u;
  QR(13) QR(15) QR(26) QR(6)   x0 += k0; x1 += k1 + 3u;
  QR(17) QR(29) QR(16) QR(24)  x0 += k1; x1 += k2 + 4u;
  QR(13) QR(15) QR(26) QR(6)   x0 += k2; x1 += k0 + 5u;
#undef QR
  proj[i] = bits_to_normal(x0 ^ x1) / 5.656854249492381f;
}

// ---------------- RoPE tables ----------------
__global__ void rope_table_kernel(float* __restrict__ cosb, float* __restrict__ sinb) {
  int s = blockIdx.x;
  int j = threadIdx.x;
  double e = (double)(2 * j) / 128.0;
  double invf = 1.0 / pow(10000.0, e);
  float freq = (float)s * (float)invf;
  cosb[s * 64 + j] = (float)cos((double)freq);
  sinb[s * 64 + j] = (float)sin((double)freq);
}

// ---------------- x -> bf16 hi/lo + fp16, single pass ----------------
__global__ __launch_bounds__(256) void split_x3_kernel(const float* __restrict__ in,
                                                       unsigned short* __restrict__ hi,
                                                       unsigned short* __restrict__ lo,
                                                       _Float16* __restrict__ f16,
                                                       int n4) {
  int i = blockIdx.x * blockDim.x + threadIdx.x;
  if (i >= n4) return;
  float4 v = ((const float4*)in)[i];
  ushort4 hv, lv;
  f16x4 fv;
  hv.x = f32_to_bf16(v.x); lv.x = f32_to_bf16(v.x - bf16_to_f32(hv.x)); fv[0] = (_Float16)v.x;
  hv.y = f32_to_bf16(v.y); lv.y = f32_to_bf16(v.y - bf16_to_f32(hv.y)); fv[1] = (_Float16)v.y;
  hv.z = f32_to_bf16(v.z); lv.z = f32_to_bf16(v.z - bf16_to_f32(hv.z)); fv[2] = (_Float16)v.z;
  hv.w = f32_to_bf16(v.w); lv.w = f32_to_bf16(v.w - bf16_to_f32(hv.w)); fv[3] = (_Float16)v.w;
  ((ushort4*)hi)[i] = hv;
  ((ushort4*)lo)[i] = lv;
  ((f16x4*)f16)[i] = fv;
}

// ---------------- fused W split: Wk -> bf16 hi/lo; Wq, Wv -> fp16 ----------
__global__ __launch_bounds__(256) void split_w3_kernel(const float* __restrict__ wk,
                                                       const float* __restrict__ wq,
                                                       const float* __restrict__ wv,
                                                       unsigned short* __restrict__ khi,
                                                       unsigned short* __restrict__ klo,
                                                       _Float16* __restrict__ qf,
                                                       _Float16* __restrict__ vf,
                                                       int n4) {
  int i = blockIdx.x * blockDim.x + threadIdx.x;
  if (i >= n4) return;
  {
    float4 v = ((const float4*)wk)[i];
    ushort4 hv, lv;
    hv.x = f32_to_bf16(v.x); lv.x = f32_to_bf16(v.x - bf16_to_f32(hv.x));
    hv.y = f32_to_bf16(v.y); lv.y = f32_to_bf16(v.y - bf16_to_f32(hv.y));
    hv.z = f32_to_bf16(v.z); lv.z = f32_to_bf16(v.z - bf16_to_f32(hv.z));
    hv.w = f32_to_bf16(v.w); lv.w = f32_to_bf16(v.w - bf16_to_f32(hv.w));
    ((ushort4*)khi)[i] = hv;
    ((ushort4*)klo)[i] = lv;
  }
  {
    float4 v = ((const float4*)wq)[i];
    f16x4 fv;
    fv[0] = (_Float16)v.x; fv[1] = (_Float16)v.y;
    fv[2] = (_Float16)v.z; fv[3] = (_Float16)v.w;
    ((f16x4*)qf)[i] = fv;
  }
  {
    float4 v = ((const float4*)wv)[i];
    f16x4 fv;
    fv[0] = (_Float16)v.x; fv[1] = (_Float16)v.y;
    fv[2] = (_Float16)v.z; fv[3] = (_Float16)v.w;
    ((f16x4*)vf)[i] = fv;
  }
}

// ---------------- W -> fp16 (Wo, late) ----------------
__global__ __launch_bounds__(256) void split_f16_kernel(const float* __restrict__ in,
                                                        _Float16* __restrict__ f16,
                                                        int n4) {
  int i = blockIdx.x * blockDim.x + threadIdx.x;
  if (i >= n4) return;
  float4 v = ((const float4*)in)[i];
  f16x4 fv;
  fv[0] = (_Float16)v.x; fv[1] = (_Float16)v.y;
  fv[2] = (_Float16)v.z; fv[3] = (_Float16)v.w;
  ((f16x4*)f16)[i] = fv;
}

// ---------------- k-GEMM: bf16x3, 256x256, 8 waves, SPLIT-K=2 ---------------
// Minimal-barrier schedule: 2 barriers per K-step (entry vmcnt sync + exit).
// Inter-quad barriers removed (all quads read the stable current buffer;
// gloads write the other buffer) -> compiler can pipeline ds_reads of quads
// 1-3 under earlier quads' MFMA. Math identical to R20 (bitwise-same k).
__global__ __launch_bounds__(512, 2) void mfma_gemm_k_sk(const unsigned short* __restrict__ Ahi,
                                                         const unsigned short* __restrict__ Alo,
                                                         const unsigned short* __restrict__ Whi,
                                                         const unsigned short* __restrict__ Wlo,
                                                         float* __restrict__ kp0,
                                                         float* __restrict__ kp1) {
  __shared__ char smem[131072];  // 2 buf x 64K: Ahi 0|Alo 16K|Bhi 32K|Blo 48K
  const int t = threadIdx.x, l = t & 63, w = t >> 6;  // 8 waves
  const int lin = blockIdx.z * 128 + blockIdx.y * 8 + blockIdx.x;
  const int swz = (lin & 7) * 32 + (lin >> 3);        // 256 blocks, bijective
  const int kz = swz >> 7;
  const int idx = swz & 127;
  const int n0 = (idx & 7) * 256;
  const int m0 = (idx >> 3) * 256;
  const int kbase = kz * 1024;
  float* C = kz ? kp1 : kp0;
  const int wm = w >> 2, wn = w & 3;                  // 2M x 4N wave grid
  const int lr = l & 15;
  const int lg8 = (l >> 4) * 8;
  const size_t rstep = (size_t)16 * DM;

  const unsigned short* gAh = Ahi + (size_t)(m0 + w * 32 + lr) * DM + lg8;
  const unsigned short* gAl = Alo + (size_t)(m0 + w * 32 + lr) * DM + lg8;
  const unsigned short* gBh = Whi + (size_t)(n0 + w * 32 + lr) * DM + lg8;
  const unsigned short* gBl = Wlo + (size_t)(n0 + w * 32 + lr) * DM + lg8;

  f32x4 acc[8][4];
#pragma unroll
  for (int i = 0; i < 8; ++i)
#pragma unroll
    for (int j = 0; j < 4; ++j) acc[i][j] = (f32x4){0.f, 0.f, 0.f, 0.f};

  {  // prologue: full stage of tile 0 into buf 0
    char* base = smem + w * 2048;
    GLOAD16(gAh + kbase, base);
    GLOAD16(gAh + rstep + kbase, base + 1024);
    GLOAD16(gAl + kbase, base + 16384);
    GLOAD16(gAl + rstep + kbase, base + 16384 + 1024);
    GLOAD16(gBh + kbase, base + 32768);
    GLOAD16(gBh + rstep + kbase, base + 32768 + 1024);
    GLOAD16(gBl + kbase, base + 49152);
    GLOAD16(gBl + rstep + kbase, base + 49152 + 1024);
  }
  int cur = 0;

#define KQUAD(q)                                                                        \
  {                                                                                     \
    short8 ah0 = *(const short8*)(buf + (wm * 8 + 2 * (q)) * 1024 + l * 16);            \
    short8 ah1 = *(const short8*)(buf + (wm * 8 + 2 * (q) + 1) * 1024 + l * 16);        \
    short8 al0 = *(const short8*)(buf + 16384 + (wm * 8 + 2 * (q)) * 1024 + l * 16);    \
    short8 al1 = *(const short8*)(buf + 16384 + (wm * 8 + 2 * (q) + 1) * 1024 + l * 16);\
    __builtin_amdgcn_s_setprio(1);                                                      \
    _Pragma("unroll")                                                                   \
    for (int n = 0; n < 4; ++n) {                                                       \
      acc[2 * (q)][n] = __builtin_amdgcn_mfma_f32_16x16x32_bf16(ah0, bh[n], acc[2 * (q)][n], 0, 0, 0); \
      acc[2 * (q)][n] = __builtin_amdgcn_mfma_f32_16x16x32_bf16(ah0, bl[n], acc[2 * (q)][n], 0, 0, 0); \
      acc[2 * (q)][n] = __builtin_amdgcn_mfma_f32_16x16x32_bf16(al0, bh[n], acc[2 * (q)][n], 0, 0, 0); \
    }                                                                                   \
    _Pragma("unroll")                                                                   \
    for (int n = 0; n < 4; ++n) {                                                       \
      acc[2 * (q) + 1][n] = __builtin_amdgcn_mfma_f32_16x16x32_bf16(ah1, bh[n], acc[2 * (q) + 1][n], 0, 0, 0); \
      acc[2 * (q) + 1][n] = __builtin_amdgcn_mfma_f32_16x16x32_bf16(ah1, bl[n], acc[2 * (q) + 1][n], 0, 0, 0); \
      acc[2 * (q) + 1][n] = __builtin_amdgcn_mfma_f32_16x16x32_bf16(al1, bh[n], acc[2 * (q) + 1][n], 0, 0, 0); \
    }                                                                                   \
    __builtin_amdgcn_s_setprio(0);                                                      \
  }

  for (int k0 = kbase; k0 < kbase + 1024; k0 += 32) {
    const bool more = (k0 + 32 < kbase + 1024);
    char* buf = smem + cur * 65536;
    char* nb = smem + (cur ^ 1) * 65536 + w * 2048;
    const int kn = k0 + 32;

    // entry: issue first 2 next-tile gloads; sync current tile across waves
    if (more) {
      GLOAD16(gBh + kn, nb + 32768);
      GLOAD16(gBh + rstep + kn, nb + 32768 + 1024);
      asm volatile("s_waitcnt vmcnt(2)" ::: "memory");
    } else {
      asm volatile("s_waitcnt vmcnt(0)" ::: "memory");
    }
    __builtin_amdgcn_s_barrier();

    short8 bh[4], bl[4];
#pragma unroll
    for (int f = 0; f < 4; ++f) {
      bh[f] = *(const short8*)(buf + 32768 + (wn * 4 + f) * 1024 + l * 16);
      bl[f] = *(const short8*)(buf + 49152 + (wn * 4 + f) * 1024 + l * 16);
    }
    KQUAD(0);

    if (more) {
      GLOAD16(gBl + kn, nb + 49152);
      GLOAD16(gBl + rstep + kn, nb + 49152 + 1024);
    }
    KQUAD(1);

    if (more) {
      GLOAD16(gAh + kn, nb);
      GLOAD16(gAh + rstep + kn, nb + 1024);
    }
    KQUAD(2);

    if (more) {
      GLOAD16(gAl + kn, nb + 16384);
      GLOAD16(gAl + rstep + kn, nb + 16384 + 1024);
    }
    KQUAD(3);

    // exit: all waves done reading buf before next iter's gloads overwrite it
    __builtin_amdgcn_s_barrier();
    cur ^= 1;
  }
#undef KQUAD

#pragma unroll
  for (int m = 0; m < 8; ++m) {
    int row0 = m0 + wm * 128 + m * 16 + (l >> 4) * 4;
#pragma unroll
    for (int n = 0; n < 4; ++n) {
      int col = n0 + wn * 64 + n * 16 + (l & 15);
      int h = col >> 7, d = col & 127;
#pragma unroll
      for (int r = 0; r < 4; ++r) {
        int mm = row0 + r;
        int b = mm >> 11, s = mm & (S_ - 1);
        C[(((size_t)(b * H_ + h) * S_) + s) * DH + d] = acc[m][n][r];
      }
    }
  }
}

// ---------------- fused q+V fp16 GEMM: 256x256, 8 waves, min-barrier --------
__global__ __launch_bounds__(512, 2) void mfma_gemm_qv(const _Float16* __restrict__ A,
                                                       const _Float16* __restrict__ W,
                                                       float* __restrict__ Cq,
                                                       _Float16* __restrict__ vt) {
  __shared__ char smem[65536];  // 2 buf x 32K: A frags 0..16K | B frags 16..32K
  const int t = threadIdx.x, l = t & 63, w = t >> 6;  // 8 waves
  const int lin = blockIdx.y * gridDim.x + blockIdx.x;
  const int swz = (lin & 7) * 32 + (lin >> 3);        // 256 blocks, bijective
  const int n0 = (swz & 15) * 256;
  const int m0 = (swz >> 4) * 256;
  const int wm = w >> 2, wn = w & 3;                  // 2M x 4N wave grid
  const int lr = l & 15;
  const int lg8 = (l >> 4) * 8;
  const size_t rstep = (size_t)16 * DM;

  const _Float16* gA = A + (size_t)(m0 + w * 32 + lr) * DM + lg8;
  const _Float16* gB = W + (size_t)(n0 + w * 32 + lr) * DM + lg8;

  f32x4 acc[8][4];
#pragma unroll
  for (int i = 0; i < 8; ++i)
#pragma unroll
    for (int j = 0; j < 4; ++j) acc[i][j] = (f32x4){0.f, 0.f, 0.f, 0.f};

  {  // prologue
    char* base = smem + w * 2048;
    GLOAD16(gA, base);
    GLOAD16(gA + rstep, base + 1024);
    GLOAD16(gB, base + 16384);
    GLOAD16(gB + rstep, base + 16384 + 1024);
  }
  int cur = 0;

  for (int k0 = 0; k0 < DM; k0 += 32) {
    const bool more = (k0 + 32 < DM);
    char* buf = smem + cur * 32768;
    char* nb = smem + (cur ^ 1) * 32768 + w * 2048;
    const int kn = k0 + 32;

    // entry: issue next A pair; sync current tile
    if (more) {
      GLOAD16(gA + kn, nb);
      GLOAD16(gA + rstep + kn, nb + 1024);
      asm volatile("s_waitcnt vmcnt(2)" ::: "memory");
    } else {
      asm volatile("s_waitcnt vmcnt(0)" ::: "memory");
    }
    __builtin_amdgcn_s_barrier();

    f16x8 b[4];
#pragma unroll
    for (int j = 0; j < 4; ++j)
      b[j] = *(const f16x8*)(buf + 16384 + (wn * 4 + j) * 1024 + l * 16);
    __builtin_amdgcn_s_setprio(1);
#pragma unroll
    for (int i = 0; i < 4; ++i) {
      f16x8 a = *(const f16x8*)(buf + (wm * 8 + i) * 1024 + l * 16);
#pragma unroll
      for (int j = 0; j < 4; ++j)
        acc[i][j] = __builtin_amdgcn_mfma_f32_16x16x32_f16(a, b[j], acc[i][j], 0, 0, 0);
    }
    __builtin_amdgcn_s_setprio(0);

    // (no mid barrier: frags 4..7 read the same stable buffer)
    if (more) {
      GLOAD16(gB + kn, nb + 16384);
      GLOAD16(gB + rstep + kn, nb + 16384 + 1024);
    }
    __builtin_amdgcn_s_setprio(1);
#pragma unroll
    for (int i = 4; i < 8; ++i) {
      f16x8 a = *(const f16x8*)(buf + (wm * 8 + i) * 1024 + l * 16);
#pragma unroll
      for (int j = 0; j < 4; ++j)
        acc[i][j] = __builtin_amdgcn_mfma_f32_16x16x32_f16(a, b[j], acc[i][j], 0, 0, 0);
    }
    __builtin_amdgcn_s_setprio(0);
    __builtin_amdgcn_s_barrier();  // exit: reads done before buf overwritten

    cur ^= 1;
  }

#pragma unroll
  for (int m = 0; m < 8; ++m) {
    int row0 = m0 + wm * 128 + m * 16 + (l >> 4) * 4;
#pragma unroll
    for (int n = 0; n < 4; ++n) {
      int col = n0 + wn * 64 + n * 16 + (l & 15);
      if (col < DM) {
        int h = col >> 7, d = col & 127;
#pragma unroll
        for (int r = 0; r < 4; ++r) {
          int mm = row0 + r;
          int b2 = mm >> 11, s = mm & (S_ - 1);
          Cq[(((size_t)(b2 * H_ + h) * S_) + s) * DH + d] = acc[m][n][r];
        }
      } else {
        int vcol = col - DM;
        int h = vcol >> 7, d = vcol & 127;
        int b2 = row0 >> 11, s0 = row0 & (S_ - 1);
        f16x4 vv;
        vv[0] = (_Float16)acc[m][n][0];
        vv[1] = (_Float16)acc[m][n][1];
        vv[2] = (_Float16)acc[m][n][2];
        vv[3] = (_Float16)acc[m][n][3];
        *(f16x4*)(vt + (((size_t)(b2 * H_ + h)) * DH + d) * S_ + s0) = vv;
      }
    }
  }
}

// ---------------- fp16 single-product GEMM (O), BK=64, 128x128 --------------
template <int MODE>
__global__ __launch_bounds__(256) void mfma_gemm_f16(const _Float16* __restrict__ A,
                                                     const _Float16* __restrict__ W,
                                                     void* __restrict__ Cout) {
  __shared__ char smem[65536];
  const int t = threadIdx.x, l = t & 63, w = t >> 6;
  const int lin = blockIdx.y * gridDim.x + blockIdx.x;
  const int cpx = (gridDim.x * gridDim.y) >> 3;
  const int swz = (lin & 7) * cpx + (lin >> 3);
  const int n0 = (swz % gridDim.x) * 128;
  const int m0 = (swz / gridDim.x) * 128;
  const int wm = w >> 1, wn = w & 1;
  const int lr = l & 15;
  const int lg8 = (l >> 4) * 8;

  auto STAGE = [&](int k0, int c) {
    char* base = smem + c * 32768;
#pragma unroll
    for (int f0 = 0; f0 < 4; ++f0) {
      int f = w * 4 + f0;
      int rb = f >> 1, kh = f & 1;
      GLOAD16(A + (size_t)(m0 + rb * 16 + lr) * DM + k0 + kh * 32 + lg8,
              base + f * 1024);
      GLOAD16(W + (size_t)(n0 + rb * 16 + lr) * DM + k0 + kh * 32 + lg8,
              base + 16384 + f * 1024);
    }
  };

  f32x4 acc[4][4];
#pragma unroll
  for (int i = 0; i < 4; ++i)
#pragma unroll
    for (int j = 0; j < 4; ++j) acc[i][j] = (f32x4){0.f, 0.f, 0.f, 0.f};

  STAGE(0, 0);
  int cur = 0;

  for (int k0 = 0; k0 < DM; k0 += 64) {
    if (k0 + 64 < DM) {
      STAGE(k0 + 64, cur ^ 1);
      asm volatile("s_waitcnt vmcnt(8)" ::: "memory");
    } else {
      asm volatile("s_waitcnt vmcnt(0)" ::: "memory");
    }
    __builtin_amdgcn_s_barrier();

    char* buf = smem + cur * 32768;
    f16x8 a[4][2], b[4][2];
#pragma unroll
    for (int i = 0; i < 4; ++i)
#pragma unroll
      for (int kh = 0; kh < 2; ++kh) {
        a[i][kh] = *(const f16x8*)(buf + ((wm * 4 + i) * 2 + kh) * 1024 + l * 16);
        b[i][kh] = *(const f16x8*)(buf + 16384 + ((wn * 4 + i) * 2 + kh) * 1024 + l * 16);
      }
    __builtin_amdgcn_s_setprio(1);
#pragma unroll
    for (int i = 0; i < 4; ++i)
#pragma unroll
      for (int j = 0; j < 4; ++j) {
        acc[i][j] = __builtin_amdgcn_mfma_f32_16x16x32_f16(a[i][0], b[j][0], acc[i][j], 0, 0, 0);
        acc[i][j] = __builtin_amdgcn_mfma_f32_16x16x32_f16(a[i][1], b[j][1], acc[i][j], 0, 0, 0);
      }
    __builtin_amdgcn_s_setprio(0);
    __builtin_amdgcn_s_barrier();
    cur ^= 1;
  }

#pragma unroll
  for (int i = 0; i < 4; ++i) {
    int row0 = m0 + wm * 64 + i * 16 + (l >> 4) * 4;
#pragma unroll
    for (int j = 0; j < 4; ++j) {
      int col = n0 + wn * 64 + j * 16 + (l & 15);
      if constexpr (MODE == 1) {
        float* C = (float*)Cout;
#pragma unroll
        for (int r = 0; r < 4; ++r)
          C[(size_t)(row0 + r) * DM + col] = acc[i][j][r];
      }
    }
  }
}

// ---------------- RMSNorm + RoPE for K: sums split-K partials, emits fp16 ---
__global__ __launch_bounds__(256) void rmsrope_k_kernel(float* __restrict__ k,
                                                        const float* __restrict__ kp1,
                                                        _Float16* __restrict__ kf,
                                                        const float* __restrict__ cosb,
                                                        const float* __restrict__ sinb) {
  int w = threadIdx.x >> 6;
  int lane = threadIdx.x & 63;
  long r = (long)blockIdx.x * 4 + w;
  float* p = k + r * DH;
  const float* p1 = kp1 + r * DH;
  int s = (int)(r & (S_ - 1));
  float x1 = p[lane] + p1[lane];
  float x2 = p[lane + 64] + p1[lane + 64];
  float ss = fmaf(x1, x1, x2 * x2);
#pragma unroll
  for (int off = 32; off; off >>= 1) ss += __shfl_xor(ss, off);
  float rms = rsqrtf(ss * (1.0f / 128.0f) + 1e-6f);
  float n1 = x1 * rms, n2 = x2 * rms;
  float c = cosb[s * 64 + lane], sn = sinb[s * 64 + lane];
  float o1 = fmaf(n1, c, n2 * sn);
  float o2 = fmaf(-n1, sn, n2 * c);
  p[lane] = o1;
  p[lane + 64] = o2;
  kf[r * DH + lane] = (_Float16)o1;
  kf[r * DH + lane + 64] = (_Float16)o2;
}

// ---------------- RMSNorm + RoPE + gain for Q: emits fp16 scaled by ---------
// SC = (1/sqrt(128))*log2(e) so attn logits land in log2 domain. The uniform
// positive SC cancels exactly in selection's _normalize(mean @ proj).
__global__ __launch_bounds__(256) void rmsrope_q_kernel(const float* __restrict__ q,
                                                        _Float16* __restrict__ qf,
                                                        const float* __restrict__ cosb,
                                                        const float* __restrict__ sinb,
                                                        const float* __restrict__ qg) {
  const float SC = 0.12751743f;  // 1/sqrt(128) * log2(e)
  int w = threadIdx.x >> 6;
  int lane = threadIdx.x & 63;
  long r = (long)blockIdx.x * 4 + w;
  const float* p = q + r * DH;
  int s = (int)(r & (S_ - 1));
  int h = (int)((r >> 11) & (H_ - 1));
  float x1 = p[lane], x2 = p[lane + 64];
  float ss = fmaf(x1, x1, x2 * x2);
#pragma unroll
  for (int off = 32; off; off >>= 1) ss += __shfl_xor(ss, off);
  float rms = rsqrtf(ss * (1.0f / 128.0f) + 1e-6f);
  float n1 = x1 * rms, n2 = x2 * rms;
  float c = cosb[s * 64 + lane], sn = sinb[s * 64 + lane];
  float g = qg[h] * SC;
  float o1 = fmaf(n1, c, n2 * sn) * g;
  float o2 = fmaf(-n1, sn, n2 * c) * g;
  qf[r * DH + lane] = (_Float16)o1;
  qf[r * DH + lane + 64] = (_Float16)o2;
}

// ---------------- selection phase 1: q-mean partial sums (fp16 q) -----------
__global__ __launch_bounds__(256) void qmean_part_kernel(const _Float16* __restrict__ qf,
                                                         float* __restrict__ partial) {
  __shared__ float red[256];
  const int bh = blockIdx.x >> 4, chunk = blockIdx.x & 15;
  const int t = threadIdx.x;
  const int d = t & 127, half = t >> 7;
  const _Float16* qb = qf + ((size_t)bh * S_ + chunk * 128 + half * 64) * DH;
  float sum = 0.0f;
#pragma unroll 4
  for (int s = 0; s < 64; ++s) sum += (float)qb[(size_t)s * DH + d];
  red[t] = sum;
  __syncthreads();
  if (t < 128) partial[(size_t)blockIdx.x * 128 + t] = red[t] + red[t + 128];
}

// ---------------- selection phase 2: finish mean, project, normalize --------
__global__ void qproj_kernel(const float* __restrict__ partial,
                             const float* __restrict__ proj,
                             float* __restrict__ qp) {
  __shared__ float meanq[128];
  __shared__ float qps[32];
  __shared__ float nrm;
  const int bh = blockIdx.x, t = threadIdx.x;
  float s = 0.0f;
#pragma unroll
  for (int c = 0; c < 16; ++c) s += partial[((size_t)bh * 16 + c) * 128 + t];
  meanq[t] = s * (1.0f / 2048.0f);
  __syncthreads();
  if (t < 32) {
    float sum = 0.0f;
    for (int d = 0; d < 128; ++d) sum = fmaf(meanq[d], proj[d * 32 + t], sum);
    qps[t] = sum;
  }
  __syncthreads();
  if (t == 0) {
    float sum = 0.0f;
    for (int j = 0; j < 32; ++j) sum += qps[j] * qps[j];
    nrm = 1.0f / fmaxf(sqrtf(sum), 1e-12f);
  }
  __syncthreads();
  if (t < 32) qp[bh * 32 + t] = qps[t] * nrm;
}

// ---------------- selection phase 3: per-(bh,block) score ----------------
__global__ __launch_bounds__(256) void kscore_kernel(const float* __restrict__ k,
                                                     const float* __restrict__ proj,
                                                     const float* __restrict__ qp,
                                                     float* __restrict__ scores) {
  __shared__ float ps[128][32];
  __shared__ float kp[64][33];
  __shared__ float cent[33];
  __shared__ float nrm;
  const int bh = blockIdx.x >> 5, n = blockIdx.x & 31;
  const int t = threadIdx.x;
  for (int i = t; i < 4096; i += 256) ps[i >> 5][i & 31] = proj[i];
  const float* kn = k + ((size_t)bh * S_ + n * 64) * DH;
  __syncthreads();
  {
    int row = t >> 2, j0 = (t & 3) * 8;
    float accv[8];
#pragma unroll
    for (int jj = 0; jj < 8; ++jj) accv[jj] = 0.0f;
#pragma unroll 4
    for (int d = 0; d < 128; ++d) {
      float kv = kn[(size_t)row * DH + d];
#pragma unroll
      for (int jj = 0; jj < 8; ++jj) accv[jj] = fmaf(kv, ps[d][j0 + jj], accv[jj]);
    }
#pragma unroll
    for (int jj = 0; jj < 8; ++jj) kp[row][j0 + jj] = accv[jj];
  }
  __syncthreads();
  if (t < 64) {
    float sum = 0.0f;
    for (int j = 0; j < 32; ++j) sum += kp[t][j] * kp[t][j];
    float scl = 1.0f / fmaxf(sqrtf(sum), 1e-12f);
    for (int j = 0; j < 32; ++j) kp[t][j] *= scl;
  }
  __syncthreads();
  if (t < 32) {
    float sum = 0.0f;
    for (int r2 = 0; r2 < 64; ++r2) sum += kp[r2][t];
    cent[t] = sum * (1.0f / 64.0f);
  }
  __syncthreads();
  if (t == 0) {
    float sum = 0.0f;
    for (int j = 0; j < 32; ++j) sum += cent[j] * cent[j];
    nrm = 1.0f / fmaxf(sqrtf(sum), 1e-12f);
  }
  __syncthreads();
  if (t < 32) cent[t] *= nrm;
  __syncthreads();
  if (t < 64) {
    float dt = 0.0f;
    for (int j = 0; j < 32; ++j) dt = fmaf(kp[t][j], cent[j], dt);
#pragma unroll
    for (int off = 32; off; off >>= 1) dt = fminf(dt, __shfl_xor(dt, off));
    if (t == 0) {
      float radius = fminf(fmaxf(1.0f - dt, 0.0f), 1.0f);
      float dq = 0.0f;
      for (int j = 0; j < 32; ++j) dq = fmaf(qp[bh * 32 + j], cent[j], dq);
      scores[bh * 32 + n] = dq + radius;
    }
  }
}

// ---------------- selection phase 4: top-18 + sort ----------------
__global__ void topk_kernel(const float* __restrict__ scores, int* __restrict__ top_idx) {
  if (threadIdx.x != 0) return;
  const int bh = blockIdx.x;
  float sc[NBLK];
  for (int j = 0; j < NBLK; ++j) sc[j] = scores[bh * 32 + j];
  sc[NBLK - 2] = INFINITY;
  sc[NBLK - 1] = INFINITY;
  int chosen[NKEEP];
  bool used[NBLK];
  for (int j = 0; j < NBLK; ++j) used[j] = false;
  for (int kk = 0; kk < NKEEP; ++kk) {
    int best = -1;
    float bv = 0.0f;
    for (int j = 0; j < NBLK; ++j)
      if (!used[j] && (best < 0 || sc[j] > bv)) { bv = sc[j]; best = j; }
    used[best] = true;
    chosen[kk] = best;
  }
  for (int a = 1; a < NKEEP; ++a) {
    int v2 = chosen[a], b2 = a - 1;
    while (b2 >= 0 && chosen[b2] > v2) { chosen[b2 + 1] = chosen[b2]; --b2; }
    chosen[b2 + 1] = v2;
  }
  for (int a = 0; a < NKEEP; ++a) top_idx[bh * NKEEP + a] = chosen[a];
}

// ---------------- MFMA attention v9: per-lane ls partials (deferred reduce) -
__global__ __launch_bounds__(256) void attn_mfma_kernel(const _Float16* __restrict__ qfp,
                                                        const _Float16* __restrict__ kf,
                                                        const _Float16* __restrict__ vt,
                                                        const int* __restrict__ top_idx,
                                                        _Float16* __restrict__ yf) {
  __shared__ char lds[74752];  // buf0 0..32K (K 16K|V 16K), buf1 32..64K, P 64K..
  const int bh = blockIdx.x >> 5;
  const int qt = blockIdx.x & 31;
  const int t = threadIdx.x, l = t & 63, w = t >> 6;
  const int lr = l & 15, lg = l >> 4;
  const float THR2 = 11.5415603f;  // 8 * log2(e)

  f16x8 qf[4];
  {
    const _Float16* qbase = qfp + ((size_t)(bh * S_ + qt * 64 + w * 16 + lr)) * DH + lg * 8;
#pragma unroll
    for (int dc = 0; dc < 4; ++dc)
      qf[dc] = *(const f16x8*)(qbase + dc * 32);
  }

  float m_[4] = {-INFINITY, -INFINITY, -INFINITY, -INFINITY};
  float ls[4] = {0.f, 0.f, 0.f, 0.f};  // PER-LANE partial sums
  f32x4 yacc[8];
#pragma unroll
  for (int dt = 0; dt < 8; ++dt) yacc[dt] = (f32x4){0.f, 0.f, 0.f, 0.f};

  char* Pw = lds + 65536 + w * 2304;  // per-wave P: [16 q][72 fp16]

  const _Float16* kb0 = kf + (size_t)bh * S_ * DH;
  const _Float16* vb0 = vt + (size_t)bh * DH * S_;
  const int* idxp = top_idx + bh * NKEEP;

  auto STAGE = [&](int blk, int c) {
    char* base = lds + c * 32768;
#pragma unroll
    for (int f0 = 0; f0 < 4; ++f0) {
      int f = w * 4 + f0;
      int kt = f >> 2, dc = f & 3;
      GLOAD16(kb0 + (size_t)(blk * 64 + kt * 16 + lr) * DH + dc * 32 + lg * 8,
              base + f * 1024);
      int K0 = f >> 3, dt = f & 7;
      GLOAD16(vb0 + (size_t)(dt * 16 + lr) * S_ + blk * 64 + K0 * 32 + lg * 8,
              base + 16384 + f * 1024);
    }
  };

  int cur = 0;
  STAGE(idxp[0], 0);

  for (int it = 0; it < NKEEP; ++it) {
    if (it + 1 < NKEEP) {
      STAGE(idxp[it + 1], cur ^ 1);
      asm volatile("s_waitcnt vmcnt(8)" ::: "memory");
    } else {
      asm volatile("s_waitcnt vmcnt(0)" ::: "memory");
    }
    __builtin_amdgcn_s_barrier();
    char* buf = lds + cur * 32768;

    f32x4 sacc[4];
#pragma unroll
    for (int kt = 0; kt < 4; ++kt) sacc[kt] = (f32x4){0.f, 0.f, 0.f, 0.f};
    __builtin_amdgcn_s_setprio(1);
#pragma unroll
    for (int kt = 0; kt < 4; ++kt)
#pragma unroll
      for (int dc = 0; dc < 4; ++dc) {
        f16x8 kfr = *(const f16x8*)(buf + (kt * 4 + dc) * 1024 + l * 16);
        sacc[kt] = __builtin_amdgcn_mfma_f32_16x16x32_f16(qf[dc], kfr, sacc[kt], 0, 0, 0);
      }
    __builtin_amdgcn_s_setprio(0);

    // per-lane LOCAL max (no reduce); __all makes the defer decision exactly
    // equivalent to the row-max check (row max = max over lanes of local max)
    float lmax[4];
#pragma unroll
    for (int r = 0; r < 4; ++r)
      lmax[r] = fmaxf(fmaxf(sacc[0][r], sacc[1][r]), fmaxf(sacc[2][r], sacc[3][r]));
    bool ok = (lmax[0] <= m_[0] + THR2) && (lmax[1] <= m_[1] + THR2) &&
              (lmax[2] <= m_[2] + THR2) && (lmax[3] <= m_[3] + THR2);
    float p[4][4];
    if (__all(ok)) {
      // defer-max: keep old max; accumulate per-lane ls partials (no shuffles)
#pragma unroll
      for (int r = 0; r < 4; ++r) {
#pragma unroll
        for (int kt = 0; kt < 4; ++kt) {
          p[kt][r] = fexp2(sacc[kt][r] - m_[r]);
          ls[r] += p[kt][r];
        }
      }
    } else {
#pragma unroll
      for (int r = 0; r < 4; ++r) {
        float mv = lmax[r];
#pragma unroll
        for (int off = 1; off < 16; off <<= 1) mv = fmaxf(mv, __shfl_xor(mv, off));
        float mn = fmaxf(m_[r], mv);
        float corr = fexp2(m_[r] - mn);   // uniform across the row's lanes
        float rs = 0.f;
#pragma unroll
        for (int kt = 0; kt < 4; ++kt) {
          p[kt][r] = fexp2(sacc[kt][r] - mn);
          rs += p[kt][r];
        }
        ls[r] = ls[r] * corr + rs;        // per-lane partial, scaled uniformly
        m_[r] = mn;
#pragma unroll
        for (int dt = 0; dt < 8; ++dt) yacc[dt][r] *= corr;
      }
    }

#pragma unroll
    for (int kt = 0; kt < 4; ++kt)
#pragma unroll
      for (int r = 0; r < 4; ++r)
        *(_Float16*)(Pw + (lg * 4 + r) * 144 + (kt * 16 + lr) * 2) = (_Float16)p[kt][r];

    __builtin_amdgcn_s_setprio(1);
#pragma unroll
    for (int K0 = 0; K0 < 2; ++K0) {
      f16x8 pa = *(const f16x8*)(Pw + lr * 144 + K0 * 64 + lg * 16);
#pragma unroll
      for (int dt = 0; dt < 8; ++dt) {
        f16x8 vf = *(const f16x8*)(buf + 16384 + (K0 * 8 + dt) * 1024 + l * 16);
        yacc[dt] = __builtin_amdgcn_mfma_f32_16x16x32_f16(pa, vf, yacc[dt], 0, 0, 0);
      }
    }
    __builtin_amdgcn_s_setprio(0);

    __builtin_amdgcn_s_barrier();
    cur ^= 1;
  }

  // epilogue: reduce per-lane ls partials across the row's 16 lanes (once)
  const int b = bh >> 4, h = bh & (H_ - 1);
  float inv[4];
#pragma unroll
  for (int r = 0; r < 4; ++r) {
    float s = ls[r];
#pragma unroll
    for (int off = 1; off < 16; off <<= 1) s += __shfl_xor(s, off);
    inv[r] = 1.0f / s;
  }
#pragma unroll
  for (int r = 0; r < 4; ++r) {
    int srow = qt * 64 + w * 16 + lg * 4 + r;
    size_t off0 = ((size_t)b * S_ + srow) * DM + h * DH + lr;
#pragma unroll
    for (int dt = 0; dt < 8; ++dt)
      yf[off0 + dt * 16] = (_Float16)(yacc[dt][r] * inv[r]);
  }
}

extern "C" void kernel_launch(void* const* d_in, const int* in_sizes, int n_in,
                              void* d_out, int out_size, void* d_ws, size_t ws_size,
                              hipStream_t stream) {
  const float* x  = (const float*)d_in[0];
  const float* Wq = (const float*)d_in[1];
  const float* Wk = (const float*)d_in[2];
  const float* Wv = (const float*)d_in[3];
  const float* Wo = (const float*)d_in[4];
  const float* qg = (const float*)d_in[5];
  float* out = (float*)d_out;

  const size_t NE = (size_t)BH * S_ * DH;   // 8388608 elements
  const size_t WE = (size_t)DM * DM;        // 4194304 elements per W
  char* p = (char*)d_ws;
  float* q_ws = (float*)p; p += NE * 4;     // kpart1 during k-GEMM, then q f32
  float* k_ws = (float*)p; p += NE * 4;     // kpart0 -> roped k f32
  unsigned short* xhi = (unsigned short*)p; p += NE * 2;  // -> yf16 after k-GEMM
  unsigned short* xlo = (unsigned short*)p; p += NE * 2;  // -> vt after k-GEMM
  _Float16* xf16 = (_Float16*)p; p += NE * 2;             // -> qf16 after qv-GEMM
  unsigned short* wkhi = (unsigned short*)p; p += WE * 2; // \ kf16 spans wkhi+wklo
  unsigned short* wklo = (unsigned short*)p; p += WE * 2; // / (both dead post k-GEMM)
  _Float16* wqv = (_Float16*)p; p += 2 * WE * 2;          // [Wq;Wv] fp16; -> wo
  float* cosb = (float*)p; p += (size_t)S_ * 64 * 4;
  float* sinb = (float*)p; p += (size_t)S_ * 64 * 4;
  float* projb = (float*)p; p += 4096 * 4;
  int* idxb = (int*)p; p += BH * NKEEP * 4;
  float* scores = (float*)p; p += BH * NBLK * 4;
  float* qpbuf = (float*)p; p += BH * 32 * 4;
  // aliases (each with size check, stream-ordered):
  float* qpart = cosb;                   // 262KB <= 1MB; writer after rmsrope_q
  float* kpart1 = q_ws;                  // NE f32 = NE f32; qv writes q after rmsrope_k
  _Float16* kf16 = (_Float16*)wkhi;      // NE fp16 = 16.8MB = wkhi+wklo (16.8MB), both dead
  _Float16* vt = (_Float16*)xlo;         // NE fp16 <= NE ushort; xlo dead after k-GEMM
  _Float16* yf16 = (_Float16*)xhi;       // NE fp16 <= NE ushort; xhi dead after k-GEMM
  _Float16* qf16 = xf16;                 // NE fp16 = NE fp16; xf16 dead after qv-GEMM
  _Float16* wo = wqv;                    // WE fp16 <= 2WE fp16; wqv dead after qv-GEMM
  // total ws use ~152 MB (proven footprint, no growth)

  const int nx4 = (int)(NE / 4);
  const int nw4 = (int)(WE / 4);

  proj_kernel<<<dim3(16), dim3(256), 0, stream>>>(projb);
  rope_table_kernel<<<dim3(S_), dim3(64), 0, stream>>>(cosb, sinb);
  split_x3_kernel<<<dim3(nx4 / 256), dim3(256), 0, stream>>>(x, xhi, xlo, xf16, nx4);
  split_w3_kernel<<<dim3(nw4 / 256), dim3(256), 0, stream>>>(Wk, Wq, Wv, wkhi, wklo,
                                                             wqv, wqv + WE, nw4);

  // k: bf16x3, split-K=2, 8-wave 256^2, min-barrier counted-vmcnt schedule
  mfma_gemm_k_sk<<<dim3(8, 16, 2), dim3(512), 0, stream>>>(xhi, xlo, wkhi, wklo,
                                                           k_ws, kpart1);

  // k finalize: sum partials + RMS + RoPE; writes k f32 (in place) + kf16
  rmsrope_k_kernel<<<dim3((BH * S_) / 4), dim3(256), 0, stream>>>(k_ws, kpart1, kf16, cosb, sinb);

  // q+V fused: fp16, 256^2 8-wave, min-barrier; overwrites kpart1 — safe now
  mfma_gemm_qv<<<dim3(16, 16), dim3(512), 0, stream>>>(xf16, wqv, q_ws, vt);

  // q finalize: RMS + RoPE + gain, emits fp16 q scaled by scale*log2e
  rmsrope_q_kernel<<<dim3((BH * S_) / 4), dim3(256), 0, stream>>>(q_ws, qf16, cosb, sinb, qg);

  qmean_part_kernel<<<dim3(BH * 16), dim3(256), 0, stream>>>(qf16, qpart);
  qproj_kernel<<<dim3(BH), dim3(128), 0, stream>>>(qpart, projb, qpbuf);
  kscore_kernel<<<dim3(BH * NBLK), dim3(256), 0, stream>>>(k_ws, projb, qpbuf, scores);
  topk_kernel<<<dim3(BH), dim3(64), 0, stream>>>(scores, idxb);

  // attn v9: per-lane ls partials, raw v_exp softmax, lazy max-reduce defer
  attn_mfma_kernel<<<dim3(BH * 32), dim3(256), 0, stream>>>(qf16, kf16, vt, idxb, yf16);

  // O: fp16 x1 on yf16 and Wo-f16
  split_f16_kernel<<<dim3(nw4 / 256), dim3(256), 0, stream>>>(Wo, wo, nw4);
  mfma_gemm_f16<1><<<dim3(16, 32), dim3(256), 0, stream>>>(yf16, wo, out);
}

// Round 22
// 411.113 us; speedup vs baseline: 1.0882x; 1.0173x over previous
//
#include <hip/hip_runtime.h>
#include <hip/hip_bf16.h>

#define B_ 2
#define S_ 2048
#define DM 2048
#define H_ 16
#define DH 128
#define NBLK 32
#define NKEEP 18
#define BH (B_ * H_)

typedef __attribute__((ext_vector_type(8))) short short8;
typedef __attribute__((ext_vector_type(8))) _Float16 f16x8;
typedef __attribute__((ext_vector_type(4))) _Float16 f16x4;
typedef __attribute__((ext_vector_type(4))) float f32x4;

#define GLOAD16(gp, lp)                                                        \
  __builtin_amdgcn_global_load_lds(                                            \
      (const __attribute__((address_space(1))) unsigned int*)(const void*)(gp),\
      (__attribute__((address_space(3))) unsigned int*)(void*)(lp), 16, 0, 0)

__device__ __forceinline__ unsigned short f32_to_bf16(float f) {
  unsigned u = __float_as_uint(f);
  unsigned r = (u + 0x7fffu + ((u >> 16) & 1u)) >> 16;
  return (unsigned short)r;
}
__device__ __forceinline__ float bf16_to_f32(unsigned short h) {
  return __uint_as_float(((unsigned)h) << 16);
}
// raw HW 2^x (logits pre-scaled into log2 domain); no libm fixup code
__device__ __forceinline__ float fexp2(float x) {
  float r;
  asm("v_exp_f32 %0, %1" : "=v"(r) : "v"(x));
  return r;
}

// ---------------- proj: threefry2x32 (partitionable) + erfinv ----------------
__device__ __forceinline__ unsigned rotl32(unsigned x, int r) {
  return (x << r) | (x >> (32 - r));
}

__device__ __forceinline__ float erfinv_f32(float x) {
  float w = -log1pf(-x * x);
  float p;
  if (w < 5.0f) {
    w -= 2.5f;
    p = 2.81022636e-08f;
    p = fmaf(p, w, 3.43273939e-07f);
    p = fmaf(p, w, -3.5233877e-06f);
    p = fmaf(p, w, -4.39150654e-06f);
    p = fmaf(p, w, 0.00021858087f);
    p = fmaf(p, w, -0.00125372503f);
    p = fmaf(p, w, -0.00417768164f);
    p = fmaf(p, w, 0.246640727f);
    p = fmaf(p, w, 1.50140941f);
  } else {
    w = sqrtf(w) - 3.0f;
    p = -0.000200214257f;
    p = fmaf(p, w, 0.000100950558f);
    p = fmaf(p, w, 0.00134934322f);
    p = fmaf(p, w, -0.00367342844f);
    p = fmaf(p, w, 0.00573950773f);
    p = fmaf(p, w, -0.0076224613f);
    p = fmaf(p, w, 0.00943887047f);
    p = fmaf(p, w, 1.00167406f);
    p = fmaf(p, w, 2.83297682f);
  }
  return p * x;
}

__device__ __forceinline__ float bits_to_normal(unsigned b) {
  float f = __uint_as_float((b >> 9) | 0x3f800000u) - 1.0f;
  const float lo = -0.9999999403953552f;
  float u = fmaxf(lo, fmaf(f, 2.0f, lo));
  return 1.4142135623730951f * erfinv_f32(u);
}

// ---------------- fused tables: proj (blocks 0..15) + RoPE (blocks 16..) ----
__global__ void tables_kernel(float* __restrict__ proj,
                              float* __restrict__ cosb,
                              float* __restrict__ sinb) {
  if (blockIdx.x < 16) {
    int i = blockIdx.x * 256 + threadIdx.x;
    unsigned k0 = 0u, k1 = 42u;
    unsigned k2 = 0x1BD11BDAu ^ k0 ^ k1;
    unsigned x0 = 0u, x1 = (unsigned)i;
    x0 += k0; x1 += k1;
#define QR(r) { x0 += x1; x1 = rotl32(x1, r); x1 ^= x0; }
    QR(13) QR(15) QR(26) QR(6)   x0 += k1; x1 += k2 + 1u;
    QR(17) QR(29) QR(16) QR(24)  x0 += k2; x1 += k0 + 2u;
    QR(13) QR(15) QR(26) QR(6)   x0 += k0; x1 += k1 + 3u;
    QR(17) QR(29) QR(16) QR(24)  x0 += k1; x1 += k2 + 4u;
    QR(13) QR(15) QR(26) QR(6)   x0 += k2; x1 += k0 + 5u;
#undef QR
    proj[i] = bits_to_normal(x0 ^ x1) / 5.656854249492381f;
  } else {
    int s = blockIdx.x - 16;
    int j = threadIdx.x;
    if (j < 64) {
      double e = (double)(2 * j) / 128.0;
      double invf = 1.0 / pow(10000.0, e);
      float freq = (float)s * (float)invf;
      cosb[s * 64 + j] = (float)cos((double)freq);
      sinb[s * 64 + j] = (float)sin((double)freq);
    }
  }
}

// ---------------- x -> bf16 hi/lo + fp16, single pass ----------------
__global__ __launch_bounds__(256) void split_x3_kernel(const float* __restrict__ in,
                                                       unsigned short* __restrict__ hi,
                                                       unsigned short* __restrict__ lo,
                                                       _Float16* __restrict__ f16,
                                                       int n4) {
  int i = blockIdx.x * blockDim.x + threadIdx.x;
  if (i >= n4) return;
  float4 v = ((const float4*)in)[i];
  ushort4 hv, lv;
  f16x4 fv;
  hv.x = f32_to_bf16(v.x); lv.x = f32_to_bf16(v.x - bf16_to_f32(hv.x)); fv[0] = (_Float16)v.x;
  hv.y = f32_to_bf16(v.y); lv.y = f32_to_bf16(v.y - bf16_to_f32(hv.y)); fv[1] = (_Float16)v.y;
  hv.z = f32_to_bf16(v.z); lv.z = f32_to_bf16(v.z - bf16_to_f32(hv.z)); fv[2] = (_Float16)v.z;
  hv.w = f32_to_bf16(v.w); lv.w = f32_to_bf16(v.w - bf16_to_f32(hv.w)); fv[3] = (_Float16)v.w;
  ((ushort4*)hi)[i] = hv;
  ((ushort4*)lo)[i] = lv;
  ((f16x4*)f16)[i] = fv;
}

// ---------------- fused W split: Wk -> bf16 hi/lo; Wq, Wv -> fp16 ----------
__global__ __launch_bounds__(256) void split_w3_kernel(const float* __restrict__ wk,
                                                       const float* __restrict__ wq,
                                                       const float* __restrict__ wv,
                                                       unsigned short* __restrict__ khi,
                                                       unsigned short* __restrict__ klo,
                                                       _Float16* __restrict__ qf,
                                                       _Float16* __restrict__ vf,
                                                       int n4) {
  int i = blockIdx.x * blockDim.x + threadIdx.x;
  if (i >= n4) return;
  {
    float4 v = ((const float4*)wk)[i];
    ushort4 hv, lv;
    hv.x = f32_to_bf16(v.x); lv.x = f32_to_bf16(v.x - bf16_to_f32(hv.x));
    hv.y = f32_to_bf16(v.y); lv.y = f32_to_bf16(v.y - bf16_to_f32(hv.y));
    hv.z = f32_to_bf16(v.z); lv.z = f32_to_bf16(v.z - bf16_to_f32(hv.z));
    hv.w = f32_to_bf16(v.w); lv.w = f32_to_bf16(v.w - bf16_to_f32(hv.w));
    ((ushort4*)khi)[i] = hv;
    ((ushort4*)klo)[i] = lv;
  }
  {
    float4 v = ((const float4*)wq)[i];
    f16x4 fv;
    fv[0] = (_Float16)v.x; fv[1] = (_Float16)v.y;
    fv[2] = (_Float16)v.z; fv[3] = (_Float16)v.w;
    ((f16x4*)qf)[i] = fv;
  }
  {
    float4 v = ((const float4*)wv)[i];
    f16x4 fv;
    fv[0] = (_Float16)v.x; fv[1] = (_Float16)v.y;
    fv[2] = (_Float16)v.z; fv[3] = (_Float16)v.w;
    ((f16x4*)vf)[i] = fv;
  }
}

// ---------------- W -> fp16 (Wo, late) ----------------
__global__ __launch_bounds__(256) void split_f16_kernel(const float* __restrict__ in,
                                                        _Float16* __restrict__ f16,
                                                        int n4) {
  int i = blockIdx.x * blockDim.x + threadIdx.x;
  if (i >= n4) return;
  float4 v = ((const float4*)in)[i];
  f16x4 fv;
  fv[0] = (_Float16)v.x; fv[1] = (_Float16)v.y;
  fv[2] = (_Float16)v.z; fv[3] = (_Float16)v.w;
  ((f16x4*)f16)[i] = fv;
}

// ---------------- k-GEMM: bf16x3, 256x256, 8 waves, SPLIT-K=2 ---------------
// Minimal-barrier schedule (R21-proven): 2 barriers per K-step.
__global__ __launch_bounds__(512, 2) void mfma_gemm_k_sk(const unsigned short* __restrict__ Ahi,
                                                         const unsigned short* __restrict__ Alo,
                                                         const unsigned short* __restrict__ Whi,
                                                         const unsigned short* __restrict__ Wlo,
                                                         float* __restrict__ kp0,
                                                         float* __restrict__ kp1) {
  __shared__ char smem[131072];  // 2 buf x 64K: Ahi 0|Alo 16K|Bhi 32K|Blo 48K
  const int t = threadIdx.x, l = t & 63, w = t >> 6;  // 8 waves
  const int lin = blockIdx.z * 128 + blockIdx.y * 8 + blockIdx.x;
  const int swz = (lin & 7) * 32 + (lin >> 3);        // 256 blocks, bijective
  const int kz = swz >> 7;
  const int idx = swz & 127;
  const int n0 = (idx & 7) * 256;
  const int m0 = (idx >> 3) * 256;
  const int kbase = kz * 1024;
  float* C = kz ? kp1 : kp0;
  const int wm = w >> 2, wn = w & 3;                  // 2M x 4N wave grid
  const int lr = l & 15;
  const int lg8 = (l >> 4) * 8;
  const size_t rstep = (size_t)16 * DM;

  const unsigned short* gAh = Ahi + (size_t)(m0 + w * 32 + lr) * DM + lg8;
  const unsigned short* gAl = Alo + (size_t)(m0 + w * 32 + lr) * DM + lg8;
  const unsigned short* gBh = Whi + (size_t)(n0 + w * 32 + lr) * DM + lg8;
  const unsigned short* gBl = Wlo + (size_t)(n0 + w * 32 + lr) * DM + lg8;

  f32x4 acc[8][4];
#pragma unroll
  for (int i = 0; i < 8; ++i)
#pragma unroll
    for (int j = 0; j < 4; ++j) acc[i][j] = (f32x4){0.f, 0.f, 0.f, 0.f};

  {  // prologue: full stage of tile 0 into buf 0
    char* base = smem + w * 2048;
    GLOAD16(gAh + kbase, base);
    GLOAD16(gAh + rstep + kbase, base + 1024);
    GLOAD16(gAl + kbase, base + 16384);
    GLOAD16(gAl + rstep + kbase, base + 16384 + 1024);
    GLOAD16(gBh + kbase, base + 32768);
    GLOAD16(gBh + rstep + kbase, base + 32768 + 1024);
    GLOAD16(gBl + kbase, base + 49152);
    GLOAD16(gBl + rstep + kbase, base + 49152 + 1024);
  }
  int cur = 0;

#define KQUAD(q)                                                                        \
  {                                                                                     \
    short8 ah0 = *(const short8*)(buf + (wm * 8 + 2 * (q)) * 1024 + l * 16);            \
    short8 ah1 = *(const short8*)(buf + (wm * 8 + 2 * (q) + 1) * 1024 + l * 16);        \
    short8 al0 = *(const short8*)(buf + 16384 + (wm * 8 + 2 * (q)) * 1024 + l * 16);    \
    short8 al1 = *(const short8*)(buf + 16384 + (wm * 8 + 2 * (q) + 1) * 1024 + l * 16);\
    __builtin_amdgcn_s_setprio(1);                                                      \
    _Pragma("unroll")                                                                   \
    for (int n = 0; n < 4; ++n) {                                                       \
      acc[2 * (q)][n] = __builtin_amdgcn_mfma_f32_16x16x32_bf16(ah0, bh[n], acc[2 * (q)][n], 0, 0, 0); \
      acc[2 * (q)][n] = __builtin_amdgcn_mfma_f32_16x16x32_bf16(ah0, bl[n], acc[2 * (q)][n], 0, 0, 0); \
      acc[2 * (q)][n] = __builtin_amdgcn_mfma_f32_16x16x32_bf16(al0, bh[n], acc[2 * (q)][n], 0, 0, 0); \
    }                                                                                   \
    _Pragma("unroll")                                                                   \
    for (int n = 0; n < 4; ++n) {                                                       \
      acc[2 * (q) + 1][n] = __builtin_amdgcn_mfma_f32_16x16x32_bf16(ah1, bh[n], acc[2 * (q) + 1][n], 0, 0, 0); \
      acc[2 * (q) + 1][n] = __builtin_amdgcn_mfma_f32_16x16x32_bf16(ah1, bl[n], acc[2 * (q) + 1][n], 0, 0, 0); \
      acc[2 * (q) + 1][n] = __builtin_amdgcn_mfma_f32_16x16x32_bf16(al1, bh[n], acc[2 * (q) + 1][n], 0, 0, 0); \
    }                                                                                   \
    __builtin_amdgcn_s_setprio(0);                                                      \
  }

  for (int k0 = kbase; k0 < kbase + 1024; k0 += 32) {
    const bool more = (k0 + 32 < kbase + 1024);
    char* buf = smem + cur * 65536;
    char* nb = smem + (cur ^ 1) * 65536 + w * 2048;
    const int kn = k0 + 32;

    if (more) {
      GLOAD16(gBh + kn, nb + 32768);
      GLOAD16(gBh + rstep + kn, nb + 32768 + 1024);
      asm volatile("s_waitcnt vmcnt(2)" ::: "memory");
    } else {
      asm volatile("s_waitcnt vmcnt(0)" ::: "memory");
    }
    __builtin_amdgcn_s_barrier();

    short8 bh[4], bl[4];
#pragma unroll
    for (int f = 0; f < 4; ++f) {
      bh[f] = *(const short8*)(buf + 32768 + (wn * 4 + f) * 1024 + l * 16);
      bl[f] = *(const short8*)(buf + 49152 + (wn * 4 + f) * 1024 + l * 16);
    }
    KQUAD(0);

    if (more) {
      GLOAD16(gBl + kn, nb + 49152);
      GLOAD16(gBl + rstep + kn, nb + 49152 + 1024);
    }
    KQUAD(1);

    if (more) {
      GLOAD16(gAh + kn, nb);
      GLOAD16(gAh + rstep + kn, nb + 1024);
    }
    KQUAD(2);

    if (more) {
      GLOAD16(gAl + kn, nb + 16384);
      GLOAD16(gAl + rstep + kn, nb + 16384 + 1024);
    }
    KQUAD(3);

    __builtin_amdgcn_s_barrier();
    cur ^= 1;
  }
#undef KQUAD

#pragma unroll
  for (int m = 0; m < 8; ++m) {
    int row0 = m0 + wm * 128 + m * 16 + (l >> 4) * 4;
#pragma unroll
    for (int n = 0; n < 4; ++n) {
      int col = n0 + wn * 64 + n * 16 + (l & 15);
      int h = col >> 7, d = col & 127;
#pragma unroll
      for (int r = 0; r < 4; ++r) {
        int mm = row0 + r;
        int b = mm >> 11, s = mm & (S_ - 1);
        C[(((size_t)(b * H_ + h) * S_) + s) * DH + d] = acc[m][n][r];
      }
    }
  }
}

// ---------------- fused q+V fp16 GEMM: 256x256, 8 waves, min-barrier --------
__global__ __launch_bounds__(512, 2) void mfma_gemm_qv(const _Float16* __restrict__ A,
                                                       const _Float16* __restrict__ W,
                                                       float* __restrict__ Cq,
                                                       _Float16* __restrict__ vt) {
  __shared__ char smem[65536];  // 2 buf x 32K: A frags 0..16K | B frags 16..32K
  const int t = threadIdx.x, l = t & 63, w = t >> 6;  // 8 waves
  const int lin = blockIdx.y * gridDim.x + blockIdx.x;
  const int swz = (lin & 7) * 32 + (lin >> 3);        // 256 blocks, bijective
  const int n0 = (swz & 15) * 256;
  const int m0 = (swz >> 4) * 256;
  const int wm = w >> 2, wn = w & 3;                  // 2M x 4N wave grid
  const int lr = l & 15;
  const int lg8 = (l >> 4) * 8;
  const size_t rstep = (size_t)16 * DM;

  const _Float16* gA = A + (size_t)(m0 + w * 32 + lr) * DM + lg8;
  const _Float16* gB = W + (size_t)(n0 + w * 32 + lr) * DM + lg8;

  f32x4 acc[8][4];
#pragma unroll
  for (int i = 0; i < 8; ++i)
#pragma unroll
    for (int j = 0; j < 4; ++j) acc[i][j] = (f32x4){0.f, 0.f, 0.f, 0.f};

  {  // prologue
    char* base = smem + w * 2048;
    GLOAD16(gA, base);
    GLOAD16(gA + rstep, base + 1024);
    GLOAD16(gB, base + 16384);
    GLOAD16(gB + rstep, base + 16384 + 1024);
  }
  int cur = 0;

  for (int k0 = 0; k0 < DM; k0 += 32) {
    const bool more = (k0 + 32 < DM);
    char* buf = smem + cur * 32768;
    char* nb = smem + (cur ^ 1) * 32768 + w * 2048;
    const int kn = k0 + 32;

    if (more) {
      GLOAD16(gA + kn, nb);
      GLOAD16(gA + rstep + kn, nb + 1024);
      asm volatile("s_waitcnt vmcnt(2)" ::: "memory");
    } else {
      asm volatile("s_waitcnt vmcnt(0)" ::: "memory");
    }
    __builtin_amdgcn_s_barrier();

    f16x8 b[4];
#pragma unroll
    for (int j = 0; j < 4; ++j)
      b[j] = *(const f16x8*)(buf + 16384 + (wn * 4 + j) * 1024 + l * 16);
    __builtin_amdgcn_s_setprio(1);
#pragma unroll
    for (int i = 0; i < 4; ++i) {
      f16x8 a = *(const f16x8*)(buf + (wm * 8 + i) * 1024 + l * 16);
#pragma unroll
      for (int j = 0; j < 4; ++j)
        acc[i][j] = __builtin_amdgcn_mfma_f32_16x16x32_f16(a, b[j], acc[i][j], 0, 0, 0);
    }
    __builtin_amdgcn_s_setprio(0);

    if (more) {
      GLOAD16(gB + kn, nb + 16384);
      GLOAD16(gB + rstep + kn, nb + 16384 + 1024);
    }
    __builtin_amdgcn_s_setprio(1);
#pragma unroll
    for (int i = 4; i < 8; ++i) {
      f16x8 a = *(const f16x8*)(buf + (wm * 8 + i) * 1024 + l * 16);
#pragma unroll
      for (int j = 0; j < 4; ++j)
        acc[i][j] = __builtin_amdgcn_mfma_f32_16x16x32_f16(a, b[j], acc[i][j], 0, 0, 0);
    }
    __builtin_amdgcn_s_setprio(0);
    __builtin_amdgcn_s_barrier();

    cur ^= 1;
  }

#pragma unroll
  for (int m = 0; m < 8; ++m) {
    int row0 = m0 + wm * 128 + m * 16 + (l >> 4) * 4;
#pragma unroll
    for (int n = 0; n < 4; ++n) {
      int col = n0 + wn * 64 + n * 16 + (l & 15);
      if (col < DM) {
        int h = col >> 7, d = col & 127;
#pragma unroll
        for (int r = 0; r < 4; ++r) {
          int mm = row0 + r;
          int b2 = mm >> 11, s = mm & (S_ - 1);
          Cq[(((size_t)(b2 * H_ + h) * S_) + s) * DH + d] = acc[m][n][r];
        }
      } else {
        int vcol = col - DM;
        int h = vcol >> 7, d = vcol & 127;
        int b2 = row0 >> 11, s0 = row0 & (S_ - 1);
        f16x4 vv;
        vv[0] = (_Float16)acc[m][n][0];
        vv[1] = (_Float16)acc[m][n][1];
        vv[2] = (_Float16)acc[m][n][2];
        vv[3] = (_Float16)acc[m][n][3];
        *(f16x4*)(vt + (((size_t)(b2 * H_ + h)) * DH + d) * S_ + s0) = vv;
      }
    }
  }
}

// ---------------- fp16 single-product GEMM (O), BK=64, 128x128 --------------
template <int MODE>
__global__ __launch_bounds__(256) void mfma_gemm_f16(const _Float16* __restrict__ A,
                                                     const _Float16* __restrict__ W,
                                                     void* __restrict__ Cout) {
  __shared__ char smem[65536];
  const int t = threadIdx.x, l = t & 63, w = t >> 6;
  const int lin = blockIdx.y * gridDim.x + blockIdx.x;
  const int cpx = (gridDim.x * gridDim.y) >> 3;
  const int swz = (lin & 7) * cpx + (lin >> 3);
  const int n0 = (swz % gridDim.x) * 128;
  const int m0 = (swz / gridDim.x) * 128;
  const int wm = w >> 1, wn = w & 1;
  const int lr = l & 15;
  const int lg8 = (l >> 4) * 8;

  auto STAGE = [&](int k0, int c) {
    char* base = smem + c * 32768;
#pragma unroll
    for (int f0 = 0; f0 < 4; ++f0) {
      int f = w * 4 + f0;
      int rb = f >> 1, kh = f & 1;
      GLOAD16(A + (size_t)(m0 + rb * 16 + lr) * DM + k0 + kh * 32 + lg8,
              base + f * 1024);
      GLOAD16(W + (size_t)(n0 + rb * 16 + lr) * DM + k0 + kh * 32 + lg8,
              base + 16384 + f * 1024);
    }
  };

  f32x4 acc[4][4];
#pragma unroll
  for (int i = 0; i < 4; ++i)
#pragma unroll
    for (int j = 0; j < 4; ++j) acc[i][j] = (f32x4){0.f, 0.f, 0.f, 0.f};

  STAGE(0, 0);
  int cur = 0;

  for (int k0 = 0; k0 < DM; k0 += 64) {
    if (k0 + 64 < DM) {
      STAGE(k0 + 64, cur ^ 1);
      asm volatile("s_waitcnt vmcnt(8)" ::: "memory");
    } else {
      asm volatile("s_waitcnt vmcnt(0)" ::: "memory");
    }
    __builtin_amdgcn_s_barrier();

    char* buf = smem + cur * 32768;
    f16x8 a[4][2], b[4][2];
#pragma unroll
    for (int i = 0; i < 4; ++i)
#pragma unroll
      for (int kh = 0; kh < 2; ++kh) {
        a[i][kh] = *(const f16x8*)(buf + ((wm * 4 + i) * 2 + kh) * 1024 + l * 16);
        b[i][kh] = *(const f16x8*)(buf + 16384 + ((wn * 4 + i) * 2 + kh) * 1024 + l * 16);
      }
    __builtin_amdgcn_s_setprio(1);
#pragma unroll
    for (int i = 0; i < 4; ++i)
#pragma unroll
      for (int j = 0; j < 4; ++j) {
        acc[i][j] = __builtin_amdgcn_mfma_f32_16x16x32_f16(a[i][0], b[j][0], acc[i][j], 0, 0, 0);
        acc[i][j] = __builtin_amdgcn_mfma_f32_16x16x32_f16(a[i][1], b[j][1], acc[i][j], 0, 0, 0);
      }
    __builtin_amdgcn_s_setprio(0);
    __builtin_amdgcn_s_barrier();
    cur ^= 1;
  }

#pragma unroll
  for (int i = 0; i < 4; ++i) {
    int row0 = m0 + wm * 64 + i * 16 + (l >> 4) * 4;
#pragma unroll
    for (int j = 0; j < 4; ++j) {
      int col = n0 + wn * 64 + j * 16 + (l & 15);
      if constexpr (MODE == 1) {
        float* C = (float*)Cout;
#pragma unroll
        for (int r = 0; r < 4; ++r)
          C[(size_t)(row0 + r) * DM + col] = acc[i][j][r];
      }
    }
  }
}

// ---------------- RMSNorm + RoPE for K: sums split-K partials, emits fp16 ---
__global__ __launch_bounds__(256) void rmsrope_k_kernel(float* __restrict__ k,
                                                        const float* __restrict__ kp1,
                                                        _Float16* __restrict__ kf,
                                                        const float* __restrict__ cosb,
                                                        const float* __restrict__ sinb) {
  int w = threadIdx.x >> 6;
  int lane = threadIdx.x & 63;
  long r = (long)blockIdx.x * 4 + w;
  float* p = k + r * DH;
  const float* p1 = kp1 + r * DH;
  int s = (int)(r & (S_ - 1));
  float x1 = p[lane] + p1[lane];
  float x2 = p[lane + 64] + p1[lane + 64];
  float ss = fmaf(x1, x1, x2 * x2);
#pragma unroll
  for (int off = 32; off; off >>= 1) ss += __shfl_xor(ss, off);
  float rms = rsqrtf(ss * (1.0f / 128.0f) + 1e-6f);
  float n1 = x1 * rms, n2 = x2 * rms;
  float c = cosb[s * 64 + lane], sn = sinb[s * 64 + lane];
  float o1 = fmaf(n1, c, n2 * sn);
  float o2 = fmaf(-n1, sn, n2 * c);
  p[lane] = o1;
  p[lane + 64] = o2;
  kf[r * DH + lane] = (_Float16)o1;
  kf[r * DH + lane + 64] = (_Float16)o2;
}

// ---------------- RMSNorm + RoPE + gain for Q + fused q-mean partials -------
// grid BH*16, 256 thr (4 waves). Each wave serially processes 32 rows of its
// 128-row chunk, accumulating per-d partial sums; block reduces via LDS into
// qpart[bh*16+chunk][d] (layout identical to the old qmean_part output).
__global__ __launch_bounds__(256) void rmsrope_q_kernel(const float* __restrict__ q,
                                                        _Float16* __restrict__ qf,
                                                        const float* __restrict__ cosb,
                                                        const float* __restrict__ sinb,
                                                        const float* __restrict__ qg,
                                                        float* __restrict__ qpart) {
  __shared__ float red[4][128];
  const float SC = 0.12751743f;  // 1/sqrt(128) * log2(e)
  const int w = threadIdx.x >> 6;
  const int lane = threadIdx.x & 63;
  const int bh = blockIdx.x >> 4, chunk = blockIdx.x & 15;
  const int h = bh & (H_ - 1);
  const float g = qg[h] * SC;
  float s0 = 0.f, s1 = 0.f;
  long rbase = (long)bh * S_ + chunk * 128 + w * 32;
  for (int i = 0; i < 32; ++i) {
    long r = rbase + i;
    const float* p = q + r * DH;
    int s = (int)(r & (S_ - 1));
    float x1 = p[lane], x2 = p[lane + 64];
    float ss = fmaf(x1, x1, x2 * x2);
#pragma unroll
    for (int off = 32; off; off >>= 1) ss += __shfl_xor(ss, off);
    float rms = rsqrtf(ss * (1.0f / 128.0f) + 1e-6f);
    float n1 = x1 * rms, n2 = x2 * rms;
    float c = cosb[s * 64 + lane], sn = sinb[s * 64 + lane];
    float o1 = fmaf(n1, c, n2 * sn) * g;
    float o2 = fmaf(-n1, sn, n2 * c) * g;
    qf[r * DH + lane] = (_Float16)o1;
    qf[r * DH + lane + 64] = (_Float16)o2;
    s0 += o1;
    s1 += o2;
  }
  red[w][lane] = s0;
  red[w][lane + 64] = s1;
  __syncthreads();
  int t = threadIdx.x;
  if (t < 128)
    qpart[(size_t)blockIdx.x * 128 + t] =
        (red[0][t] + red[1][t]) + (red[2][t] + red[3][t]);
}

// ---------------- selection phase 2: finish mean, project, normalize --------
// NOTE: qpart holds SC-scaled sums; uniform positive scale cancels in
// _normalize, so scores are unchanged (up to fp rounding ~1e-7).
__global__ void qproj_kernel(const float* __restrict__ partial,
                             const float* __restrict__ proj,
                             float* __restrict__ qp) {
  __shared__ float meanq[128];
  __shared__ float qps[32];
  __shared__ float nrm;
  const int bh = blockIdx.x, t = threadIdx.x;
  float s = 0.0f;
#pragma unroll
  for (int c = 0; c < 16; ++c) s += partial[((size_t)bh * 16 + c) * 128 + t];
  meanq[t] = s * (1.0f / 2048.0f);
  __syncthreads();
  if (t < 32) {
    float sum = 0.0f;
    for (int d = 0; d < 128; ++d) sum = fmaf(meanq[d], proj[d * 32 + t], sum);
    qps[t] = sum;
  }
  __syncthreads();
  if (t == 0) {
    float sum = 0.0f;
    for (int j = 0; j < 32; ++j) sum += qps[j] * qps[j];
    nrm = 1.0f / fmaxf(sqrtf(sum), 1e-12f);
  }
  __syncthreads();
  if (t < 32) qp[bh * 32 + t] = qps[t] * nrm;
}

// ---------------- selection phase 3: per-(bh,block) score ----------------
__global__ __launch_bounds__(256) void kscore_kernel(const float* __restrict__ k,
                                                     const float* __restrict__ proj,
                                                     const float* __restrict__ qp,
                                                     float* __restrict__ scores) {
  __shared__ float ps[128][32];
  __shared__ float kp[64][33];
  __shared__ float cent[33];
  __shared__ float nrm;
  const int bh = blockIdx.x >> 5, n = blockIdx.x & 31;
  const int t = threadIdx.x;
  for (int i = t; i < 4096; i += 256) ps[i >> 5][i & 31] = proj[i];
  const float* kn = k + ((size_t)bh * S_ + n * 64) * DH;
  __syncthreads();
  {
    int row = t >> 2, j0 = (t & 3) * 8;
    float accv[8];
#pragma unroll
    for (int jj = 0; jj < 8; ++jj) accv[jj] = 0.0f;
#pragma unroll 4
    for (int d = 0; d < 128; ++d) {
      float kv = kn[(size_t)row * DH + d];
#pragma unroll
      for (int jj = 0; jj < 8; ++jj) accv[jj] = fmaf(kv, ps[d][j0 + jj], accv[jj]);
    }
#pragma unroll
    for (int jj = 0; jj < 8; ++jj) kp[row][j0 + jj] = accv[jj];
  }
  __syncthreads();
  if (t < 64) {
    float sum = 0.0f;
    for (int j = 0; j < 32; ++j) sum += kp[t][j] * kp[t][j];
    float scl = 1.0f / fmaxf(sqrtf(sum), 1e-12f);
    for (int j = 0; j < 32; ++j) kp[t][j] *= scl;
  }
  __syncthreads();
  if (t < 32) {
    float sum = 0.0f;
    for (int r2 = 0; r2 < 64; ++r2) sum += kp[r2][t];
    cent[t] = sum * (1.0f / 64.0f);
  }
  __syncthreads();
  if (t == 0) {
    float sum = 0.0f;
    for (int j = 0; j < 32; ++j) sum += cent[j] * cent[j];
    nrm = 1.0f / fmaxf(sqrtf(sum), 1e-12f);
  }
  __syncthreads();
  if (t < 32) cent[t] *= nrm;
  __syncthreads();
  if (t < 64) {
    float dt = 0.0f;
    for (int j = 0; j < 32; ++j) dt = fmaf(kp[t][j], cent[j], dt);
#pragma unroll
    for (int off = 32; off; off >>= 1) dt = fminf(dt, __shfl_xor(dt, off));
    if (t == 0) {
      float radius = fminf(fmaxf(1.0f - dt, 0.0f), 1.0f);
      float dq = 0.0f;
      for (int j = 0; j < 32; ++j) dq = fmaf(qp[bh * 32 + j], cent[j], dq);
      scores[bh * 32 + n] = dq + radius;
    }
  }
}

// ---------------- selection phase 4: top-18 + sort ----------------
__global__ void topk_kernel(const float* __restrict__ scores, int* __restrict__ top_idx) {
  if (threadIdx.x != 0) return;
  const int bh = blockIdx.x;
  float sc[NBLK];
  for (int j = 0; j < NBLK; ++j) sc[j] = scores[bh * 32 + j];
  sc[NBLK - 2] = INFINITY;
  sc[NBLK - 1] = INFINITY;
  int chosen[NKEEP];
  bool used[NBLK];
  for (int j = 0; j < NBLK; ++j) used[j] = false;
  for (int kk = 0; kk < NKEEP; ++kk) {
    int best = -1;
    float bv = 0.0f;
    for (int j = 0; j < NBLK; ++j)
      if (!used[j] && (best < 0 || sc[j] > bv)) { bv = sc[j]; best = j; }
    used[best] = true;
    chosen[kk] = best;
  }
  for (int a = 1; a < NKEEP; ++a) {
    int v2 = chosen[a], b2 = a - 1;
    while (b2 >= 0 && chosen[b2] > v2) { chosen[b2 + 1] = chosen[b2]; --b2; }
    chosen[b2 + 1] = v2;
  }
  for (int a = 0; a < NKEEP; ++a) top_idx[bh * NKEEP + a] = chosen[a];
}

// ---------------- MFMA attention v9: per-lane ls partials (deferred reduce) -
__global__ __launch_bounds__(256) void attn_mfma_kernel(const _Float16* __restrict__ qfp,
                                                        const _Float16* __restrict__ kf,
                                                        const _Float16* __restrict__ vt,
                                                        const int* __restrict__ top_idx,
                                                        _Float16* __restrict__ yf) {
  __shared__ char lds[74752];  // buf0 0..32K (K 16K|V 16K), buf1 32..64K, P 64K..
  const int bh = blockIdx.x >> 5;
  const int qt = blockIdx.x & 31;
  const int t = threadIdx.x, l = t & 63, w = t >> 6;
  const int lr = l & 15, lg = l >> 4;
  const float THR2 = 11.5415603f;  // 8 * log2(e)

  f16x8 qf[4];
  {
    const _Float16* qbase = qfp + ((size_t)(bh * S_ + qt * 64 + w * 16 + lr)) * DH + lg * 8;
#pragma unroll
    for (int dc = 0; dc < 4; ++dc)
      qf[dc] = *(const f16x8*)(qbase + dc * 32);
  }

  float m_[4] = {-INFINITY, -INFINITY, -INFINITY, -INFINITY};
  float ls[4] = {0.f, 0.f, 0.f, 0.f};  // PER-LANE partial sums
  f32x4 yacc[8];
#pragma unroll
  for (int dt = 0; dt < 8; ++dt) yacc[dt] = (f32x4){0.f, 0.f, 0.f, 0.f};

  char* Pw = lds + 65536 + w * 2304;  // per-wave P: [16 q][72 fp16]

  const _Float16* kb0 = kf + (size_t)bh * S_ * DH;
  const _Float16* vb0 = vt + (size_t)bh * DH * S_;
  const int* idxp = top_idx + bh * NKEEP;

  auto STAGE = [&](int blk, int c) {
    char* base = lds + c * 32768;
#pragma unroll
    for (int f0 = 0; f0 < 4; ++f0) {
      int f = w * 4 + f0;
      int kt = f >> 2, dc = f & 3;
      GLOAD16(kb0 + (size_t)(blk * 64 + kt * 16 + lr) * DH + dc * 32 + lg * 8,
              base + f * 1024);
      int K0 = f >> 3, dt = f & 7;
      GLOAD16(vb0 + (size_t)(dt * 16 + lr) * S_ + blk * 64 + K0 * 32 + lg * 8,
              base + 16384 + f * 1024);
    }
  };

  int cur = 0;
  STAGE(idxp[0], 0);

  for (int it = 0; it < NKEEP; ++it) {
    if (it + 1 < NKEEP) {
      STAGE(idxp[it + 1], cur ^ 1);
      asm volatile("s_waitcnt vmcnt(8)" ::: "memory");
    } else {
      asm volatile("s_waitcnt vmcnt(0)" ::: "memory");
    }
    __builtin_amdgcn_s_barrier();
    char* buf = lds + cur * 32768;

    f32x4 sacc[4];
#pragma unroll
    for (int kt = 0; kt < 4; ++kt) sacc[kt] = (f32x4){0.f, 0.f, 0.f, 0.f};
    __builtin_amdgcn_s_setprio(1);
#pragma unroll
    for (int kt = 0; kt < 4; ++kt)
#pragma unroll
      for (int dc = 0; dc < 4; ++dc) {
        f16x8 kfr = *(const f16x8*)(buf + (kt * 4 + dc) * 1024 + l * 16);
        sacc[kt] = __builtin_amdgcn_mfma_f32_16x16x32_f16(qf[dc], kfr, sacc[kt], 0, 0, 0);
      }
    __builtin_amdgcn_s_setprio(0);

    float lmax[4];
#pragma unroll
    for (int r = 0; r < 4; ++r)
      lmax[r] = fmaxf(fmaxf(sacc[0][r], sacc[1][r]), fmaxf(sacc[2][r], sacc[3][r]));
    bool ok = (lmax[0] <= m_[0] + THR2) && (lmax[1] <= m_[1] + THR2) &&
              (lmax[2] <= m_[2] + THR2) && (lmax[3] <= m_[3] + THR2);
    float p[4][4];
    if (__all(ok)) {
#pragma unroll
      for (int r = 0; r < 4; ++r) {
#pragma unroll
        for (int kt = 0; kt < 4; ++kt) {
          p[kt][r] = fexp2(sacc[kt][r] - m_[r]);
          ls[r] += p[kt][r];
        }
      }
    } else {
#pragma unroll
      for (int r = 0; r < 4; ++r) {
        float mv = lmax[r];
#pragma unroll
        for (int off = 1; off < 16; off <<= 1) mv = fmaxf(mv, __shfl_xor(mv, off));
        float mn = fmaxf(m_[r], mv);
        float corr = fexp2(m_[r] - mn);
        float rs = 0.f;
#pragma unroll
        for (int kt = 0; kt < 4; ++kt) {
          p[kt][r] = fexp2(sacc[kt][r] - mn);
          rs += p[kt][r];
        }
        ls[r] = ls[r] * corr + rs;
        m_[r] = mn;
#pragma unroll
        for (int dt = 0; dt < 8; ++dt) yacc[dt][r] *= corr;
      }
    }

#pragma unroll
    for (int kt = 0; kt < 4; ++kt)
#pragma unroll
      for (int r = 0; r < 4; ++r)
        *(_Float16*)(Pw + (lg * 4 + r) * 144 + (kt * 16 + lr) * 2) = (_Float16)p[kt][r];

    __builtin_amdgcn_s_setprio(1);
#pragma unroll
    for (int K0 = 0; K0 < 2; ++K0) {
      f16x8 pa = *(const f16x8*)(Pw + lr * 144 + K0 * 64 + lg * 16);
#pragma unroll
      for (int dt = 0; dt < 8; ++dt) {
        f16x8 vf = *(const f16x8*)(buf + 16384 + (K0 * 8 + dt) * 1024 + l * 16);
        yacc[dt] = __builtin_amdgcn_mfma_f32_16x16x32_f16(pa, vf, yacc[dt], 0, 0, 0);
      }
    }
    __builtin_amdgcn_s_setprio(0);

    __builtin_amdgcn_s_barrier();
    cur ^= 1;
  }

  // epilogue: reduce per-lane ls partials across the row's 16 lanes (once)
  const int b = bh >> 4, h = bh & (H_ - 1);
  float inv[4];
#pragma unroll
  for (int r = 0; r < 4; ++r) {
    float s = ls[r];
#pragma unroll
    for (int off = 1; off < 16; off <<= 1) s += __shfl_xor(s, off);
    inv[r] = 1.0f / s;
  }
#pragma unroll
  for (int r = 0; r < 4; ++r) {
    int srow = qt * 64 + w * 16 + lg * 4 + r;
    size_t off0 = ((size_t)b * S_ + srow) * DM + h * DH + lr;
#pragma unroll
    for (int dt = 0; dt < 8; ++dt)
      yf[off0 + dt * 16] = (_Float16)(yacc[dt][r] * inv[r]);
  }
}

extern "C" void kernel_launch(void* const* d_in, const int* in_sizes, int n_in,
                              void* d_out, int out_size, void* d_ws, size_t ws_size,
                              hipStream_t stream) {
  const float* x  = (const float*)d_in[0];
  const float* Wq = (const float*)d_in[1];
  const float* Wk = (const float*)d_in[2];
  const float* Wv = (const float*)d_in[3];
  const float* Wo = (const float*)d_in[4];
  const float* qg = (const float*)d_in[5];
  float* out = (float*)d_out;

  const size_t NE = (size_t)BH * S_ * DH;   // 8388608 elements
  const size_t WE = (size_t)DM * DM;        // 4194304 elements per W
  char* p = (char*)d_ws;
  float* q_ws = (float*)p; p += NE * 4;     // kpart1 during k-GEMM, then q f32
  float* k_ws = (float*)p; p += NE * 4;     // kpart0 -> roped k f32
  unsigned short* xhi = (unsigned short*)p; p += NE * 2;  // -> yf16 after k-GEMM
  unsigned short* xlo = (unsigned short*)p; p += NE * 2;  // -> vt after k-GEMM
  _Float16* xf16 = (_Float16*)p; p += NE * 2;             // -> qf16 after qv-GEMM
  unsigned short* wkhi = (unsigned short*)p; p += WE * 2; // \ kf16 spans wkhi+wklo
  unsigned short* wklo = (unsigned short*)p; p += WE * 2; // / (both dead post k-GEMM)
  _Float16* wqv = (_Float16*)p; p += 2 * WE * 2;          // [Wq;Wv] fp16; -> wo
  float* cosb = (float*)p; p += (size_t)S_ * 64 * 4;
  float* sinb = (float*)p; p += (size_t)S_ * 64 * 4;
  float* projb = (float*)p; p += 4096 * 4;
  int* idxb = (int*)p; p += BH * NKEEP * 4;
  float* scores = (float*)p; p += BH * NBLK * 4;
  float* qpbuf = (float*)p; p += BH * 32 * 4;
  // aliases (each with size check, stream-ordered):
  float* qpart = cosb;                   // 512*128*4 = 262KB <= 1MB (cosb+sinb);
                                         // written by rmsrope_q AFTER its cosb reads
                                         // within the same kernel? NO - see below.
  float* kpart1 = q_ws;                  // NE f32 = NE f32; qv writes q after rmsrope_k
  _Float16* kf16 = (_Float16*)wkhi;      // NE fp16 = 16.8MB = wkhi+wklo, both dead
  _Float16* vt = (_Float16*)xlo;         // NE fp16 <= NE ushort; xlo dead after k-GEMM
  _Float16* yf16 = (_Float16*)xhi;       // NE fp16 <= NE ushort; xhi dead after k-GEMM
  _Float16* qf16 = xf16;                 // NE fp16 = NE fp16; xf16 dead after qv-GEMM
  _Float16* wo = wqv;                    // WE fp16 <= 2WE fp16; wqv dead after qv-GEMM
  // HAZARD CHECK: rmsrope_q now READS cosb while qpart aliases cosb -> must NOT
  // alias. Use sinb+tail? sinb also read. SAFE FIX: qpart goes to the scores
  // tail region instead (fresh 262KB after qpbuf).
  float* qpart2 = (float*)p; p += (size_t)BH * 16 * 128 * 4;  // 262KB, fresh
  qpart = qpart2;
  // total ws use ~152.4 MB

  const int nx4 = (int)(NE / 4);
  const int nw4 = (int)(WE / 4);

  tables_kernel<<<dim3(16 + S_), dim3(256), 0, stream>>>(projb, cosb, sinb);
  split_x3_kernel<<<dim3(nx4 / 256), dim3(256), 0, stream>>>(x, xhi, xlo, xf16, nx4);
  split_w3_kernel<<<dim3(nw4 / 256), dim3(256), 0, stream>>>(Wk, Wq, Wv, wkhi, wklo,
                                                             wqv, wqv + WE, nw4);

  // k: bf16x3, split-K=2, 8-wave 256^2, min-barrier counted-vmcnt schedule
  mfma_gemm_k_sk<<<dim3(8, 16, 2), dim3(512), 0, stream>>>(xhi, xlo, wkhi, wklo,
                                                           k_ws, kpart1);

  // k finalize: sum partials + RMS + RoPE; writes k f32 (in place) + kf16
  rmsrope_k_kernel<<<dim3((BH * S_) / 4), dim3(256), 0, stream>>>(k_ws, kpart1, kf16, cosb, sinb);

  // q+V fused: fp16, 256^2 8-wave, min-barrier; overwrites kpart1 — safe now
  mfma_gemm_qv<<<dim3(16, 16), dim3(512), 0, stream>>>(xf16, wqv, q_ws, vt);

  // q finalize: RMS + RoPE + gain + fused q-mean partials (replaces qmean_part)
  rmsrope_q_kernel<<<dim3(BH * 16), dim3(256), 0, stream>>>(q_ws, qf16, cosb, sinb, qg, qpart);

  qproj_kernel<<<dim3(BH), dim3(128), 0, stream>>>(qpart, projb, qpbuf);
  kscore_kernel<<<dim3(BH * NBLK), dim3(256), 0, stream>>>(k_ws, projb, qpbuf, scores);
  topk_kernel<<<dim3(BH), dim3(64), 0, stream>>>(scores, idxb);

  // attn v9: per-lane ls partials, raw v_exp softmax, lazy max-reduce defer
  attn_mfma_kernel<<<dim3(BH * 32), dim3(256), 0, stream>>>(qf16, kf16, vt, idxb, yf16);

  // O: fp16 x1 on yf16 and Wo-f16
  split_f16_kernel<<<dim3(nw4 / 256), dim3(256), 0, stream>>>(Wo, wo, nw4);
  mfma_gemm_f16<1><<<dim3(16, 32), dim3(256), 0, stream>>>(yf16, wo, out);
}

// Round 23
// 397.426 us; speedup vs baseline: 1.1257x; 1.0344x over previous
//
#include <hip/hip_runtime.h>
#include <hip/hip_bf16.h>

#define B_ 2
#define S_ 2048
#define DM 2048
#define H_ 16
#define DH 128
#define NBLK 32
#define NKEEP 18
#define BH (B_ * H_)

typedef __attribute__((ext_vector_type(8))) short short8;
typedef __attribute__((ext_vector_type(8))) _Float16 f16x8;
typedef __attribute__((ext_vector_type(4))) _Float16 f16x4;
typedef __attribute__((ext_vector_type(4))) float f32x4;

#define GLOAD16(gp, lp)                                                        \
  __builtin_amdgcn_global_load_lds(                                            \
      (const __attribute__((address_space(1))) unsigned int*)(const void*)(gp),\
      (__attribute__((address_space(3))) unsigned int*)(void*)(lp), 16, 0, 0)

__device__ __forceinline__ unsigned short f32_to_bf16(float f) {
  unsigned u = __float_as_uint(f);
  unsigned r = (u + 0x7fffu + ((u >> 16) & 1u)) >> 16;
  return (unsigned short)r;
}
__device__ __forceinline__ float bf16_to_f32(unsigned short h) {
  return __uint_as_float(((unsigned)h) << 16);
}
// raw HW 2^x (logits pre-scaled into log2 domain); no libm fixup code
__device__ __forceinline__ float fexp2(float x) {
  float r;
  asm("v_exp_f32 %0, %1" : "=v"(r) : "v"(x));
  return r;
}

// ---------------- proj: threefry2x32 (partitionable) + erfinv ----------------
__device__ __forceinline__ unsigned rotl32(unsigned x, int r) {
  return (x << r) | (x >> (32 - r));
}

__device__ __forceinline__ float erfinv_f32(float x) {
  float w = -log1pf(-x * x);
  float p;
  if (w < 5.0f) {
    w -= 2.5f;
    p = 2.81022636e-08f;
    p = fmaf(p, w, 3.43273939e-07f);
    p = fmaf(p, w, -3.5233877e-06f);
    p = fmaf(p, w, -4.39150654e-06f);
    p = fmaf(p, w, 0.00021858087f);
    p = fmaf(p, w, -0.00125372503f);
    p = fmaf(p, w, -0.00417768164f);
    p = fmaf(p, w, 0.246640727f);
    p = fmaf(p, w, 1.50140941f);
  } else {
    w = sqrtf(w) - 3.0f;
    p = -0.000200214257f;
    p = fmaf(p, w, 0.000100950558f);
    p = fmaf(p, w, 0.00134934322f);
    p = fmaf(p, w, -0.00367342844f);
    p = fmaf(p, w, 0.00573950773f);
    p = fmaf(p, w, -0.0076224613f);
    p = fmaf(p, w, 0.00943887047f);
    p = fmaf(p, w, 1.00167406f);
    p = fmaf(p, w, 2.83297682f);
  }
  return p * x;
}

__device__ __forceinline__ float bits_to_normal(unsigned b) {
  float f = __uint_as_float((b >> 9) | 0x3f800000u) - 1.0f;
  const float lo = -0.9999999403953552f;
  float u = fmaxf(lo, fmaf(f, 2.0f, lo));
  return 1.4142135623730951f * erfinv_f32(u);
}

// ---------------- fused tables: proj (blocks 0..15) + RoPE (blocks 16..) ----
__global__ void tables_kernel(float* __restrict__ proj,
                              float* __restrict__ cosb,
                              float* __restrict__ sinb) {
  if (blockIdx.x < 16) {
    int i = blockIdx.x * 256 + threadIdx.x;
    unsigned k0 = 0u, k1 = 42u;
    unsigned k2 = 0x1BD11BDAu ^ k0 ^ k1;
    unsigned x0 = 0u, x1 = (unsigned)i;
    x0 += k0; x1 += k1;
#define QR(r) { x0 += x1; x1 = rotl32(x1, r); x1 ^= x0; }
    QR(13) QR(15) QR(26) QR(6)   x0 += k1; x1 += k2 + 1u;
    QR(17) QR(29) QR(16) QR(24)  x0 += k2; x1 += k0 + 2u;
    QR(13) QR(15) QR(26) QR(6)   x0 += k0; x1 += k1 + 3u;
    QR(17) QR(29) QR(16) QR(24)  x0 += k1; x1 += k2 + 4u;
    QR(13) QR(15) QR(26) QR(6)   x0 += k2; x1 += k0 + 5u;
#undef QR
    proj[i] = bits_to_normal(x0 ^ x1) / 5.656854249492381f;
  } else {
    int s = blockIdx.x - 16;
    int j = threadIdx.x;
    if (j < 64) {
      double e = (double)(2 * j) / 128.0;
      double invf = 1.0 / pow(10000.0, e);
      float freq = (float)s * (float)invf;
      cosb[s * 64 + j] = (float)cos((double)freq);
      sinb[s * 64 + j] = (float)sin((double)freq);
    }
  }
}

// ---------------- x -> bf16 hi/lo + fp16, single pass ----------------
__global__ __launch_bounds__(256) void split_x3_kernel(const float* __restrict__ in,
                                                       unsigned short* __restrict__ hi,
                                                       unsigned short* __restrict__ lo,
                                                       _Float16* __restrict__ f16,
                                                       int n4) {
  int i = blockIdx.x * blockDim.x + threadIdx.x;
  if (i >= n4) return;
  float4 v = ((const float4*)in)[i];
  ushort4 hv, lv;
  f16x4 fv;
  hv.x = f32_to_bf16(v.x); lv.x = f32_to_bf16(v.x - bf16_to_f32(hv.x)); fv[0] = (_Float16)v.x;
  hv.y = f32_to_bf16(v.y); lv.y = f32_to_bf16(v.y - bf16_to_f32(hv.y)); fv[1] = (_Float16)v.y;
  hv.z = f32_to_bf16(v.z); lv.z = f32_to_bf16(v.z - bf16_to_f32(hv.z)); fv[2] = (_Float16)v.z;
  hv.w = f32_to_bf16(v.w); lv.w = f32_to_bf16(v.w - bf16_to_f32(hv.w)); fv[3] = (_Float16)v.w;
  ((ushort4*)hi)[i] = hv;
  ((ushort4*)lo)[i] = lv;
  ((f16x4*)f16)[i] = fv;
}

// ---------------- fused W split: Wk -> bf16 hi/lo; Wq, Wv -> fp16 ----------
__global__ __launch_bounds__(256) void split_w3_kernel(const float* __restrict__ wk,
                                                       const float* __restrict__ wq,
                                                       const float* __restrict__ wv,
                                                       unsigned short* __restrict__ khi,
                                                       unsigned short* __restrict__ klo,
                                                       _Float16* __restrict__ qf,
                                                       _Float16* __restrict__ vf,
                                                       int n4) {
  int i = blockIdx.x * blockDim.x + threadIdx.x;
  if (i >= n4) return;
  {
    float4 v = ((const float4*)wk)[i];
    ushort4 hv, lv;
    hv.x = f32_to_bf16(v.x); lv.x = f32_to_bf16(v.x - bf16_to_f32(hv.x));
    hv.y = f32_to_bf16(v.y); lv.y = f32_to_bf16(v.y - bf16_to_f32(hv.y));
    hv.z = f32_to_bf16(v.z); lv.z = f32_to_bf16(v.z - bf16_to_f32(hv.z));
    hv.w = f32_to_bf16(v.w); lv.w = f32_to_bf16(v.w - bf16_to_f32(hv.w));
    ((ushort4*)khi)[i] = hv;
    ((ushort4*)klo)[i] = lv;
  }
  {
    float4 v = ((const float4*)wq)[i];
    f16x4 fv;
    fv[0] = (_Float16)v.x; fv[1] = (_Float16)v.y;
    fv[2] = (_Float16)v.z; fv[3] = (_Float16)v.w;
    ((f16x4*)qf)[i] = fv;
  }
  {
    float4 v = ((const float4*)wv)[i];
    f16x4 fv;
    fv[0] = (_Float16)v.x; fv[1] = (_Float16)v.y;
    fv[2] = (_Float16)v.z; fv[3] = (_Float16)v.w;
    ((f16x4*)vf)[i] = fv;
  }
}

// ---------------- W -> fp16 (Wo, late) ----------------
__global__ __launch_bounds__(256) void split_f16_kernel(const float* __restrict__ in,
                                                        _Float16* __restrict__ f16,
                                                        int n4) {
  int i = blockIdx.x * blockDim.x + threadIdx.x;
  if (i >= n4) return;
  float4 v = ((const float4*)in)[i];
  f16x4 fv;
  fv[0] = (_Float16)v.x; fv[1] = (_Float16)v.y;
  fv[2] = (_Float16)v.z; fv[3] = (_Float16)v.w;
  ((f16x4*)f16)[i] = fv;
}

// ---------------- k-GEMM: bf16x3, 256x256, 8 waves, SPLIT-K=2 ---------------
// Minimal-barrier schedule (R21-proven): 2 barriers per K-step.
__global__ __launch_bounds__(512, 2) void mfma_gemm_k_sk(const unsigned short* __restrict__ Ahi,
                                                         const unsigned short* __restrict__ Alo,
                                                         const unsigned short* __restrict__ Whi,
                                                         const unsigned short* __restrict__ Wlo,
                                                         float* __restrict__ kp0,
                                                         float* __restrict__ kp1) {
  __shared__ char smem[131072];  // 2 buf x 64K: Ahi 0|Alo 16K|Bhi 32K|Blo 48K
  const int t = threadIdx.x, l = t & 63, w = t >> 6;  // 8 waves
  const int lin = blockIdx.z * 128 + blockIdx.y * 8 + blockIdx.x;
  const int swz = (lin & 7) * 32 + (lin >> 3);        // 256 blocks, bijective
  const int kz = swz >> 7;
  const int idx = swz & 127;
  const int n0 = (idx & 7) * 256;
  const int m0 = (idx >> 3) * 256;
  const int kbase = kz * 1024;
  float* C = kz ? kp1 : kp0;
  const int wm = w >> 2, wn = w & 3;                  // 2M x 4N wave grid
  const int lr = l & 15;
  const int lg8 = (l >> 4) * 8;
  const size_t rstep = (size_t)16 * DM;

  const unsigned short* gAh = Ahi + (size_t)(m0 + w * 32 + lr) * DM + lg8;
  const unsigned short* gAl = Alo + (size_t)(m0 + w * 32 + lr) * DM + lg8;
  const unsigned short* gBh = Whi + (size_t)(n0 + w * 32 + lr) * DM + lg8;
  const unsigned short* gBl = Wlo + (size_t)(n0 + w * 32 + lr) * DM + lg8;

  f32x4 acc[8][4];
#pragma unroll
  for (int i = 0; i < 8; ++i)
#pragma unroll
    for (int j = 0; j < 4; ++j) acc[i][j] = (f32x4){0.f, 0.f, 0.f, 0.f};

  {  // prologue: full stage of tile 0 into buf 0
    char* base = smem + w * 2048;
    GLOAD16(gAh + kbase, base);
    GLOAD16(gAh + rstep + kbase, base + 1024);
    GLOAD16(gAl + kbase, base + 16384);
    GLOAD16(gAl + rstep + kbase, base + 16384 + 1024);
    GLOAD16(gBh + kbase, base + 32768);
    GLOAD16(gBh + rstep + kbase, base + 32768 + 1024);
    GLOAD16(gBl + kbase, base + 49152);
    GLOAD16(gBl + rstep + kbase, base + 49152 + 1024);
  }
  int cur = 0;

#define KQUAD(q)                                                                        \
  {                                                                                     \
    short8 ah0 = *(const short8*)(buf + (wm * 8 + 2 * (q)) * 1024 + l * 16);            \
    short8 ah1 = *(const short8*)(buf + (wm * 8 + 2 * (q) + 1) * 1024 + l * 16);        \
    short8 al0 = *(const short8*)(buf + 16384 + (wm * 8 + 2 * (q)) * 1024 + l * 16);    \
    short8 al1 = *(const short8*)(buf + 16384 + (wm * 8 + 2 * (q) + 1) * 1024 + l * 16);\
    __builtin_amdgcn_s_setprio(1);                                                      \
    _Pragma("unroll")                                                                   \
    for (int n = 0; n < 4; ++n) {                                                       \
      acc[2 * (q)][n] = __builtin_amdgcn_mfma_f32_16x16x32_bf16(ah0, bh[n], acc[2 * (q)][n], 0, 0, 0); \
      acc[2 * (q)][n] = __builtin_amdgcn_mfma_f32_16x16x32_bf16(ah0, bl[n], acc[2 * (q)][n], 0, 0, 0); \
      acc[2 * (q)][n] = __builtin_amdgcn_mfma_f32_16x16x32_bf16(al0, bh[n], acc[2 * (q)][n], 0, 0, 0); \
    }                                                                                   \
    _Pragma("unroll")                                                                   \
    for (int n = 0; n < 4; ++n) {                                                       \
      acc[2 * (q) + 1][n] = __builtin_amdgcn_mfma_f32_16x16x32_bf16(ah1, bh[n], acc[2 * (q) + 1][n], 0, 0, 0); \
      acc[2 * (q) + 1][n] = __builtin_amdgcn_mfma_f32_16x16x32_bf16(ah1, bl[n], acc[2 * (q) + 1][n], 0, 0, 0); \
      acc[2 * (q) + 1][n] = __builtin_amdgcn_mfma_f32_16x16x32_bf16(al1, bh[n], acc[2 * (q) + 1][n], 0, 0, 0); \
    }                                                                                   \
    __builtin_amdgcn_s_setprio(0);                                                      \
  }

  for (int k0 = kbase; k0 < kbase + 1024; k0 += 32) {
    const bool more = (k0 + 32 < kbase + 1024);
    char* buf = smem + cur * 65536;
    char* nb = smem + (cur ^ 1) * 65536 + w * 2048;
    const int kn = k0 + 32;

    if (more) {
      GLOAD16(gBh + kn, nb + 32768);
      GLOAD16(gBh + rstep + kn, nb + 32768 + 1024);
      asm volatile("s_waitcnt vmcnt(2)" ::: "memory");
    } else {
      asm volatile("s_waitcnt vmcnt(0)" ::: "memory");
    }
    __builtin_amdgcn_s_barrier();

    short8 bh[4], bl[4];
#pragma unroll
    for (int f = 0; f < 4; ++f) {
      bh[f] = *(const short8*)(buf + 32768 + (wn * 4 + f) * 1024 + l * 16);
      bl[f] = *(const short8*)(buf + 49152 + (wn * 4 + f) * 1024 + l * 16);
    }
    KQUAD(0);

    if (more) {
      GLOAD16(gBl + kn, nb + 49152);
      GLOAD16(gBl + rstep + kn, nb + 49152 + 1024);
    }
    KQUAD(1);

    if (more) {
      GLOAD16(gAh + kn, nb);
      GLOAD16(gAh + rstep + kn, nb + 1024);
    }
    KQUAD(2);

    if (more) {
      GLOAD16(gAl + kn, nb + 16384);
      GLOAD16(gAl + rstep + kn, nb + 16384 + 1024);
    }
    KQUAD(3);

    __builtin_amdgcn_s_barrier();
    cur ^= 1;
  }
#undef KQUAD

#pragma unroll
  for (int m = 0; m < 8; ++m) {
    int row0 = m0 + wm * 128 + m * 16 + (l >> 4) * 4;
#pragma unroll
    for (int n = 0; n < 4; ++n) {
      int col = n0 + wn * 64 + n * 16 + (l & 15);
      int h = col >> 7, d = col & 127;
#pragma unroll
      for (int r = 0; r < 4; ++r) {
        int mm = row0 + r;
        int b = mm >> 11, s = mm & (S_ - 1);
        C[(((size_t)(b * H_ + h) * S_) + s) * DH + d] = acc[m][n][r];
      }
    }
  }
}

// ---------------- fused q+V fp16 GEMM, 256x256, 8 waves, 4Mx2N wave grid ----
// Wave tile 64 rows x 128 cols = one FULL head per wave -> the q epilogue can
// do RMS+RoPE+gain+fp16-emit+q-mean-partials entirely in registers (replaces
// rmsrope_q and the q f32 round-trip). MFMA accumulation order per output
// element is identical to the 2Mx4N schedule -> pre-epilogue values bitwise
// same. Min-barrier 2-phase schedule (16 MFMA/phase, R18-proven granularity).
__global__ __launch_bounds__(512, 2) void mfma_gemm_qv(const _Float16* __restrict__ A,
                                                       const _Float16* __restrict__ W,
                                                       const float* __restrict__ cosb,
                                                       const float* __restrict__ sinb,
                                                       const float* __restrict__ qg,
                                                       _Float16* __restrict__ qf,
                                                       float* __restrict__ qpart,
                                                       _Float16* __restrict__ vt) {
  __shared__ char smem[65536];  // 2 buf x 32K: A frags 0..16K | B frags 16..32K
  const int t = threadIdx.x, l = t & 63, w = t >> 6;  // 8 waves
  const int lin = blockIdx.y * gridDim.x + blockIdx.x;
  const int swz = (lin & 7) * 32 + (lin >> 3);        // 256 blocks, bijective
  const int n0 = (swz & 15) * 256;
  const int m0 = (swz >> 4) * 256;
  const int wm = w >> 1, wn = w & 1;                  // 4M x 2N wave grid
  const int lr = l & 15;
  const int lg = l >> 4;
  const int lg8 = lg * 8;
  const size_t rstep = (size_t)16 * DM;

  const _Float16* gA = A + (size_t)(m0 + w * 32 + lr) * DM + lg8;
  const _Float16* gB = W + (size_t)(n0 + w * 32 + lr) * DM + lg8;

  f32x4 acc[4][8];
#pragma unroll
  for (int i = 0; i < 4; ++i)
#pragma unroll
    for (int j = 0; j < 8; ++j) acc[i][j] = (f32x4){0.f, 0.f, 0.f, 0.f};

  {  // prologue (staging assignment independent of compute wave grid)
    char* base = smem + w * 2048;
    GLOAD16(gA, base);
    GLOAD16(gA + rstep, base + 1024);
    GLOAD16(gB, base + 16384);
    GLOAD16(gB + rstep, base + 16384 + 1024);
  }
  int cur = 0;

  for (int k0 = 0; k0 < DM; k0 += 32) {
    const bool more = (k0 + 32 < DM);
    char* buf = smem + cur * 32768;
    char* nb = smem + (cur ^ 1) * 32768 + w * 2048;
    const int kn = k0 + 32;

    // entry: issue next A pair; sync current tile
    if (more) {
      GLOAD16(gA + kn, nb);
      GLOAD16(gA + rstep + kn, nb + 1024);
      asm volatile("s_waitcnt vmcnt(2)" ::: "memory");
    } else {
      asm volatile("s_waitcnt vmcnt(0)" ::: "memory");
    }
    __builtin_amdgcn_s_barrier();

    f16x8 a[4];
#pragma unroll
    for (int m = 0; m < 4; ++m)
      a[m] = *(const f16x8*)(buf + (wm * 4 + m) * 1024 + l * 16);
    __builtin_amdgcn_s_setprio(1);
#pragma unroll
    for (int n = 0; n < 4; ++n) {
      f16x8 b = *(const f16x8*)(buf + 16384 + (wn * 8 + n) * 1024 + l * 16);
#pragma unroll
      for (int m = 0; m < 4; ++m)
        acc[m][n] = __builtin_amdgcn_mfma_f32_16x16x32_f16(a[m], b, acc[m][n], 0, 0, 0);
    }
    __builtin_amdgcn_s_setprio(0);

    // (no mid barrier: frags read the same stable buffer)
    if (more) {
      GLOAD16(gB + kn, nb + 16384);
      GLOAD16(gB + rstep + kn, nb + 16384 + 1024);
    }
    __builtin_amdgcn_s_setprio(1);
#pragma unroll
    for (int n = 4; n < 8; ++n) {
      f16x8 b = *(const f16x8*)(buf + 16384 + (wn * 8 + n) * 1024 + l * 16);
#pragma unroll
      for (int m = 0; m < 4; ++m)
        acc[m][n] = __builtin_amdgcn_mfma_f32_16x16x32_f16(a[m], b, acc[m][n], 0, 0, 0);
    }
    __builtin_amdgcn_s_setprio(0);
    __builtin_amdgcn_s_barrier();  // exit: reads done before buf overwritten

    cur ^= 1;
  }

  const int b2 = m0 >> 11;                // batch
  const int sbase = (m0 & (S_ - 1)) + wm * 64;

  if (n0 < DM) {
    // ---- q epilogue: RMS + RoPE + gain, emit fp16 + q-mean col partials ----
    const int h = (n0 >> 7) + wn;
    const float g = qg[h] * 0.12751743f;  // 1/sqrt(128) * log2(e)
    float csum[8];
#pragma unroll
    for (int n = 0; n < 8; ++n) csum[n] = 0.f;
#pragma unroll
    for (int m = 0; m < 4; ++m) {
#pragma unroll
      for (int r = 0; r < 4; ++r) {
        int srow = sbase + m * 16 + lg * 4 + r;
        float ss = 0.f;
#pragma unroll
        for (int n = 0; n < 8; ++n) ss = fmaf(acc[m][n][r], acc[m][n][r], ss);
#pragma unroll
        for (int off = 1; off < 16; off <<= 1) ss += __shfl_xor(ss, off);
        float rms = rsqrtf(ss * (1.0f / 128.0f) + 1e-6f);
        size_t rowoff = ((size_t)(b2 * H_ + h) * S_ + srow) * DH;
#pragma unroll
        for (int n = 0; n < 4; ++n) {
          int j = n * 16 + lr;
          float c = cosb[srow * 64 + j], sn = sinb[srow * 64 + j];
          float x1 = acc[m][n][r] * rms, x2 = acc[m][n + 4][r] * rms;
          float o1 = fmaf(x1, c, x2 * sn) * g;
          float o2 = fmaf(-x1, sn, x2 * c) * g;
          qf[rowoff + j] = (_Float16)o1;
          qf[rowoff + j + 64] = (_Float16)o2;
          csum[n] += o1;
          csum[n + 4] += o2;
        }
      }
    }
    // reduce col sums over lg groups (l, l^16, l^32, l^48) -> 64-row sums
#pragma unroll
    for (int n = 0; n < 8; ++n) {
      csum[n] += __shfl_xor(csum[n], 16);
      csum[n] += __shfl_xor(csum[n], 32);
    }
    if (lg == 0) {
      int chunk = sbase >> 6;  // 32 chunks of 64 rows
      size_t base = (((size_t)(b2 * H_ + h) * 32) + chunk) * 128;
#pragma unroll
      for (int n = 0; n < 8; ++n) qpart[base + n * 16 + lr] = csum[n];
    }
  } else {
    // ---- v epilogue: transposed fp16 emit (unchanged values) ----
    const int h = ((n0 - DM) >> 7) + wn;
#pragma unroll
    for (int m = 0; m < 4; ++m) {
      int s0 = sbase + m * 16 + lg * 4;
#pragma unroll
      for (int n = 0; n < 8; ++n) {
        int d = n * 16 + lr;
        f16x4 vv;
        vv[0] = (_Float16)acc[m][n][0];
        vv[1] = (_Float16)acc[m][n][1];
        vv[2] = (_Float16)acc[m][n][2];
        vv[3] = (_Float16)acc[m][n][3];
        *(f16x4*)(vt + (((size_t)(b2 * H_ + h)) * DH + d) * S_ + s0) = vv;
      }
    }
  }
}

// ---------------- fp16 single-product GEMM (O), BK=64, 128x128 --------------
template <int MODE>
__global__ __launch_bounds__(256) void mfma_gemm_f16(const _Float16* __restrict__ A,
                                                     const _Float16* __restrict__ W,
                                                     void* __restrict__ Cout) {
  __shared__ char smem[65536];
  const int t = threadIdx.x, l = t & 63, w = t >> 6;
  const int lin = blockIdx.y * gridDim.x + blockIdx.x;
  const int cpx = (gridDim.x * gridDim.y) >> 3;
  const int swz = (lin & 7) * cpx + (lin >> 3);
  const int n0 = (swz % gridDim.x) * 128;
  const int m0 = (swz / gridDim.x) * 128;
  const int wm = w >> 1, wn = w & 1;
  const int lr = l & 15;
  const int lg8 = (l >> 4) * 8;

  auto STAGE = [&](int k0, int c) {
    char* base = smem + c * 32768;
#pragma unroll
    for (int f0 = 0; f0 < 4; ++f0) {
      int f = w * 4 + f0;
      int rb = f >> 1, kh = f & 1;
      GLOAD16(A + (size_t)(m0 + rb * 16 + lr) * DM + k0 + kh * 32 + lg8,
              base + f * 1024);
      GLOAD16(W + (size_t)(n0 + rb * 16 + lr) * DM + k0 + kh * 32 + lg8,
              base + 16384 + f * 1024);
    }
  };

  f32x4 acc[4][4];
#pragma unroll
  for (int i = 0; i < 4; ++i)
#pragma unroll
    for (int j = 0; j < 4; ++j) acc[i][j] = (f32x4){0.f, 0.f, 0.f, 0.f};

  STAGE(0, 0);
  int cur = 0;

  for (int k0 = 0; k0 < DM; k0 += 64) {
    if (k0 + 64 < DM) {
      STAGE(k0 + 64, cur ^ 1);
      asm volatile("s_waitcnt vmcnt(8)" ::: "memory");
    } else {
      asm volatile("s_waitcnt vmcnt(0)" ::: "memory");
    }
    __builtin_amdgcn_s_barrier();

    char* buf = smem + cur * 32768;
    f16x8 a[4][2], b[4][2];
#pragma unroll
    for (int i = 0; i < 4; ++i)
#pragma unroll
      for (int kh = 0; kh < 2; ++kh) {
        a[i][kh] = *(const f16x8*)(buf + ((wm * 4 + i) * 2 + kh) * 1024 + l * 16);
        b[i][kh] = *(const f16x8*)(buf + 16384 + ((wn * 4 + i) * 2 + kh) * 1024 + l * 16);
      }
    __builtin_amdgcn_s_setprio(1);
#pragma unroll
    for (int i = 0; i < 4; ++i)
#pragma unroll
      for (int j = 0; j < 4; ++j) {
        acc[i][j] = __builtin_amdgcn_mfma_f32_16x16x32_f16(a[i][0], b[j][0], acc[i][j], 0, 0, 0);
        acc[i][j] = __builtin_amdgcn_mfma_f32_16x16x32_f16(a[i][1], b[j][1], acc[i][j], 0, 0, 0);
      }
    __builtin_amdgcn_s_setprio(0);
    __builtin_amdgcn_s_barrier();
    cur ^= 1;
  }

#pragma unroll
  for (int i = 0; i < 4; ++i) {
    int row0 = m0 + wm * 64 + i * 16 + (l >> 4) * 4;
#pragma unroll
    for (int j = 0; j < 4; ++j) {
      int col = n0 + wn * 64 + j * 16 + (l & 15);
      if constexpr (MODE == 1) {
        float* C = (float*)Cout;
#pragma unroll
        for (int r = 0; r < 4; ++r)
          C[(size_t)(row0 + r) * DM + col] = acc[i][j][r];
      }
    }
  }
}

// ---------------- RMSNorm + RoPE for K: sums split-K partials, emits fp16 ---
__global__ __launch_bounds__(256) void rmsrope_k_kernel(float* __restrict__ k,
                                                        const float* __restrict__ kp1,
                                                        _Float16* __restrict__ kf,
                                                        const float* __restrict__ cosb,
                                                        const float* __restrict__ sinb) {
  int w = threadIdx.x >> 6;
  int lane = threadIdx.x & 63;
  long r = (long)blockIdx.x * 4 + w;
  float* p = k + r * DH;
  const float* p1 = kp1 + r * DH;
  int s = (int)(r & (S_ - 1));
  float x1 = p[lane] + p1[lane];
  float x2 = p[lane + 64] + p1[lane + 64];
  float ss = fmaf(x1, x1, x2 * x2);
#pragma unroll
  for (int off = 32; off; off >>= 1) ss += __shfl_xor(ss, off);
  float rms = rsqrtf(ss * (1.0f / 128.0f) + 1e-6f);
  float n1 = x1 * rms, n2 = x2 * rms;
  float c = cosb[s * 64 + lane], sn = sinb[s * 64 + lane];
  float o1 = fmaf(n1, c, n2 * sn);
  float o2 = fmaf(-n1, sn, n2 * c);
  p[lane] = o1;
  p[lane + 64] = o2;
  kf[r * DH + lane] = (_Float16)o1;
  kf[r * DH + lane + 64] = (_Float16)o2;
}

// ---------------- selection phase 2: finish mean, project, normalize --------
// qpart now holds 32 chunks of 64 rows (SC-scaled sums; uniform positive
// scale cancels in _normalize).
__global__ void qproj_kernel(const float* __restrict__ partial,
                             const float* __restrict__ proj,
                             float* __restrict__ qp) {
  __shared__ float meanq[128];
  __shared__ float qps[32];
  __shared__ float nrm;
  const int bh = blockIdx.x, t = threadIdx.x;
  float s = 0.0f;
#pragma unroll
  for (int c = 0; c < 32; ++c) s += partial[((size_t)bh * 32 + c) * 128 + t];
  meanq[t] = s * (1.0f / 2048.0f);
  __syncthreads();
  if (t < 32) {
    float sum = 0.0f;
    for (int d = 0; d < 128; ++d) sum = fmaf(meanq[d], proj[d * 32 + t], sum);
    qps[t] = sum;
  }
  __syncthreads();
  if (t == 0) {
    float sum = 0.0f;
    for (int j = 0; j < 32; ++j) sum += qps[j] * qps[j];
    nrm = 1.0f / fmaxf(sqrtf(sum), 1e-12f);
  }
  __syncthreads();
  if (t < 32) qp[bh * 32 + t] = qps[t] * nrm;
}

// ---------------- selection phase 3: per-(bh,block) score ----------------
__global__ __launch_bounds__(256) void kscore_kernel(const float* __restrict__ k,
                                                     const float* __restrict__ proj,
                                                     const float* __restrict__ qp,
                                                     float* __restrict__ scores) {
  __shared__ float ps[128][32];
  __shared__ float kp[64][33];
  __shared__ float cent[33];
  __shared__ float nrm;
  const int bh = blockIdx.x >> 5, n = blockIdx.x & 31;
  const int t = threadIdx.x;
  for (int i = t; i < 4096; i += 256) ps[i >> 5][i & 31] = proj[i];
  const float* kn = k + ((size_t)bh * S_ + n * 64) * DH;
  __syncthreads();
  {
    int row = t >> 2, j0 = (t & 3) * 8;
    float accv[8];
#pragma unroll
    for (int jj = 0; jj < 8; ++jj) accv[jj] = 0.0f;
#pragma unroll 4
    for (int d = 0; d < 128; ++d) {
      float kv = kn[(size_t)row * DH + d];
#pragma unroll
      for (int jj = 0; jj < 8; ++jj) accv[jj] = fmaf(kv, ps[d][j0 + jj], accv[jj]);
    }
#pragma unroll
    for (int jj = 0; jj < 8; ++jj) kp[row][j0 + jj] = accv[jj];
  }
  __syncthreads();
  if (t < 64) {
    float sum = 0.0f;
    for (int j = 0; j < 32; ++j) sum += kp[t][j] * kp[t][j];
    float scl = 1.0f / fmaxf(sqrtf(sum), 1e-12f);
    for (int j = 0; j < 32; ++j) kp[t][j] *= scl;
  }
  __syncthreads();
  if (t < 32) {
    float sum = 0.0f;
    for (int r2 = 0; r2 < 64; ++r2) sum += kp[r2][t];
    cent[t] = sum * (1.0f / 64.0f);
  }
  __syncthreads();
  if (t == 0) {
    float sum = 0.0f;
    for (int j = 0; j < 32; ++j) sum += cent[j] * cent[j];
    nrm = 1.0f / fmaxf(sqrtf(sum), 1e-12f);
  }
  __syncthreads();
  if (t < 32) cent[t] *= nrm;
  __syncthreads();
  if (t < 64) {
    float dt = 0.0f;
    for (int j = 0; j < 32; ++j) dt = fmaf(kp[t][j], cent[j], dt);
#pragma unroll
    for (int off = 32; off; off >>= 1) dt = fminf(dt, __shfl_xor(dt, off));
    if (t == 0) {
      float radius = fminf(fmaxf(1.0f - dt, 0.0f), 1.0f);
      float dq = 0.0f;
      for (int j = 0; j < 32; ++j) dq = fmaf(qp[bh * 32 + j], cent[j], dq);
      scores[bh * 32 + n] = dq + radius;
    }
  }
}

// ---------------- selection phase 4: top-18 + sort ----------------
__global__ void topk_kernel(const float* __restrict__ scores, int* __restrict__ top_idx) {
  if (threadIdx.x != 0) return;
  const int bh = blockIdx.x;
  float sc[NBLK];
  for (int j = 0; j < NBLK; ++j) sc[j] = scores[bh * 32 + j];
  sc[NBLK - 2] = INFINITY;
  sc[NBLK - 1] = INFINITY;
  int chosen[NKEEP];
  bool used[NBLK];
  for (int j = 0; j < NBLK; ++j) used[j] = false;
  for (int kk = 0; kk < NKEEP; ++kk) {
    int best = -1;
    float bv = 0.0f;
    for (int j = 0; j < NBLK; ++j)
      if (!used[j] && (best < 0 || sc[j] > bv)) { bv = sc[j]; best = j; }
    used[best] = true;
    chosen[kk] = best;
  }
  for (int a = 1; a < NKEEP; ++a) {
    int v2 = chosen[a], b2 = a - 1;
    while (b2 >= 0 && chosen[b2] > v2) { chosen[b2 + 1] = chosen[b2]; --b2; }
    chosen[b2 + 1] = v2;
  }
  for (int a = 0; a < NKEEP; ++a) top_idx[bh * NKEEP + a] = chosen[a];
}

// ---------------- MFMA attention v9: per-lane ls partials (deferred reduce) -
__global__ __launch_bounds__(256) void attn_mfma_kernel(const _Float16* __restrict__ qfp,
                                                        const _Float16* __restrict__ kf,
                                                        const _Float16* __restrict__ vt,
                                                        const int* __restrict__ top_idx,
                                                        _Float16* __restrict__ yf) {
  __shared__ char lds[74752];  // buf0 0..32K (K 16K|V 16K), buf1 32..64K, P 64K..
  const int bh = blockIdx.x >> 5;
  const int qt = blockIdx.x & 31;
  const int t = threadIdx.x, l = t & 63, w = t >> 6;
  const int lr = l & 15, lg = l >> 4;
  const float THR2 = 11.5415603f;  // 8 * log2(e)

  f16x8 qf[4];
  {
    const _Float16* qbase = qfp + ((size_t)(bh * S_ + qt * 64 + w * 16 + lr)) * DH + lg * 8;
#pragma unroll
    for (int dc = 0; dc < 4; ++dc)
      qf[dc] = *(const f16x8*)(qbase + dc * 32);
  }

  float m_[4] = {-INFINITY, -INFINITY, -INFINITY, -INFINITY};
  float ls[4] = {0.f, 0.f, 0.f, 0.f};  // PER-LANE partial sums
  f32x4 yacc[8];
#pragma unroll
  for (int dt = 0; dt < 8; ++dt) yacc[dt] = (f32x4){0.f, 0.f, 0.f, 0.f};

  char* Pw = lds + 65536 + w * 2304;  // per-wave P: [16 q][72 fp16]

  const _Float16* kb0 = kf + (size_t)bh * S_ * DH;
  const _Float16* vb0 = vt + (size_t)bh * DH * S_;
  const int* idxp = top_idx + bh * NKEEP;

  auto STAGE = [&](int blk, int c) {
    char* base = lds + c * 32768;
#pragma unroll
    for (int f0 = 0; f0 < 4; ++f0) {
      int f = w * 4 + f0;
      int kt = f >> 2, dc = f & 3;
      GLOAD16(kb0 + (size_t)(blk * 64 + kt * 16 + lr) * DH + dc * 32 + lg * 8,
              base + f * 1024);
      int K0 = f >> 3, dt = f & 7;
      GLOAD16(vb0 + (size_t)(dt * 16 + lr) * S_ + blk * 64 + K0 * 32 + lg * 8,
              base + 16384 + f * 1024);
    }
  };

  int cur = 0;
  STAGE(idxp[0], 0);

  for (int it = 0; it < NKEEP; ++it) {
    if (it + 1 < NKEEP) {
      STAGE(idxp[it + 1], cur ^ 1);
      asm volatile("s_waitcnt vmcnt(8)" ::: "memory");
    } else {
      asm volatile("s_waitcnt vmcnt(0)" ::: "memory");
    }
    __builtin_amdgcn_s_barrier();
    char* buf = lds + cur * 32768;

    f32x4 sacc[4];
#pragma unroll
    for (int kt = 0; kt < 4; ++kt) sacc[kt] = (f32x4){0.f, 0.f, 0.f, 0.f};
    __builtin_amdgcn_s_setprio(1);
#pragma unroll
    for (int kt = 0; kt < 4; ++kt)
#pragma unroll
      for (int dc = 0; dc < 4; ++dc) {
        f16x8 kfr = *(const f16x8*)(buf + (kt * 4 + dc) * 1024 + l * 16);
        sacc[kt] = __builtin_amdgcn_mfma_f32_16x16x32_f16(qf[dc], kfr, sacc[kt], 0, 0, 0);
      }
    __builtin_amdgcn_s_setprio(0);

    float lmax[4];
#pragma unroll
    for (int r = 0; r < 4; ++r)
      lmax[r] = fmaxf(fmaxf(sacc[0][r], sacc[1][r]), fmaxf(sacc[2][r], sacc[3][r]));
    bool ok = (lmax[0] <= m_[0] + THR2) && (lmax[1] <= m_[1] + THR2) &&
              (lmax[2] <= m_[2] + THR2) && (lmax[3] <= m_[3] + THR2);
    float p[4][4];
    if (__all(ok)) {
#pragma unroll
      for (int r = 0; r < 4; ++r) {
#pragma unroll
        for (int kt = 0; kt < 4; ++kt) {
          p[kt][r] = fexp2(sacc[kt][r] - m_[r]);
          ls[r] += p[kt][r];
        }
      }
    } else {
#pragma unroll
      for (int r = 0; r < 4; ++r) {
        float mv = lmax[r];
#pragma unroll
        for (int off = 1; off < 16; off <<= 1) mv = fmaxf(mv, __shfl_xor(mv, off));
        float mn = fmaxf(m_[r], mv);
        float corr = fexp2(m_[r] - mn);
        float rs = 0.f;
#pragma unroll
        for (int kt = 0; kt < 4; ++kt) {
          p[kt][r] = fexp2(sacc[kt][r] - mn);
          rs += p[kt][r];
        }
        ls[r] = ls[r] * corr + rs;
        m_[r] = mn;
#pragma unroll
        for (int dt = 0; dt < 8; ++dt) yacc[dt][r] *= corr;
      }
    }

#pragma unroll
    for (int kt = 0; kt < 4; ++kt)
#pragma unroll
      for (int r = 0; r < 4; ++r)
        *(_Float16*)(Pw + (lg * 4 + r) * 144 + (kt * 16 + lr) * 2) = (_Float16)p[kt][r];

    __builtin_amdgcn_s_setprio(1);
#pragma unroll
    for (int K0 = 0; K0 < 2; ++K0) {
      f16x8 pa = *(const f16x8*)(Pw + lr * 144 + K0 * 64 + lg * 16);
#pragma unroll
      for (int dt = 0; dt < 8; ++dt) {
        f16x8 vf = *(const f16x8*)(buf + 16384 + (K0 * 8 + dt) * 1024 + l * 16);
        yacc[dt] = __builtin_amdgcn_mfma_f32_16x16x32_f16(pa, vf, yacc[dt], 0, 0, 0);
      }
    }
    __builtin_amdgcn_s_setprio(0);

    __builtin_amdgcn_s_barrier();
    cur ^= 1;
  }

  // epilogue: reduce per-lane ls partials across the row's 16 lanes (once)
  const int b = bh >> 4, h = bh & (H_ - 1);
  float inv[4];
#pragma unroll
  for (int r = 0; r < 4; ++r) {
    float s = ls[r];
#pragma unroll
    for (int off = 1; off < 16; off <<= 1) s += __shfl_xor(s, off);
    inv[r] = 1.0f / s;
  }
#pragma unroll
  for (int r = 0; r < 4; ++r) {
    int srow = qt * 64 + w * 16 + lg * 4 + r;
    size_t off0 = ((size_t)b * S_ + srow) * DM + h * DH + lr;
#pragma unroll
    for (int dt = 0; dt < 8; ++dt)
      yf[off0 + dt * 16] = (_Float16)(yacc[dt][r] * inv[r]);
  }
}

extern "C" void kernel_launch(void* const* d_in, const int* in_sizes, int n_in,
                              void* d_out, int out_size, void* d_ws, size_t ws_size,
                              hipStream_t stream) {
  const float* x  = (const float*)d_in[0];
  const float* Wq = (const float*)d_in[1];
  const float* Wk = (const float*)d_in[2];
  const float* Wv = (const float*)d_in[3];
  const float* Wo = (const float*)d_in[4];
  const float* qg = (const float*)d_in[5];
  float* out = (float*)d_out;

  const size_t NE = (size_t)BH * S_ * DH;   // 8388608 elements
  const size_t WE = (size_t)DM * DM;        // 4194304 elements per W
  char* p = (char*)d_ws;
  float* q_ws = (float*)p; p += NE * 4;     // kpart1 during k-GEMM; then qf16+qpart
  float* k_ws = (float*)p; p += NE * 4;     // kpart0 -> roped k f32
  unsigned short* xhi = (unsigned short*)p; p += NE * 2;  // -> yf16 after k-GEMM
  unsigned short* xlo = (unsigned short*)p; p += NE * 2;  // -> vt after k-GEMM
  _Float16* xf16 = (_Float16*)p; p += NE * 2;             // x fp16 (qv A input)
  unsigned short* wkhi = (unsigned short*)p; p += WE * 2; // \ kf16 spans wkhi+wklo
  unsigned short* wklo = (unsigned short*)p; p += WE * 2; // / (both dead post k-GEMM)
  _Float16* wqv = (_Float16*)p; p += 2 * WE * 2;          // [Wq;Wv] fp16; -> wo
  float* cosb = (float*)p; p += (size_t)S_ * 64 * 4;
  float* sinb = (float*)p; p += (size_t)S_ * 64 * 4;
  float* projb = (float*)p; p += 4096 * 4;
  int* idxb = (int*)p; p += BH * NKEEP * 4;
  float* scores = (float*)p; p += BH * NBLK * 4;
  float* qpbuf = (float*)p; p += BH * 32 * 4;
  // aliases (each with size + ordering check, stream-ordered):
  float* kpart1 = q_ws;                  // NE f32; read by rmsrope_k, dead after
  _Float16* qf16 = (_Float16*)q_ws;      // NE fp16 (16MB) in q_ws (33.5MB):
                                         // written by qv AFTER rmsrope_k read kpart1
  float* qpart = (float*)((char*)q_ws + NE * 2);  // +16MB, 512KB (BH*32*128 f32)
  _Float16* kf16 = (_Float16*)wkhi;      // NE fp16 = wkhi+wklo (16.8MB), both dead
  _Float16* vt = (_Float16*)xlo;         // NE fp16 <= NE ushort; xlo dead after k-GEMM
  _Float16* yf16 = (_Float16*)xhi;       // NE fp16 <= NE ushort; xhi dead after k-GEMM
  _Float16* wo = wqv;                    // WE fp16 <= 2WE fp16; wqv dead after qv-GEMM
  // total ws use ~152 MB (no growth)

  const int nx4 = (int)(NE / 4);
  const int nw4 = (int)(WE / 4);

  tables_kernel<<<dim3(16 + S_), dim3(256), 0, stream>>>(projb, cosb, sinb);
  split_x3_kernel<<<dim3(nx4 / 256), dim3(256), 0, stream>>>(x, xhi, xlo, xf16, nx4);
  split_w3_kernel<<<dim3(nw4 / 256), dim3(256), 0, stream>>>(Wk, Wq, Wv, wkhi, wklo,
                                                             wqv, wqv + WE, nw4);

  // k: bf16x3, split-K=2, 8-wave 256^2, min-barrier counted-vmcnt schedule
  mfma_gemm_k_sk<<<dim3(8, 16, 2), dim3(512), 0, stream>>>(xhi, xlo, wkhi, wklo,
                                                           k_ws, kpart1);

  // k finalize: sum partials + RMS + RoPE; writes k f32 (in place) + kf16
  // (also the last reader of kpart1=q_ws before qv overwrites it with qf16)
  rmsrope_k_kernel<<<dim3((BH * S_) / 4), dim3(256), 0, stream>>>(k_ws, kpart1, kf16, cosb, sinb);

  // q+V fused GEMM with in-epilogue RMS+RoPE+gain+fp16+q-mean partials
  // (replaces rmsrope_q; q f32 never materialized)
  mfma_gemm_qv<<<dim3(16, 16), dim3(512), 0, stream>>>(xf16, wqv, cosb, sinb, qg,
                                                       qf16, qpart, vt);

  qproj_kernel<<<dim3(BH), dim3(128), 0, stream>>>(qpart, projb, qpbuf);
  kscore_kernel<<<dim3(BH * NBLK), dim3(256), 0, stream>>>(k_ws, projb, qpbuf, scores);
  topk_kernel<<<dim3(BH), dim3(64), 0, stream>>>(scores, idxb);

  // attn v9: per-lane ls partials, raw v_exp softmax, lazy max-reduce defer
  attn_mfma_kernel<<<dim3(BH * 32), dim3(256), 0, stream>>>(qf16, kf16, vt, idxb, yf16);

  // O: fp16 x1 on yf16 and Wo-f16
  split_f16_kernel<<<dim3(nw4 / 256), dim3(256), 0, stream>>>(Wo, wo, nw4);
  mfma_gemm_f16<1><<<dim3(16, 32), dim3(256), 0, stream>>>(yf16, wo, out);
}